// Round 1
// baseline (1915.097 us; speedup 1.0000x reference)
//
#include <hip/hip_runtime.h>

// Problem constants (from reference): N=100000, H=20000, E=1600000, D=64, L=3, F=256
#define HYP 20000
#define NLAYER 3

static __device__ __forceinline__ void wave_ln_stats(float v, float& mu, float& rs){
  float s = v, q = v*v;
  #pragma unroll
  for (int o = 32; o > 0; o >>= 1){
    s += __shfl_xor(s, o, 64);
    q += __shfl_xor(q, o, 64);
  }
  mu = s * (1.0f/64.0f);
  float var = fmaf(-mu, mu, q*(1.0f/64.0f));
  rs = rsqrtf(var + 1e-5f);
}

__global__ void k_count(const int* __restrict__ src, const int* __restrict__ dst, int E,
                        int* __restrict__ cnt_n, int* __restrict__ cnt_h){
  int i = blockIdx.x*blockDim.x + threadIdx.x;
  int st = gridDim.x*blockDim.x;
  for (; i < E; i += st){
    atomicAdd(&cnt_n[src[i]], 1);
    atomicAdd(&cnt_h[dst[i]], 1);
  }
}

// Single-workgroup exclusive scan (arrays are <=100K ints). Also emits rsqrt(max(deg,1)).
__global__ __launch_bounds__(1024) void k_scan(const int* __restrict__ cnt, int n,
                                               int* __restrict__ off, float* __restrict__ isv){
  __shared__ int sm[32];
  __shared__ int s_carry;
  int tid = threadIdx.x;
  int lane = tid & 63, wv = tid >> 6;   // 16 waves
  if (tid == 0) s_carry = 0;
  __syncthreads();
  int nchunk = (n + 4095) >> 12;
  for (int c = 0; c < nchunk; ++c){
    int base = (c << 12) + tid*4;
    int v0 = (base+0 < n) ? cnt[base+0] : 0;
    int v1 = (base+1 < n) ? cnt[base+1] : 0;
    int v2 = (base+2 < n) ? cnt[base+2] : 0;
    int v3 = (base+3 < n) ? cnt[base+3] : 0;
    int s = v0+v1+v2+v3;
    int x = s;
    #pragma unroll
    for (int o = 1; o < 64; o <<= 1){
      int t = __shfl_up(x, o, 64);
      if (lane >= o) x += t;
    }
    if (lane == 63) sm[wv] = x;
    __syncthreads();
    if (wv == 0){
      int y = (lane < 16) ? sm[lane] : 0;
      #pragma unroll
      for (int o = 1; o < 16; o <<= 1){
        int t = __shfl_up(y, o, 64);
        if (lane >= o) y += t;
      }
      if (lane < 16) sm[lane] = y;
    }
    __syncthreads();
    int waveoff = (wv == 0) ? 0 : sm[wv-1];
    int carry = s_carry;
    int run = carry + waveoff + (x - s);
    if (base+0 < n){ off[base+0] = run; isv[base+0] = rsqrtf((float)(v0>0?v0:1)); run += v0; }
    if (base+1 < n){ off[base+1] = run; isv[base+1] = rsqrtf((float)(v1>0?v1:1)); run += v1; }
    if (base+2 < n){ off[base+2] = run; isv[base+2] = rsqrtf((float)(v2>0?v2:1)); run += v2; }
    if (base+3 < n){ off[base+3] = run; isv[base+3] = rsqrtf((float)(v3>0?v3:1)); run += v3; }
    __syncthreads();
    if (tid == 1023) s_carry = carry + waveoff + x;
    __syncthreads();
  }
  if (tid == 0) off[n] = s_carry;
}

__global__ void k_fill(const int* __restrict__ src, const int* __restrict__ dst, int E,
    const int* __restrict__ off_h, int* __restrict__ cur_h, int* __restrict__ csr_h,
    const int* __restrict__ off_n, int* __restrict__ cur_n, int* __restrict__ csr_n){
  int i = blockIdx.x*blockDim.x + threadIdx.x;
  int st = gridDim.x*blockDim.x;
  for (; i < E; i += st){
    int s = src[i], d = dst[i];
    int p = atomicAdd(&cur_h[d], 1);
    csr_h[off_h[d] + p] = s;
    int q = atomicAdd(&cur_n[s], 1);
    csr_n[off_n[s] + q] = d;
  }
}

// One wave per destination row: acc[lane] = sum over CSR list of feat[idx][lane] (* isv[idx] if SCALE)
template<bool SCALE>
__global__ __launch_bounds__(256) void k_gather(const float* __restrict__ feat,
    const int* __restrict__ csr, const int* __restrict__ off,
    const float* __restrict__ isv, float* __restrict__ agg, int nrows){
  int lane = threadIdx.x & 63, wv = threadIdx.x >> 6;
  int r = blockIdx.x*4 + wv;
  int stride = gridDim.x*4;
  for (; r < nrows; r += stride){
    int b = off[r], e = off[r+1];
    float acc = 0.f;
    int t = b;
    for (; t + 4 <= e; t += 4){
      int s0 = csr[t], s1 = csr[t+1], s2 = csr[t+2], s3 = csr[t+3];
      float v0 = feat[s0*64 + lane];
      float v1 = feat[s1*64 + lane];
      float v2 = feat[s2*64 + lane];
      float v3 = feat[s3*64 + lane];
      if (SCALE){
        acc = fmaf(v0, isv[s0], acc); acc = fmaf(v1, isv[s1], acc);
        acc = fmaf(v2, isv[s2], acc); acc = fmaf(v3, isv[s3], acc);
      } else {
        acc += (v0 + v1) + (v2 + v3);
      }
    }
    for (; t < e; ++t){
      int s0 = csr[t];
      float v0 = feat[s0*64 + lane];
      acc = SCALE ? fmaf(v0, isv[s0], acc) : (acc + v0);
    }
    agg[r*64 + lane] = acc;
  }
}

// h_hyper_scaled[j] = ((aggx[j] @ W) * is_hyp + b) * is_hyp
__global__ __launch_bounds__(256) void k_mmA(const float* __restrict__ agg,
    const float* __restrict__ Wg, const float* __restrict__ bias,
    const float* __restrict__ ihy, float* __restrict__ ouths, int nrows){
  __shared__ __align__(16) float Ws[64*68];
  int tid = threadIdx.x;
  #pragma unroll
  for (int i = 0; i < 16; ++i){ int e = tid + i*256; Ws[(e>>6)*68 + (e&63)] = Wg[e]; }
  __syncthreads();
  int lane = tid & 63, wv = tid >> 6;
  float bl = bias[lane];
  int r = blockIdx.x*4 + wv, stride = gridDim.x*4;
  for (; r < nrows; r += stride){
    float val = agg[r*64 + lane];
    float acc = 0.f;
    #pragma unroll
    for (int k = 0; k < 64; ++k) acc = fmaf(__shfl(val, k, 64), Ws[k*68 + lane], acc);
    float ih = ihy[r];
    ouths[r*64 + lane] = fmaf(acc, ih, bl) * ih;
  }
}

// P[n] = LN( hin[n] + (aggh[n] @ W)*is_node[n] + b , g, be )
__global__ __launch_bounds__(256) void k_mmB_ln(const float* __restrict__ agg,
    const float* __restrict__ Wg, const float* __restrict__ bias,
    const float* __restrict__ isn, const float* __restrict__ hin,
    const float* __restrict__ g, const float* __restrict__ be,
    float* __restrict__ P, int nrows){
  __shared__ __align__(16) float Ws[64*68];
  int tid = threadIdx.x;
  #pragma unroll
  for (int i = 0; i < 16; ++i){ int e = tid + i*256; Ws[(e>>6)*68 + (e&63)] = Wg[e]; }
  __syncthreads();
  int lane = tid & 63, wv = tid >> 6;
  float bl = bias[lane], gl = g[lane], bel = be[lane];
  int r = blockIdx.x*4 + wv, stride = gridDim.x*4;
  for (; r < nrows; r += stride){
    float val = agg[r*64 + lane];
    float acc = 0.f;
    #pragma unroll
    for (int k = 0; k < 64; ++k) acc = fmaf(__shfl(val, k, 64), Ws[k*68 + lane], acc);
    float v = fmaf(acc, isn[r], bl) + hin[r*64 + lane];
    float mu, rs; wave_ln_stats(v, mu, rs);
    P[r*64 + lane] = fmaf((v - mu)*rs, gl, bel);
  }
}

// Fused FFN: Out = LN( X + relu(X@W1+b1)@W2 + b2 , g, be ); 64-row tile per block, 4x4 reg tiles.
__global__ __launch_bounds__(256) void k_ffn(const float* __restrict__ X,
    const float* __restrict__ W1g, const float* __restrict__ b1g,
    const float* __restrict__ W2g, const float* __restrict__ b2g,
    const float* __restrict__ g, const float* __restrict__ be,
    float* __restrict__ Outp, int nrows){
  __shared__ __align__(16) float XsT[64*68];  // XsT[c][r]
  __shared__ __align__(16) float Ws1[64*68];  // Ws1[k][c] ; reused as PRE row-major in epilogue
  __shared__ __align__(16) float C1T[64*68];  // C1T[kk][r]
  __shared__ __align__(16) float Ws2[64*68];  // Ws2[kk][c]
  int tid = threadIdx.x;
  int tx = tid & 15, ty = tid >> 4;
  int rowbase = blockIdx.x * 64;
  #pragma unroll
  for (int i = 0; i < 16; ++i){
    int e = tid + i*256; int r = e >> 6, c = e & 63;
    int rr = rowbase + r;
    float v = (rr < nrows) ? X[rr*64 + c] : 0.f;
    XsT[c*68 + r] = v;
  }
  float acc2[4][4];
  #pragma unroll
  for (int i = 0; i < 4; ++i)
    #pragma unroll
    for (int j = 0; j < 4; ++j) acc2[i][j] = 0.f;

  for (int blk = 0; blk < 4; ++blk){
    __syncthreads();
    #pragma unroll
    for (int i = 0; i < 16; ++i){
      int e = tid + i*256; int k = e >> 6, c = e & 63;
      Ws1[k*68 + c] = W1g[k*256 + blk*64 + c];
      Ws2[k*68 + c] = W2g[(blk*64 + k)*64 + c];
    }
    __syncthreads();
    float c1[4][4];
    #pragma unroll
    for (int i = 0; i < 4; ++i)
      #pragma unroll
      for (int j = 0; j < 4; ++j) c1[i][j] = 0.f;
    #pragma unroll
    for (int k = 0; k < 64; ++k){
      float4 a = *(const float4*)&XsT[k*68 + ty*4];
      float4 b = *(const float4*)&Ws1[k*68 + tx*4];
      float av[4] = {a.x, a.y, a.z, a.w};
      float bv[4] = {b.x, b.y, b.z, b.w};
      #pragma unroll
      for (int i = 0; i < 4; ++i)
        #pragma unroll
        for (int j = 0; j < 4; ++j) c1[i][j] = fmaf(av[i], bv[j], c1[i][j]);
    }
    float4 b1v = *(const float4*)&b1g[blk*64 + tx*4];
    float b1a[4] = {b1v.x, b1v.y, b1v.z, b1v.w};
    #pragma unroll
    for (int i = 0; i < 4; ++i)
      #pragma unroll
      for (int j = 0; j < 4; ++j) c1[i][j] = fmaxf(c1[i][j] + b1a[j], 0.f);
    #pragma unroll
    for (int j = 0; j < 4; ++j){
      float4 v; v.x = c1[0][j]; v.y = c1[1][j]; v.z = c1[2][j]; v.w = c1[3][j];
      *(float4*)&C1T[(tx*4 + j)*68 + ty*4] = v;
    }
    __syncthreads();
    #pragma unroll
    for (int k = 0; k < 64; ++k){
      float4 a = *(const float4*)&C1T[k*68 + ty*4];
      float4 b = *(const float4*)&Ws2[k*68 + tx*4];
      float av[4] = {a.x, a.y, a.z, a.w};
      float bv[4] = {b.x, b.y, b.z, b.w};
      #pragma unroll
      for (int i = 0; i < 4; ++i)
        #pragma unroll
        for (int j = 0; j < 4; ++j) acc2[i][j] = fmaf(av[i], bv[j], acc2[i][j]);
    }
  }
  // epilogue: pre = acc2 + b2 + X (residual), then per-row LN
  float4 b2v = *(const float4*)&b2g[tx*4];
  float b2a[4] = {b2v.x, b2v.y, b2v.z, b2v.w};
  float pre[4][4];
  #pragma unroll
  for (int i = 0; i < 4; ++i)
    #pragma unroll
    for (int j = 0; j < 4; ++j)
      pre[i][j] = acc2[i][j] + b2a[j] + XsT[(tx*4 + j)*68 + (ty*4 + i)];
  __syncthreads();
  #pragma unroll
  for (int i = 0; i < 4; ++i){
    float4 v; v.x = pre[i][0]; v.y = pre[i][1]; v.z = pre[i][2]; v.w = pre[i][3];
    *(float4*)&Ws1[(ty*4 + i)*68 + tx*4] = v;
  }
  __syncthreads();
  int wv = tid >> 6, lane = tid & 63;
  float gl = g[lane], bel = be[lane];
  #pragma unroll
  for (int t = 0; t < 16; ++t){
    int r = t*4 + wv;
    int grow = rowbase + r;
    float v = Ws1[r*68 + lane];
    float mu, rs; wave_ln_stats(v, mu, rs);
    if (grow < nrows) Outp[grow*64 + lane] = fmaf((v - mu)*rs, gl, bel);
  }
}

// out[n] = LN(Q[n], gF, bF) @ Wo + bo
__global__ __launch_bounds__(256) void k_final(const float* __restrict__ Q,
    const float* __restrict__ Wg, const float* __restrict__ bog,
    const float* __restrict__ gF, const float* __restrict__ bF,
    float* __restrict__ out, int nrows){
  __shared__ __align__(16) float Ws[64*68];
  int tid = threadIdx.x;
  #pragma unroll
  for (int i = 0; i < 16; ++i){ int e = tid + i*256; Ws[(e>>6)*68 + (e&63)] = Wg[e]; }
  __syncthreads();
  int lane = tid & 63, wv = tid >> 6;
  float gl = gF[lane], bl = bF[lane], bol = bog[lane];
  int r = blockIdx.x*4 + wv, stride = gridDim.x*4;
  for (; r < nrows; r += stride){
    float v = Q[r*64 + lane];
    float mu, rs; wave_ln_stats(v, mu, rs);
    float nv = fmaf((v - mu)*rs, gl, bl);
    float acc = 0.f;
    #pragma unroll
    for (int k = 0; k < 64; ++k) acc = fmaf(__shfl(nv, k, 64), Ws[k*68 + lane], acc);
    out[r*64 + lane] = acc + bol;
  }
}

extern "C" void kernel_launch(void* const* d_in, const int* in_sizes, int n_in,
                              void* d_out, int out_size, void* d_ws, size_t ws_size,
                              hipStream_t stream){
  const float* nf   = (const float*)d_in[0];
  const int*   esrc = (const int*)d_in[1];
  const int*   edst = (const int*)d_in[2];
  // d_in[3] = n_hyper scalar (device); H hardcoded from reference constants
  const float* Wn2h = (const float*)d_in[4];
  const float* bn2h = (const float*)d_in[5];
  const float* Wh2n = (const float*)d_in[6];
  const float* bh2n = (const float*)d_in[7];
  const float* W1   = (const float*)d_in[8];
  const float* b1   = (const float*)d_in[9];
  const float* W2   = (const float*)d_in[10];
  const float* b2   = (const float*)d_in[11];
  const float* g1   = (const float*)d_in[12];
  const float* be1  = (const float*)d_in[13];
  const float* g2   = (const float*)d_in[14];
  const float* be2  = (const float*)d_in[15];
  const float* gF   = (const float*)d_in[16];
  const float* bF   = (const float*)d_in[17];
  const float* Wo   = (const float*)d_in[18];
  const float* bo   = (const float*)d_in[19];
  const int N = in_sizes[0] / 64;
  const int E = in_sizes[1];
  const int H = HYP;
  float* out = (float*)d_out;

  char* w = (char*)d_ws;
  auto carve = [&](size_t bytes) -> char* {
    char* p = w; w += (bytes + 255) & ~(size_t)255; return p;
  };
  int* cnt_h = (int*)carve((size_t)H*4);
  int* cnt_n = (int*)carve((size_t)N*4);
  int* cur_h = (int*)carve((size_t)H*4);
  int* cur_n = (int*)carve((size_t)N*4);
  size_t zero_span = (size_t)(w - (char*)cnt_h);
  int*   off_h = (int*)carve((size_t)(H+1)*4);
  int*   off_n = (int*)carve((size_t)(N+1)*4);
  float* is_h  = (float*)carve((size_t)H*4);
  float* is_n  = (float*)carve((size_t)N*4);
  int*   csr_h = (int*)carve((size_t)E*4);
  int*   csr_n = (int*)carve((size_t)E*4);
  float* aggx  = (float*)carve((size_t)H*64*4);
  float* hhs   = (float*)carve((size_t)H*64*4);
  float* aggh  = (float*)carve((size_t)N*64*4);
  float* Pb    = (float*)carve((size_t)N*64*4);
  float* Qb    = (float*)carve((size_t)N*64*4);

  hipMemsetAsync(cnt_h, 0, zero_span, stream);
  k_count<<<2048, 256, 0, stream>>>(esrc, edst, E, cnt_n, cnt_h);
  k_scan<<<1, 1024, 0, stream>>>(cnt_h, H, off_h, is_h);
  k_scan<<<1, 1024, 0, stream>>>(cnt_n, N, off_n, is_n);
  k_fill<<<2048, 256, 0, stream>>>(esrc, edst, E, off_h, cur_h, csr_h, off_n, cur_n, csr_n);

  for (int l = 0; l < NLAYER; ++l){
    const float* hin = (l == 0) ? nf : Qb;
    k_gather<true><<<2048, 256, 0, stream>>>(hin, csr_h, off_h, is_n, aggx, H);
    k_mmA<<<512, 256, 0, stream>>>(aggx, Wn2h + l*4096, bn2h + l*64, is_h, hhs, H);
    k_gather<false><<<2048, 256, 0, stream>>>(hhs, csr_n, off_n, nullptr, aggh, N);
    k_mmB_ln<<<1024, 256, 0, stream>>>(aggh, Wh2n + l*4096, bh2n + l*64, is_n, hin,
                                       g1 + l*64, be1 + l*64, Pb, N);
    k_ffn<<<(N + 63)/64, 256, 0, stream>>>(Pb, W1 + l*64*256, b1 + l*256, W2 + l*256*64,
                                           b2 + l*64, g2 + l*64, be2 + l*64, Qb, N);
  }
  k_final<<<1024, 256, 0, stream>>>(Qb, Wo, bo, gF, bF, out, N);
}

// Round 2
// 1415.955 us; speedup vs baseline: 1.3525x; 1.3525x over previous
//
#include <hip/hip_runtime.h>

// Problem constants (from reference): N=100000, H=20000, E=1600000, D=64, L=3, F=256
#define HYP 20000
#define NLAYER 3

typedef __attribute__((ext_vector_type(8))) short short8;
typedef __attribute__((ext_vector_type(4))) float floatx4;
typedef __attribute__((ext_vector_type(4))) unsigned short ushort4v;

static __device__ __forceinline__ unsigned short f2bf(float f){
  union { float f; unsigned u; } v; v.f = f;
  unsigned r = v.u + 0x7FFF + ((v.u >> 16) & 1);
  return (unsigned short)(r >> 16);
}

static __device__ __forceinline__ void wave_ln_stats(float v, float& mu, float& rs){
  float s = v, q = v*v;
  #pragma unroll
  for (int o = 32; o > 0; o >>= 1){
    s += __shfl_xor(s, o, 64);
    q += __shfl_xor(q, o, 64);
  }
  mu = s * (1.0f/64.0f);
  float var = fmaf(-mu, mu, q*(1.0f/64.0f));
  rs = rsqrtf(var + 1e-5f);
}

__global__ void k_count(const int* __restrict__ src, const int* __restrict__ dst, int E,
                        int* __restrict__ cnt_n, int* __restrict__ cnt_h){
  int i = blockIdx.x*blockDim.x + threadIdx.x;
  int st = gridDim.x*blockDim.x;
  for (; i < E; i += st){
    atomicAdd(&cnt_n[src[i]], 1);
    atomicAdd(&cnt_h[dst[i]], 1);
  }
}

// Single-workgroup exclusive scan (arrays are <=100K ints). Also emits rsqrt(max(deg,1)).
__global__ __launch_bounds__(1024) void k_scan(const int* __restrict__ cnt, int n,
                                               int* __restrict__ off, float* __restrict__ isv){
  __shared__ int sm[32];
  __shared__ int s_carry;
  int tid = threadIdx.x;
  int lane = tid & 63, wv = tid >> 6;   // 16 waves
  if (tid == 0) s_carry = 0;
  __syncthreads();
  int nchunk = (n + 4095) >> 12;
  for (int c = 0; c < nchunk; ++c){
    int base = (c << 12) + tid*4;
    int v0 = (base+0 < n) ? cnt[base+0] : 0;
    int v1 = (base+1 < n) ? cnt[base+1] : 0;
    int v2 = (base+2 < n) ? cnt[base+2] : 0;
    int v3 = (base+3 < n) ? cnt[base+3] : 0;
    int s = v0+v1+v2+v3;
    int x = s;
    #pragma unroll
    for (int o = 1; o < 64; o <<= 1){
      int t = __shfl_up(x, o, 64);
      if (lane >= o) x += t;
    }
    if (lane == 63) sm[wv] = x;
    __syncthreads();
    if (wv == 0){
      int y = (lane < 16) ? sm[lane] : 0;
      #pragma unroll
      for (int o = 1; o < 16; o <<= 1){
        int t = __shfl_up(y, o, 64);
        if (lane >= o) y += t;
      }
      if (lane < 16) sm[lane] = y;
    }
    __syncthreads();
    int waveoff = (wv == 0) ? 0 : sm[wv-1];
    int carry = s_carry;
    int run = carry + waveoff + (x - s);
    if (base+0 < n){ off[base+0] = run; isv[base+0] = rsqrtf((float)(v0>0?v0:1)); run += v0; }
    if (base+1 < n){ off[base+1] = run; isv[base+1] = rsqrtf((float)(v1>0?v1:1)); run += v1; }
    if (base+2 < n){ off[base+2] = run; isv[base+2] = rsqrtf((float)(v2>0?v2:1)); run += v2; }
    if (base+3 < n){ off[base+3] = run; isv[base+3] = rsqrtf((float)(v3>0?v3:1)); run += v3; }
    __syncthreads();
    if (tid == 1023) s_carry = carry + waveoff + x;
    __syncthreads();
  }
  if (tid == 0) off[n] = s_carry;
}

__global__ void k_fill(const int* __restrict__ src, const int* __restrict__ dst, int E,
    const int* __restrict__ off_h, int* __restrict__ cur_h, int* __restrict__ csr_h,
    const int* __restrict__ off_n, int* __restrict__ cur_n, int* __restrict__ csr_n){
  int i = blockIdx.x*blockDim.x + threadIdx.x;
  int st = gridDim.x*blockDim.x;
  for (; i < E; i += st){
    int s = src[i], d = dst[i];
    int p = atomicAdd(&cur_h[d], 1);
    csr_h[off_h[d] + p] = s;
    int q = atomicAdd(&cur_n[s], 1);
    csr_n[off_n[s] + q] = d;
  }
}

// One wave per destination row: acc[lane] = sum over CSR list of feat[idx][lane] (* isv[idx] if SCALE)
template<bool SCALE>
__global__ __launch_bounds__(256) void k_gather(const float* __restrict__ feat,
    const int* __restrict__ csr, const int* __restrict__ off,
    const float* __restrict__ isv, float* __restrict__ agg, int nrows){
  int lane = threadIdx.x & 63, wv = threadIdx.x >> 6;
  int r = blockIdx.x*4 + wv;
  int stride = gridDim.x*4;
  for (; r < nrows; r += stride){
    int b = off[r], e = off[r+1];
    float acc = 0.f;
    int t = b;
    for (; t + 4 <= e; t += 4){
      int s0 = csr[t], s1 = csr[t+1], s2 = csr[t+2], s3 = csr[t+3];
      float v0 = feat[s0*64 + lane];
      float v1 = feat[s1*64 + lane];
      float v2 = feat[s2*64 + lane];
      float v3 = feat[s3*64 + lane];
      if (SCALE){
        acc = fmaf(v0, isv[s0], acc); acc = fmaf(v1, isv[s1], acc);
        acc = fmaf(v2, isv[s2], acc); acc = fmaf(v3, isv[s3], acc);
      } else {
        acc += (v0 + v1) + (v2 + v3);
      }
    }
    for (; t < e; ++t){
      int s0 = csr[t];
      float v0 = feat[s0*64 + lane];
      acc = SCALE ? fmaf(v0, isv[s0], acc) : (acc + v0);
    }
    agg[r*64 + lane] = acc;
  }
}

// h_hyper_scaled[j] = ((aggx[j] @ W) * is_hyp + b) * is_hyp
__global__ __launch_bounds__(256) void k_mmA(const float* __restrict__ agg,
    const float* __restrict__ Wg, const float* __restrict__ bias,
    const float* __restrict__ ihy, float* __restrict__ ouths, int nrows){
  __shared__ __align__(16) float Ws[64*68];
  int tid = threadIdx.x;
  #pragma unroll
  for (int i = 0; i < 16; ++i){ int e = tid + i*256; Ws[(e>>6)*68 + (e&63)] = Wg[e]; }
  __syncthreads();
  int lane = tid & 63, wv = tid >> 6;
  float bl = bias[lane];
  int r = blockIdx.x*4 + wv, stride = gridDim.x*4;
  for (; r < nrows; r += stride){
    float val = agg[r*64 + lane];
    float acc = 0.f;
    #pragma unroll
    for (int k = 0; k < 64; ++k) acc = fmaf(__shfl(val, k, 64), Ws[k*68 + lane], acc);
    float ih = ihy[r];
    ouths[r*64 + lane] = fmaf(acc, ih, bl) * ih;
  }
}

// P[n] = LN( hin[n] + (aggh[n] @ W)*is_node[n] + b , g, be )
__global__ __launch_bounds__(256) void k_mmB_ln(const float* __restrict__ agg,
    const float* __restrict__ Wg, const float* __restrict__ bias,
    const float* __restrict__ isn, const float* __restrict__ hin,
    const float* __restrict__ g, const float* __restrict__ be,
    float* __restrict__ P, int nrows){
  __shared__ __align__(16) float Ws[64*68];
  int tid = threadIdx.x;
  #pragma unroll
  for (int i = 0; i < 16; ++i){ int e = tid + i*256; Ws[(e>>6)*68 + (e&63)] = Wg[e]; }
  __syncthreads();
  int lane = tid & 63, wv = tid >> 6;
  float bl = bias[lane], gl = g[lane], bel = be[lane];
  int r = blockIdx.x*4 + wv, stride = gridDim.x*4;
  for (; r < nrows; r += stride){
    float val = agg[r*64 + lane];
    float acc = 0.f;
    #pragma unroll
    for (int k = 0; k < 64; ++k) acc = fmaf(__shfl(val, k, 64), Ws[k*68 + lane], acc);
    float v = fmaf(acc, isn[r], bl) + hin[r*64 + lane];
    float mu, rs; wave_ln_stats(v, mu, rs);
    P[r*64 + lane] = fmaf((v - mu)*rs, gl, bel);
  }
}

// Convert fp32 weights to bf16 once per launch (all layers).
__global__ void k_cvtw(const float* __restrict__ W1, const float* __restrict__ W2,
                       unsigned short* __restrict__ W1b, unsigned short* __restrict__ W2b,
                       int n1, int n2){
  int st = gridDim.x*blockDim.x;
  for (int i = blockIdx.x*blockDim.x + threadIdx.x; i < n1; i += st) W1b[i] = f2bf(W1[i]);
  for (int i = blockIdx.x*blockDim.x + threadIdx.x; i < n2; i += st) W2b[i] = f2bf(W2[i]);
}

// Fused MFMA FFN: Out = LN( X + relu(X@W1+b1)@W2 + b2 , g, be )
// Block = 256 threads = 4 waves, 64 rows/block (16 rows/wave), bf16 MFMA 16x16x32.
// LDS: W1^T chunk [128 hidden][64+pad k], W2^T chunk [64 out][128+pad k],
//      per-wave H1 chunk [16 rows][32+pad k] for the C-layout -> A-layout transform.
__global__ __launch_bounds__(256) void k_ffn(
    const float* __restrict__ X,                 // N x 64 fp32 (A source + residual)
    const unsigned short* __restrict__ W1b,      // 64 x 256 bf16 (layer slice)
    const float* __restrict__ b1g,
    const unsigned short* __restrict__ W2b,      // 256 x 64 bf16 (layer slice)
    const float* __restrict__ b2g,
    const float* __restrict__ g, const float* __restrict__ be,
    float* __restrict__ Outp, int nrows)
{
  __shared__ unsigned short sW1T[128*72];    // [hidden_local][k] pad 72 (2-way banks: free)
  __shared__ unsigned short sW2T[64*136];    // [out_col][k_local] pad 136
  __shared__ unsigned short sHc[4*16*40];    // per-wave [row][k within 32-chunk] pad 40
  int tid = threadIdx.x;
  int lane = tid & 63, w = tid >> 6;
  int quad = lane >> 4, n16 = lane & 15;
  int rowbase = blockIdx.x*64 + w*16;

  // ---- A-frags for pass1 (K=64, 2 chunks of 32), convert fp32 -> bf16 in-register
  int arow = min(rowbase + n16, nrows-1);
  const float4* X4 = (const float4*)X;
  short8 a0, a1;
  {
    float4 u0 = X4[(size_t)arow*16 + quad*2];
    float4 u1 = X4[(size_t)arow*16 + quad*2 + 1];
    float4 u2 = X4[(size_t)arow*16 + 8 + quad*2];
    float4 u3 = X4[(size_t)arow*16 + 8 + quad*2 + 1];
    a0[0]=f2bf(u0.x); a0[1]=f2bf(u0.y); a0[2]=f2bf(u0.z); a0[3]=f2bf(u0.w);
    a0[4]=f2bf(u1.x); a0[5]=f2bf(u1.y); a0[6]=f2bf(u1.z); a0[7]=f2bf(u1.w);
    a1[0]=f2bf(u2.x); a1[1]=f2bf(u2.y); a1[2]=f2bf(u2.z); a1[3]=f2bf(u2.w);
    a1[4]=f2bf(u3.x); a1[5]=f2bf(u3.y); a1[6]=f2bf(u3.z); a1[7]=f2bf(u3.w);
  }

  floatx4 acc2[4];
  #pragma unroll
  for (int t = 0; t < 4; ++t) acc2[t] = (floatx4){0.f,0.f,0.f,0.f};

  unsigned short* myHc = &sHc[w*16*40];

  for (int hb = 0; hb < 2; ++hb){
    __syncthreads();
    // stage W1^T chunk: sW1T[nn][k] = W1[k][hb*128+nn]; vectorized ushort4 global reads
    #pragma unroll
    for (int i = 0; i < 8; ++i){
      int idx = i*256 + tid;           // 2048 quads of 4 -> 128x64
      int k = idx >> 5, nnb = (idx & 31)*4;
      ushort4v v = *(const ushort4v*)&W1b[k*256 + hb*128 + nnb];
      sW1T[(nnb+0)*72 + k] = v[0];
      sW1T[(nnb+1)*72 + k] = v[1];
      sW1T[(nnb+2)*72 + k] = v[2];
      sW1T[(nnb+3)*72 + k] = v[3];
    }
    // stage W2^T chunk: sW2T[o][kk] = W2[hb*128+kk][o]
    #pragma unroll
    for (int i = 0; i < 8; ++i){
      int idx = i*256 + tid;           // 2048 quads of 4 -> 128x64
      int kk = idx >> 4, ob = (idx & 15)*4;
      ushort4v v = *(const ushort4v*)&W2b[(hb*128 + kk)*64 + ob];
      sW2T[(ob+0)*136 + kk] = v[0];
      sW2T[(ob+1)*136 + kk] = v[1];
      sW2T[(ob+2)*136 + kk] = v[2];
      sW2T[(ob+3)*136 + kk] = v[3];
    }
    __syncthreads();

    // 4 chunks of 32 hidden: pass1 (2 n-tiles) -> relu -> LDS -> pass2 (4 out-tiles)
    for (int ck = 0; ck < 4; ++ck){
      #pragma unroll
      for (int nt = 0; nt < 2; ++nt){
        int nn = ck*32 + nt*16 + n16;          // hidden local within 128
        floatx4 c = (floatx4){0.f,0.f,0.f,0.f};
        short8 b0 = *(const short8*)&sW1T[nn*72 + quad*8];
        short8 b1f = *(const short8*)&sW1T[nn*72 + 32 + quad*8];
        c = __builtin_amdgcn_mfma_f32_16x16x32_bf16(a0, b0, c, 0, 0, 0);
        c = __builtin_amdgcn_mfma_f32_16x16x32_bf16(a1, b1f, c, 0, 0, 0);
        float bb = b1g[hb*128 + nn];
        #pragma unroll
        for (int r = 0; r < 4; ++r){
          float h = fmaxf(c[r] + bb, 0.f);
          myHc[(quad*4 + r)*40 + nt*16 + n16] = f2bf(h);
        }
      }
      // C-layout -> A-layout via per-wave LDS round trip (same-wave, lgkmcnt-ordered)
      short8 a2 = *(const short8*)&myHc[n16*40 + quad*8];
      #pragma unroll
      for (int ot = 0; ot < 4; ++ot){
        short8 b2f = *(const short8*)&sW2T[(ot*16 + n16)*136 + ck*32 + quad*8];
        acc2[ot] = __builtin_amdgcn_mfma_f32_16x16x32_bf16(a2, b2f, acc2[ot], 0, 0, 0);
      }
    }
  }

  // ---- epilogue: + b2 + residual X, then per-row LN (row = quad*4 + r)
  float pre[4][4];   // [ot][r]
  #pragma unroll
  for (int ot = 0; ot < 4; ++ot){
    float b2c = b2g[ot*16 + n16];
    #pragma unroll
    for (int r = 0; r < 4; ++r){
      int rr = min(rowbase + quad*4 + r, nrows-1);
      pre[ot][r] = acc2[ot][r] + b2c + X[(size_t)rr*64 + ot*16 + n16];
    }
  }
  float gl[4], bel[4];
  #pragma unroll
  for (int ot = 0; ot < 4; ++ot){ gl[ot] = g[ot*16 + n16]; bel[ot] = be[ot*16 + n16]; }
  #pragma unroll
  for (int r = 0; r < 4; ++r){
    float s = (pre[0][r] + pre[1][r]) + (pre[2][r] + pre[3][r]);
    float q = fmaf(pre[0][r], pre[0][r], pre[1][r]*pre[1][r]) +
              fmaf(pre[2][r], pre[2][r], pre[3][r]*pre[3][r]);
    #pragma unroll
    for (int o = 8; o >= 1; o >>= 1){
      s += __shfl_xor(s, o, 64);
      q += __shfl_xor(q, o, 64);
    }
    float mu = s*(1.f/64.f);
    float var = fmaf(-mu, mu, q*(1.f/64.f));
    float rs = rsqrtf(var + 1e-5f);
    int rr = rowbase + quad*4 + r;
    if (rr < nrows){
      #pragma unroll
      for (int ot = 0; ot < 4; ++ot)
        Outp[(size_t)rr*64 + ot*16 + n16] = fmaf((pre[ot][r]-mu)*rs, gl[ot], bel[ot]);
    }
  }
}

// out[n] = LN(Q[n], gF, bF) @ Wo + bo
__global__ __launch_bounds__(256) void k_final(const float* __restrict__ Q,
    const float* __restrict__ Wg, const float* __restrict__ bog,
    const float* __restrict__ gF, const float* __restrict__ bF,
    float* __restrict__ out, int nrows){
  __shared__ __align__(16) float Ws[64*68];
  int tid = threadIdx.x;
  #pragma unroll
  for (int i = 0; i < 16; ++i){ int e = tid + i*256; Ws[(e>>6)*68 + (e&63)] = Wg[e]; }
  __syncthreads();
  int lane = tid & 63, wv = tid >> 6;
  float gl = gF[lane], bl = bF[lane], bol = bog[lane];
  int r = blockIdx.x*4 + wv, stride = gridDim.x*4;
  for (; r < nrows; r += stride){
    float v = Q[r*64 + lane];
    float mu, rs; wave_ln_stats(v, mu, rs);
    float nv = fmaf((v - mu)*rs, gl, bl);
    float acc = 0.f;
    #pragma unroll
    for (int k = 0; k < 64; ++k) acc = fmaf(__shfl(nv, k, 64), Ws[k*68 + lane], acc);
    out[r*64 + lane] = acc + bol;
  }
}

extern "C" void kernel_launch(void* const* d_in, const int* in_sizes, int n_in,
                              void* d_out, int out_size, void* d_ws, size_t ws_size,
                              hipStream_t stream){
  const float* nf   = (const float*)d_in[0];
  const int*   esrc = (const int*)d_in[1];
  const int*   edst = (const int*)d_in[2];
  // d_in[3] = n_hyper scalar (device); H hardcoded from reference constants
  const float* Wn2h = (const float*)d_in[4];
  const float* bn2h = (const float*)d_in[5];
  const float* Wh2n = (const float*)d_in[6];
  const float* bh2n = (const float*)d_in[7];
  const float* W1   = (const float*)d_in[8];
  const float* b1   = (const float*)d_in[9];
  const float* W2   = (const float*)d_in[10];
  const float* b2   = (const float*)d_in[11];
  const float* g1   = (const float*)d_in[12];
  const float* be1  = (const float*)d_in[13];
  const float* g2   = (const float*)d_in[14];
  const float* be2  = (const float*)d_in[15];
  const float* gF   = (const float*)d_in[16];
  const float* bF   = (const float*)d_in[17];
  const float* Wo   = (const float*)d_in[18];
  const float* bo   = (const float*)d_in[19];
  const int N = in_sizes[0] / 64;
  const int E = in_sizes[1];
  const int H = HYP;
  float* out = (float*)d_out;

  char* w = (char*)d_ws;
  auto carve = [&](size_t bytes) -> char* {
    char* p = w; w += (bytes + 255) & ~(size_t)255; return p;
  };
  int* cnt_h = (int*)carve((size_t)H*4);
  int* cnt_n = (int*)carve((size_t)N*4);
  int* cur_h = (int*)carve((size_t)H*4);
  int* cur_n = (int*)carve((size_t)N*4);
  size_t zero_span = (size_t)(w - (char*)cnt_h);
  int*   off_h = (int*)carve((size_t)(H+1)*4);
  int*   off_n = (int*)carve((size_t)(N+1)*4);
  float* is_h  = (float*)carve((size_t)H*4);
  float* is_n  = (float*)carve((size_t)N*4);
  int*   csr_h = (int*)carve((size_t)E*4);
  int*   csr_n = (int*)carve((size_t)E*4);
  float* aggx  = (float*)carve((size_t)H*64*4);
  float* hhs   = (float*)carve((size_t)H*64*4);
  float* aggh  = (float*)carve((size_t)N*64*4);
  float* Pb    = (float*)carve((size_t)N*64*4);
  float* Qb    = (float*)carve((size_t)N*64*4);
  unsigned short* W1g16 = (unsigned short*)carve((size_t)NLAYER*64*256*2);
  unsigned short* W2g16 = (unsigned short*)carve((size_t)NLAYER*256*64*2);

  hipMemsetAsync(cnt_h, 0, zero_span, stream);
  k_count<<<2048, 256, 0, stream>>>(esrc, edst, E, cnt_n, cnt_h);
  k_cvtw<<<96, 256, 0, stream>>>(W1, W2, W1g16, W2g16, NLAYER*64*256, NLAYER*256*64);
  k_scan<<<1, 1024, 0, stream>>>(cnt_h, H, off_h, is_h);
  k_scan<<<1, 1024, 0, stream>>>(cnt_n, N, off_n, is_n);
  k_fill<<<2048, 256, 0, stream>>>(esrc, edst, E, off_h, cur_h, csr_h, off_n, cur_n, csr_n);

  for (int l = 0; l < NLAYER; ++l){
    const float* hin = (l == 0) ? nf : Qb;
    k_gather<true><<<2048, 256, 0, stream>>>(hin, csr_h, off_h, is_n, aggx, H);
    k_mmA<<<512, 256, 0, stream>>>(aggx, Wn2h + l*4096, bn2h + l*64, is_h, hhs, H);
    k_gather<false><<<2048, 256, 0, stream>>>(hhs, csr_n, off_n, nullptr, aggh, N);
    k_mmB_ln<<<1024, 256, 0, stream>>>(aggh, Wh2n + l*4096, bh2n + l*64, is_n, hin,
                                       g1 + l*64, be1 + l*64, Pb, N);
    k_ffn<<<(N + 63)/64, 256, 0, stream>>>(Pb, W1g16 + l*64*256, b1 + l*256,
                                           W2g16 + l*256*64, b2 + l*64,
                                           g2 + l*64, be2 + l*64, Qb, N);
  }
  k_final<<<1024, 256, 0, stream>>>(Qb, Wo, bo, gF, bF, out, N);
}

// Round 3
// 1260.093 us; speedup vs baseline: 1.5198x; 1.1237x over previous
//
#include <hip/hip_runtime.h>

// Problem constants (from reference): N=100000, H=20000, E=1600000, D=64, L=3, F=256
#define HYP 20000
#define NLAYER 3

typedef __attribute__((ext_vector_type(8))) short short8;
typedef __attribute__((ext_vector_type(4))) float floatx4;
typedef __attribute__((ext_vector_type(4))) unsigned short ushort4v;

static __device__ __forceinline__ unsigned short f2bf(float f){
  union { float f; unsigned u; } v; v.f = f;
  unsigned r = v.u + 0x7FFF + ((v.u >> 16) & 1);
  return (unsigned short)(r >> 16);
}

static __device__ __forceinline__ void wave_ln_stats(float v, float& mu, float& rs){
  float s = v, q = v*v;
  #pragma unroll
  for (int o = 32; o > 0; o >>= 1){
    s += __shfl_xor(s, o, 64);
    q += __shfl_xor(q, o, 64);
  }
  mu = s * (1.0f/64.0f);
  float var = fmaf(-mu, mu, q*(1.0f/64.0f));
  rs = rsqrtf(var + 1e-5f);
}

__global__ void k_count(const int* __restrict__ src, const int* __restrict__ dst, int E,
                        int* __restrict__ cnt_n, int* __restrict__ cnt_h){
  int i = blockIdx.x*blockDim.x + threadIdx.x;
  int st = gridDim.x*blockDim.x;
  for (; i < E; i += st){
    atomicAdd(&cnt_n[src[i]], 1);
    atomicAdd(&cnt_h[dst[i]], 1);
  }
}

// ---- 3-kernel parallel exclusive scan (cnt -> off, also emits rsqrt(max(deg,1))) ----
__global__ __launch_bounds__(256) void k_psum(const int* __restrict__ cnt, int n, int S,
                                              int* __restrict__ part){
  __shared__ int sm[4];
  int b = blockIdx.x, tid = threadIdx.x;
  int lane = tid & 63, wv = tid >> 6;
  int lo = b*S, hi = min(n, lo+S);
  int s = 0;
  for (int i = lo + tid; i < hi; i += 256) s += cnt[i];
  #pragma unroll
  for (int o = 32; o; o >>= 1) s += __shfl_xor(s, o, 64);
  if (lane == 0) sm[wv] = s;
  __syncthreads();
  if (tid == 0) part[b] = sm[0]+sm[1]+sm[2]+sm[3];
}

__global__ __launch_bounds__(256) void k_pscan(int* __restrict__ part, int nb,
                                               int* __restrict__ off_last){
  __shared__ int sm[4];
  int tid = threadIdx.x, lane = tid & 63, wv = tid >> 6;
  int v = (tid < nb) ? part[tid] : 0;
  int x = v;
  #pragma unroll
  for (int o = 1; o < 64; o <<= 1){ int t = __shfl_up(x, o, 64); if (lane >= o) x += t; }
  if (lane == 63) sm[wv] = x;
  __syncthreads();
  int add = 0;
  if (wv > 0) add = sm[0];
  if (wv > 1) add += sm[1];
  if (wv > 2) add += sm[2];
  int incl = x + add;
  if (tid < nb) part[tid] = incl - v;   // exclusive prefix
  if (tid == nb-1) *off_last = incl;    // grand total -> off[n]
}

__global__ __launch_bounds__(256) void k_poff(const int* __restrict__ cnt, int n, int S,
    const int* __restrict__ partx, int* __restrict__ off, float* __restrict__ isv){
  __shared__ int sm[4];
  int b = blockIdx.x, tid = threadIdx.x;
  int lane = tid & 63, wv = tid >> 6;
  int lo = b*S, hi = min(n, lo+S);
  int carry = partx[b];
  for (int base = lo; base < hi; base += 256){
    int i = base + tid;
    int v = (i < hi) ? cnt[i] : 0;
    int x = v;
    #pragma unroll
    for (int o = 1; o < 64; o <<= 1){ int t = __shfl_up(x, o, 64); if (lane >= o) x += t; }
    if (lane == 63) sm[wv] = x;
    __syncthreads();
    int add = 0;
    if (wv > 0) add = sm[0];
    if (wv > 1) add += sm[1];
    if (wv > 2) add += sm[2];
    int incl = x + add;
    if (i < hi){
      off[i] = carry + incl - v;
      isv[i] = rsqrtf((float)(v > 0 ? v : 1));
    }
    carry += sm[0]+sm[1]+sm[2]+sm[3];
    __syncthreads();
  }
}

// XCD-affine CSR fill: group g = blockIdx%8 scans the whole edge list (striped across
// its 256 blocks) and writes only ids in its 1/8 range -> write working set ~800KB,
// stays in one XCD's L2 so 64B lines fill completely before writeback.
__global__ void k_fill(const int* __restrict__ src, const int* __restrict__ dst,
    int E, int H, int N,
    const int* __restrict__ off_h, int* __restrict__ cur_h, int* __restrict__ csr_h,
    const int* __restrict__ off_n, int* __restrict__ cur_n, int* __restrict__ csr_n){
  int grp = blockIdx.x & 7;
  int nstripe = gridDim.x >> 3;
  int sid = blockIdx.x >> 3;
  int Hc = (H + 7) >> 3, Nc = (N + 7) >> 3;
  int h_lo = grp * Hc, h_hi = min(H, h_lo + Hc);
  int n_lo = grp * Nc, n_hi = min(N, n_lo + Nc);
  int i = sid*blockDim.x + threadIdx.x;
  int st = nstripe*blockDim.x;
  for (; i < E; i += st){
    int s = src[i], d = dst[i];
    if (d >= h_lo && d < h_hi){
      int p = atomicAdd(&cur_h[d], 1);
      csr_h[off_h[d] + p] = s;
    }
    if (s >= n_lo && s < n_hi){
      int q = atomicAdd(&cur_n[s], 1);
      csr_n[off_n[s] + q] = d;
    }
  }
}

// Pre-scale + bf16-convert node features for layer-0 h-gather: xb[i] = bf16(x[i]*isn[row])
__global__ void k_prescale(const float* __restrict__ x, const float* __restrict__ isn,
                           unsigned short* __restrict__ xb, int nrows){
  int i = blockIdx.x*blockDim.x + threadIdx.x;
  int st = gridDim.x*blockDim.x;
  int tot = nrows*64;
  for (; i < tot; i += st){ xb[i] = f2bf(x[i]*isn[i >> 6]); }
}

// One wave per destination row over bf16 pre-scaled features; half-waves take
// alternating edges (4B/lane coalesced), fp32 accumulate, combine via shfl_xor(32).
__global__ __launch_bounds__(256) void k_gatherb(const unsigned short* __restrict__ feat,
    const int* __restrict__ csr, const int* __restrict__ off,
    float* __restrict__ agg, int nrows){
  int lane = threadIdx.x & 63, wv = threadIdx.x >> 6;
  int half = lane >> 5, c = lane & 31;
  int r = blockIdx.x*4 + wv;
  int stride = gridDim.x*4;
  for (; r < nrows; r += stride){
    int b = off[r], e = off[r+1];
    float ax = 0.f, ay = 0.f;
    int t = b;
    for (; t + 4 <= e; t += 4){
      int sA = csr[t + half];
      int sB = csr[t + 2 + half];
      unsigned vA = *(const unsigned*)&feat[(size_t)sA*64 + c*2];
      unsigned vB = *(const unsigned*)&feat[(size_t)sB*64 + c*2];
      ax += __uint_as_float(vA << 16) + __uint_as_float(vB << 16);
      ay += __uint_as_float(vA & 0xFFFF0000u) + __uint_as_float(vB & 0xFFFF0000u);
    }
    for (; t + 2 <= e; t += 2){
      int s = csr[t + half];
      unsigned v = *(const unsigned*)&feat[(size_t)s*64 + c*2];
      ax += __uint_as_float(v << 16);
      ay += __uint_as_float(v & 0xFFFF0000u);
    }
    if (t < e && half == 0){
      int s = csr[t];
      unsigned v = *(const unsigned*)&feat[(size_t)s*64 + c*2];
      ax += __uint_as_float(v << 16);
      ay += __uint_as_float(v & 0xFFFF0000u);
    }
    ax += __shfl_xor(ax, 32, 64);
    ay += __shfl_xor(ay, 32, 64);
    if (half == 0){
      float2 o; o.x = ax; o.y = ay;
      *(float2*)&agg[(size_t)r*64 + c*2] = o;
    }
  }
}

// hhs_scaled[j] = bf16( ((aggx[j] @ W) * is_hyp + b) * is_hyp )
__global__ __launch_bounds__(256) void k_mmA(const float* __restrict__ agg,
    const float* __restrict__ Wg, const float* __restrict__ bias,
    const float* __restrict__ ihy, unsigned short* __restrict__ ouths, int nrows){
  __shared__ __align__(16) float Ws[64*68];
  int tid = threadIdx.x;
  #pragma unroll
  for (int i = 0; i < 16; ++i){ int e = tid + i*256; Ws[(e>>6)*68 + (e&63)] = Wg[e]; }
  __syncthreads();
  int lane = tid & 63, wv = tid >> 6;
  float bl = bias[lane];
  int r = blockIdx.x*4 + wv, stride = gridDim.x*4;
  for (; r < nrows; r += stride){
    float val = agg[r*64 + lane];
    float acc = 0.f;
    #pragma unroll
    for (int k = 0; k < 64; ++k) acc = fmaf(__shfl(val, k, 64), Ws[k*68 + lane], acc);
    float ih = ihy[r];
    ouths[r*64 + lane] = f2bf(fmaf(acc, ih, bl) * ih);
  }
}

// P[n] = LN( hin[n] + (aggh[n] @ W)*is_node[n] + b , g, be )
__global__ __launch_bounds__(256) void k_mmB_ln(const float* __restrict__ agg,
    const float* __restrict__ Wg, const float* __restrict__ bias,
    const float* __restrict__ isn, const float* __restrict__ hin,
    const float* __restrict__ g, const float* __restrict__ be,
    float* __restrict__ P, int nrows){
  __shared__ __align__(16) float Ws[64*68];
  int tid = threadIdx.x;
  #pragma unroll
  for (int i = 0; i < 16; ++i){ int e = tid + i*256; Ws[(e>>6)*68 + (e&63)] = Wg[e]; }
  __syncthreads();
  int lane = tid & 63, wv = tid >> 6;
  float bl = bias[lane], gl = g[lane], bel = be[lane];
  int r = blockIdx.x*4 + wv, stride = gridDim.x*4;
  for (; r < nrows; r += stride){
    float val = agg[r*64 + lane];
    float acc = 0.f;
    #pragma unroll
    for (int k = 0; k < 64; ++k) acc = fmaf(__shfl(val, k, 64), Ws[k*68 + lane], acc);
    float v = fmaf(acc, isn[r], bl) + hin[r*64 + lane];
    float mu, rs; wave_ln_stats(v, mu, rs);
    P[r*64 + lane] = fmaf((v - mu)*rs, gl, bel);
  }
}

// Convert fp32 weights to bf16 once per launch (all layers).
__global__ void k_cvtw(const float* __restrict__ W1, const float* __restrict__ W2,
                       unsigned short* __restrict__ W1b, unsigned short* __restrict__ W2b,
                       int n1, int n2){
  int st = gridDim.x*blockDim.x;
  for (int i = blockIdx.x*blockDim.x + threadIdx.x; i < n1; i += st) W1b[i] = f2bf(W1[i]);
  for (int i = blockIdx.x*blockDim.x + threadIdx.x; i < n2; i += st) W2b[i] = f2bf(W2[i]);
}

// Fused MFMA FFN: Out = LN( X + relu(X@W1+b1)@W2 + b2 , g, be ); also emits
// Qs = bf16(Out * is_n) for the next layer's h-gather.
__global__ __launch_bounds__(256) void k_ffn(
    const float* __restrict__ X,
    const unsigned short* __restrict__ W1b,
    const float* __restrict__ b1g,
    const unsigned short* __restrict__ W2b,
    const float* __restrict__ b2g,
    const float* __restrict__ g, const float* __restrict__ be,
    const float* __restrict__ isn,
    float* __restrict__ Outp, unsigned short* __restrict__ Qs, int nrows)
{
  __shared__ unsigned short sW1T[128*72];
  __shared__ unsigned short sW2T[64*136];
  __shared__ unsigned short sHc[4*16*40];
  int tid = threadIdx.x;
  int lane = tid & 63, w = tid >> 6;
  int quad = lane >> 4, n16 = lane & 15;
  int rowbase = blockIdx.x*64 + w*16;

  int arow = min(rowbase + n16, nrows-1);
  const float4* X4 = (const float4*)X;
  short8 a0, a1;
  {
    float4 u0 = X4[(size_t)arow*16 + quad*2];
    float4 u1 = X4[(size_t)arow*16 + quad*2 + 1];
    float4 u2 = X4[(size_t)arow*16 + 8 + quad*2];
    float4 u3 = X4[(size_t)arow*16 + 8 + quad*2 + 1];
    a0[0]=f2bf(u0.x); a0[1]=f2bf(u0.y); a0[2]=f2bf(u0.z); a0[3]=f2bf(u0.w);
    a0[4]=f2bf(u1.x); a0[5]=f2bf(u1.y); a0[6]=f2bf(u1.z); a0[7]=f2bf(u1.w);
    a1[0]=f2bf(u2.x); a1[1]=f2bf(u2.y); a1[2]=f2bf(u2.z); a1[3]=f2bf(u2.w);
    a1[4]=f2bf(u3.x); a1[5]=f2bf(u3.y); a1[6]=f2bf(u3.z); a1[7]=f2bf(u3.w);
  }

  floatx4 acc2[4];
  #pragma unroll
  for (int t = 0; t < 4; ++t) acc2[t] = (floatx4){0.f,0.f,0.f,0.f};

  unsigned short* myHc = &sHc[w*16*40];

  for (int hb = 0; hb < 2; ++hb){
    __syncthreads();
    #pragma unroll
    for (int i = 0; i < 8; ++i){
      int idx = i*256 + tid;
      int k = idx >> 5, nnb = (idx & 31)*4;
      ushort4v v = *(const ushort4v*)&W1b[k*256 + hb*128 + nnb];
      sW1T[(nnb+0)*72 + k] = v[0];
      sW1T[(nnb+1)*72 + k] = v[1];
      sW1T[(nnb+2)*72 + k] = v[2];
      sW1T[(nnb+3)*72 + k] = v[3];
    }
    #pragma unroll
    for (int i = 0; i < 8; ++i){
      int idx = i*256 + tid;
      int kk = idx >> 4, ob = (idx & 15)*4;
      ushort4v v = *(const ushort4v*)&W2b[(hb*128 + kk)*64 + ob];
      sW2T[(ob+0)*136 + kk] = v[0];
      sW2T[(ob+1)*136 + kk] = v[1];
      sW2T[(ob+2)*136 + kk] = v[2];
      sW2T[(ob+3)*136 + kk] = v[3];
    }
    __syncthreads();

    for (int ck = 0; ck < 4; ++ck){
      #pragma unroll
      for (int nt = 0; nt < 2; ++nt){
        int nn = ck*32 + nt*16 + n16;
        floatx4 c = (floatx4){0.f,0.f,0.f,0.f};
        short8 b0 = *(const short8*)&sW1T[nn*72 + quad*8];
        short8 b1f = *(const short8*)&sW1T[nn*72 + 32 + quad*8];
        c = __builtin_amdgcn_mfma_f32_16x16x32_bf16(a0, b0, c, 0, 0, 0);
        c = __builtin_amdgcn_mfma_f32_16x16x32_bf16(a1, b1f, c, 0, 0, 0);
        float bb = b1g[hb*128 + nn];
        #pragma unroll
        for (int r = 0; r < 4; ++r){
          float h = fmaxf(c[r] + bb, 0.f);
          myHc[(quad*4 + r)*40 + nt*16 + n16] = f2bf(h);
        }
      }
      short8 a2 = *(const short8*)&myHc[n16*40 + quad*8];
      #pragma unroll
      for (int ot = 0; ot < 4; ++ot){
        short8 b2f = *(const short8*)&sW2T[(ot*16 + n16)*136 + ck*32 + quad*8];
        acc2[ot] = __builtin_amdgcn_mfma_f32_16x16x32_bf16(a2, b2f, acc2[ot], 0, 0, 0);
      }
    }
  }

  float pre[4][4];
  #pragma unroll
  for (int ot = 0; ot < 4; ++ot){
    float b2c = b2g[ot*16 + n16];
    #pragma unroll
    for (int r = 0; r < 4; ++r){
      int rr = min(rowbase + quad*4 + r, nrows-1);
      pre[ot][r] = acc2[ot][r] + b2c + X[(size_t)rr*64 + ot*16 + n16];
    }
  }
  float gl[4], bel[4];
  #pragma unroll
  for (int ot = 0; ot < 4; ++ot){ gl[ot] = g[ot*16 + n16]; bel[ot] = be[ot*16 + n16]; }
  #pragma unroll
  for (int r = 0; r < 4; ++r){
    float s = (pre[0][r] + pre[1][r]) + (pre[2][r] + pre[3][r]);
    float q = fmaf(pre[0][r], pre[0][r], pre[1][r]*pre[1][r]) +
              fmaf(pre[2][r], pre[2][r], pre[3][r]*pre[3][r]);
    #pragma unroll
    for (int o = 8; o >= 1; o >>= 1){
      s += __shfl_xor(s, o, 64);
      q += __shfl_xor(q, o, 64);
    }
    float mu = s*(1.f/64.f);
    float var = fmaf(-mu, mu, q*(1.f/64.f));
    float rs = rsqrtf(var + 1e-5f);
    int rr = rowbase + quad*4 + r;
    if (rr < nrows){
      float isr = isn[rr];
      #pragma unroll
      for (int ot = 0; ot < 4; ++ot){
        float ov = fmaf((pre[ot][r]-mu)*rs, gl[ot], bel[ot]);
        Outp[(size_t)rr*64 + ot*16 + n16] = ov;
        Qs[(size_t)rr*64 + ot*16 + n16] = f2bf(ov * isr);
      }
    }
  }
}

// out[n] = LN(Q[n], gF, bF) @ Wo + bo
__global__ __launch_bounds__(256) void k_final(const float* __restrict__ Q,
    const float* __restrict__ Wg, const float* __restrict__ bog,
    const float* __restrict__ gF, const float* __restrict__ bF,
    float* __restrict__ out, int nrows){
  __shared__ __align__(16) float Ws[64*68];
  int tid = threadIdx.x;
  #pragma unroll
  for (int i = 0; i < 16; ++i){ int e = tid + i*256; Ws[(e>>6)*68 + (e&63)] = Wg[e]; }
  __syncthreads();
  int lane = tid & 63, wv = tid >> 6;
  float gl = gF[lane], bl = bF[lane], bol = bog[lane];
  int r = blockIdx.x*4 + wv, stride = gridDim.x*4;
  for (; r < nrows; r += stride){
    float v = Q[r*64 + lane];
    float mu, rs; wave_ln_stats(v, mu, rs);
    float nv = fmaf((v - mu)*rs, gl, bl);
    float acc = 0.f;
    #pragma unroll
    for (int k = 0; k < 64; ++k) acc = fmaf(__shfl(nv, k, 64), Ws[k*68 + lane], acc);
    out[r*64 + lane] = acc + bol;
  }
}

extern "C" void kernel_launch(void* const* d_in, const int* in_sizes, int n_in,
                              void* d_out, int out_size, void* d_ws, size_t ws_size,
                              hipStream_t stream){
  const float* nf   = (const float*)d_in[0];
  const int*   esrc = (const int*)d_in[1];
  const int*   edst = (const int*)d_in[2];
  const float* Wn2h = (const float*)d_in[4];
  const float* bn2h = (const float*)d_in[5];
  const float* Wh2n = (const float*)d_in[6];
  const float* bh2n = (const float*)d_in[7];
  const float* W1   = (const float*)d_in[8];
  const float* b1   = (const float*)d_in[9];
  const float* W2   = (const float*)d_in[10];
  const float* b2   = (const float*)d_in[11];
  const float* g1   = (const float*)d_in[12];
  const float* be1  = (const float*)d_in[13];
  const float* g2   = (const float*)d_in[14];
  const float* be2  = (const float*)d_in[15];
  const float* gF   = (const float*)d_in[16];
  const float* bF   = (const float*)d_in[17];
  const float* Wo   = (const float*)d_in[18];
  const float* bo   = (const float*)d_in[19];
  const int N = in_sizes[0] / 64;
  const int E = in_sizes[1];
  const int H = HYP;
  float* out = (float*)d_out;

  char* w = (char*)d_ws;
  auto carve = [&](size_t bytes) -> char* {
    char* p = w; w += (bytes + 255) & ~(size_t)255; return p;
  };
  int* cnt_h = (int*)carve((size_t)H*4);
  int* cnt_n = (int*)carve((size_t)N*4);
  int* cur_h = (int*)carve((size_t)H*4);
  int* cur_n = (int*)carve((size_t)N*4);
  size_t zero_span = (size_t)(w - (char*)cnt_h);
  int*   off_h = (int*)carve((size_t)(H+1)*4);
  int*   off_n = (int*)carve((size_t)(N+1)*4);
  float* is_h  = (float*)carve((size_t)H*4);
  float* is_n  = (float*)carve((size_t)N*4);
  int*   csr_h = (int*)carve((size_t)E*4);
  int*   csr_n = (int*)carve((size_t)E*4);
  float* aggx  = (float*)carve((size_t)H*64*4);
  float* aggh  = (float*)carve((size_t)N*64*4);
  float* Pb    = (float*)carve((size_t)N*64*4);
  float* Qb    = (float*)carve((size_t)N*64*4);
  unsigned short* hhsb = (unsigned short*)carve((size_t)H*64*2);
  unsigned short* xb0  = (unsigned short*)carve((size_t)N*64*2);
  unsigned short* Qs   = (unsigned short*)carve((size_t)N*64*2);
  unsigned short* W1g16 = (unsigned short*)carve((size_t)NLAYER*64*256*2);
  unsigned short* W2g16 = (unsigned short*)carve((size_t)NLAYER*256*64*2);
  int* part_h = (int*)carve(256*4);
  int* part_n = (int*)carve(256*4);

  const int S_h = (H + 255) / 256;
  const int S_n = (N + 255) / 256;

  hipMemsetAsync(cnt_h, 0, zero_span, stream);
  k_count<<<2048, 256, 0, stream>>>(esrc, edst, E, cnt_n, cnt_h);
  k_cvtw<<<96, 256, 0, stream>>>(W1, W2, W1g16, W2g16, NLAYER*64*256, NLAYER*256*64);
  k_psum<<<256, 256, 0, stream>>>(cnt_h, H, S_h, part_h);
  k_pscan<<<1, 256, 0, stream>>>(part_h, 256, off_h + H);
  k_poff<<<256, 256, 0, stream>>>(cnt_h, H, S_h, part_h, off_h, is_h);
  k_psum<<<256, 256, 0, stream>>>(cnt_n, N, S_n, part_n);
  k_pscan<<<1, 256, 0, stream>>>(part_n, 256, off_n + N);
  k_poff<<<256, 256, 0, stream>>>(cnt_n, N, S_n, part_n, off_n, is_n);
  k_fill<<<2048, 256, 0, stream>>>(esrc, edst, E, H, N, off_h, cur_h, csr_h,
                                   off_n, cur_n, csr_n);
  k_prescale<<<4096, 256, 0, stream>>>(nf, is_n, xb0, N);

  for (int l = 0; l < NLAYER; ++l){
    const float* hin = (l == 0) ? nf : Qb;
    const unsigned short* hsrc = (l == 0) ? xb0 : Qs;
    k_gatherb<<<2048, 256, 0, stream>>>(hsrc, csr_h, off_h, aggx, H);
    k_mmA<<<512, 256, 0, stream>>>(aggx, Wn2h + l*4096, bn2h + l*64, is_h, hhsb, H);
    k_gatherb<<<2048, 256, 0, stream>>>(hhsb, csr_n, off_n, aggh, N);
    k_mmB_ln<<<1024, 256, 0, stream>>>(aggh, Wh2n + l*4096, bh2n + l*64, is_n, hin,
                                       g1 + l*64, be1 + l*64, Pb, N);
    k_ffn<<<(N + 63)/64, 256, 0, stream>>>(Pb, W1g16 + l*64*256, b1 + l*256,
                                           W2g16 + l*256*64, b2 + l*64,
                                           g2 + l*64, be2 + l*64, is_n, Qb, Qs, N);
  }
  k_final<<<1024, 256, 0, stream>>>(Qb, Wo, bo, gF, bF, out, N);
}

// Round 4
// 982.642 us; speedup vs baseline: 1.9489x; 1.2824x over previous
//
#include <hip/hip_runtime.h>

// Problem constants (from reference): N=100000, H=20000, E=1600000, D=64, L=3, F=256
#define HYP 20000
#define NLAYER 3
// Bucket-sort geometry: ids fit 15 bits (H=20000) / 17 bits (N=100000).
// h entry = (d<<17)|s, bucket = entry>>23 (= d>>6, 64 ids/bucket, 313 buckets)
// n entry = (s<<15)|d, bucket = entry>>23 (= s>>8, 256 ids/bucket, 391 buckets)
#define NB_H 313
#define NB_N 391
#define PT 4096

typedef __attribute__((ext_vector_type(8))) short short8;
typedef __attribute__((ext_vector_type(4))) float floatx4;
typedef __attribute__((ext_vector_type(4))) unsigned short ushort4v;

static __device__ __forceinline__ unsigned short f2bf(float f){
  union { float f; unsigned u; } v; v.f = f;
  unsigned r = v.u + 0x7FFF + ((v.u >> 16) & 1);
  return (unsigned short)(r >> 16);
}

static __device__ __forceinline__ void wave_ln_stats(float v, float& mu, float& rs){
  float s = v, q = v*v;
  #pragma unroll
  for (int o = 32; o > 0; o >>= 1){
    s += __shfl_xor(s, o, 64);
    q += __shfl_xor(q, o, 64);
  }
  mu = s * (1.0f/64.0f);
  float var = fmaf(-mu, mu, q*(1.0f/64.0f));
  rs = rsqrtf(var + 1e-5f);
}

// ---- CSR build, stage 1: global bucket histogram (LDS-staged) ----
__global__ __launch_bounds__(256) void k_hist(const int* __restrict__ src,
    const int* __restrict__ dst, int E, int* __restrict__ bh, int* __restrict__ bn){
  __shared__ int lh[NB_H + NB_N];
  int tid = threadIdx.x;
  for (int i = tid; i < NB_H + NB_N; i += 256) lh[i] = 0;
  __syncthreads();
  for (int i = blockIdx.x*256 + tid; i < E; i += gridDim.x*256){
    atomicAdd(&lh[dst[i] >> 6], 1);
    atomicAdd(&lh[NB_H + (src[i] >> 8)], 1);
  }
  __syncthreads();
  for (int i = tid; i < NB_H; i += 256) if (lh[i]) atomicAdd(&bh[i], lh[i]);
  for (int i = tid; i < NB_N; i += 256) if (lh[NB_H+i]) atomicAdd(&bn[i], lh[NB_H+i]);
}

// ---- stage 2: exclusive scan of bucket counts -> bucket starts + cursors ----
__global__ __launch_bounds__(256) void k_bscan(const int* __restrict__ bh,
    const int* __restrict__ bn, int* __restrict__ bstart_h, int* __restrict__ gcur_h,
    int* __restrict__ bstart_n, int* __restrict__ gcur_n){
  __shared__ int ssc[4];
  __shared__ int scarry;
  int tid = threadIdx.x, lane = tid & 63, wv = tid >> 6;
  if (tid == 0) scarry = 0;
  __syncthreads();
  for (int base = 0; base < NB_H; base += 256){
    int i = base + tid; int v = (i < NB_H) ? bh[i] : 0; int x = v;
    #pragma unroll
    for (int o = 1; o < 64; o <<= 1){ int t = __shfl_up(x,o,64); if (lane >= o) x += t; }
    if (lane == 63) ssc[wv] = x;
    __syncthreads();
    int add = (wv>0?ssc[0]:0)+(wv>1?ssc[1]:0)+(wv>2?ssc[2]:0);
    int c = scarry;
    if (i < NB_H){ int ex = c + add + x - v; bstart_h[i] = ex; gcur_h[i] = ex; }
    __syncthreads();
    if (tid == 255) scarry = c + ssc[0]+ssc[1]+ssc[2]+ssc[3];
    __syncthreads();
  }
  if (tid == 0){ bstart_h[NB_H] = scarry; scarry = 0; }
  __syncthreads();
  for (int base = 0; base < NB_N; base += 256){
    int i = base + tid; int v = (i < NB_N) ? bn[i] : 0; int x = v;
    #pragma unroll
    for (int o = 1; o < 64; o <<= 1){ int t = __shfl_up(x,o,64); if (lane >= o) x += t; }
    if (lane == 63) ssc[wv] = x;
    __syncthreads();
    int add = (wv>0?ssc[0]:0)+(wv>1?ssc[1]:0)+(wv>2?ssc[2]:0);
    int c = scarry;
    if (i < NB_N){ int ex = c + add + x - v; bstart_n[i] = ex; gcur_n[i] = ex; }
    __syncthreads();
    if (tid == 255) scarry = c + ssc[0]+ssc[1]+ssc[2]+ssc[3];
    __syncthreads();
  }
  if (tid == 0) bstart_n[NB_N] = scarry;
}

// ---- stage 3: LDS-staged radix partition into bucket-contiguous entry buffer ----
__global__ __launch_bounds__(256) void k_partition(const int* __restrict__ keys,
    const int* __restrict__ pays, int E, int keyshift, int nb,
    int* __restrict__ gcur, unsigned* __restrict__ Ebuf){
  __shared__ unsigned sst[PT];
  __shared__ int lh[NB_N], lpre[NB_N], gb[NB_N];
  __shared__ int ssc[4];
  __shared__ int scarry;
  int tid = threadIdx.x, lane = tid & 63, wv = tid >> 6;
  int base = blockIdx.x*PT;
  int m = min(PT, E - base);
  for (int i = tid; i < nb; i += 256) lh[i] = 0;
  if (tid == 0) scarry = 0;
  __syncthreads();
  unsigned en[16]; int rk[16];
  #pragma unroll
  for (int j = 0; j < 16; ++j){
    int i = base + j*256 + tid;
    if (i < E){
      unsigned k = (unsigned)keys[i], p = (unsigned)pays[i];
      en[j] = (k << keyshift) | p;
      rk[j] = atomicAdd(&lh[en[j] >> 23], 1);
    } else { en[j] = 0; rk[j] = -1; }
  }
  __syncthreads();
  for (int b2 = 0; b2 < nb; b2 += 256){
    int i = b2 + tid; int v = (i < nb) ? lh[i] : 0; int x = v;
    #pragma unroll
    for (int o = 1; o < 64; o <<= 1){ int t = __shfl_up(x,o,64); if (lane >= o) x += t; }
    if (lane == 63) ssc[wv] = x;
    __syncthreads();
    int add = (wv>0?ssc[0]:0)+(wv>1?ssc[1]:0)+(wv>2?ssc[2]:0);
    int c = scarry;
    if (i < nb) lpre[i] = c + add + x - v;
    __syncthreads();
    if (tid == 255) scarry = c + ssc[0]+ssc[1]+ssc[2]+ssc[3];
    __syncthreads();
  }
  for (int i = tid; i < nb; i += 256) gb[i] = atomicAdd(&gcur[i], lh[i]);
  #pragma unroll
  for (int j = 0; j < 16; ++j){
    if (rk[j] >= 0){
      int bk = en[j] >> 23;
      sst[lpre[bk] + rk[j]] = en[j];
    }
  }
  __syncthreads();
  for (int j = tid; j < m; j += 256){
    unsigned e = sst[j];
    int bk = e >> 23;
    Ebuf[gb[bk] + (j - lpre[bk])] = e;
  }
}

// ---- stage 4: per-bucket CSR build (one block owns one bucket's KB-scale window) ----
__global__ __launch_bounds__(256) void k_build(const unsigned* __restrict__ Ebuf,
    const int* __restrict__ bstart, int keyshift, int ipb, int paymask, int limit,
    int* __restrict__ off, float* __restrict__ isv, int* __restrict__ csr){
  __shared__ int lcnt[256], lpre2[256], lcur[256];
  int tid = threadIdx.x, lane = tid & 63, wv = tid >> 6;
  int b = blockIdx.x;
  int base = bstart[b], m = bstart[b+1] - base;
  for (int i = tid; i < ipb; i += 256) lcnt[i] = 0;
  __syncthreads();
  for (int i = tid; i < m; i += 256){
    unsigned e = Ebuf[base + i];
    atomicAdd(&lcnt[(e >> keyshift) & (ipb-1)], 1);
  }
  __syncthreads();
  if (wv == 0){
    int carry = 0;
    for (int c = 0; c < ipb; c += 64){
      int li = c + lane;
      int v = lcnt[li]; int x = v;
      #pragma unroll
      for (int o = 1; o < 64; o <<= 1){ int t = __shfl_up(x,o,64); if (lane >= o) x += t; }
      int ex = carry + x - v;
      int id = b*ipb + li;
      if (id <= limit) off[id] = base + ex;
      if (id < limit) isv[id] = rsqrtf((float)(v > 0 ? v : 1));
      lpre2[li] = ex;
      carry += __shfl(x, 63, 64);
    }
  }
  for (int i = tid; i < ipb; i += 256) lcur[i] = 0;
  __syncthreads();
  for (int i = tid; i < m; i += 256){
    unsigned e = Ebuf[base + i];
    int li = (e >> keyshift) & (ipb-1);
    int pos = base + lpre2[li] + atomicAdd(&lcur[li], 1);
    csr[pos] = (int)(e & (unsigned)paymask);
  }
}

// Pre-scale + bf16-convert node features for layer-0 h-gather
__global__ void k_prescale(const float* __restrict__ x, const float* __restrict__ isn,
                           unsigned short* __restrict__ xb, int nrows){
  int i = blockIdx.x*blockDim.x + threadIdx.x;
  int st = gridDim.x*blockDim.x;
  int tot = nrows*64;
  for (; i < tot; i += st){ xb[i] = f2bf(x[i]*isn[i >> 6]); }
}

// Gather: wave per row, 8 edges per VMEM inst (lane loads uint4 = 8 bf16 channels
// of edge slot lane>>3), fp32 accumulate, butterfly-combine the 8 edge slots.
__global__ __launch_bounds__(256) void k_gather8(const unsigned short* __restrict__ feat,
    const int* __restrict__ csr, const int* __restrict__ off,
    float* __restrict__ agg, int nrows){
  int lane = threadIdx.x & 63, wvi = threadIdx.x >> 6;
  int g = lane >> 3;
  int ch = (lane & 7) * 8;
  int r = blockIdx.x*4 + wvi, stride = gridDim.x*4;
  for (; r < nrows; r += stride){
    int b = off[r], e = off[r+1];
    float a0=0,a1=0,a2=0,a3=0,a4=0,a5=0,a6=0,a7=0;
    for (int t = b; t < e; t += 8){
      int idx = t + g;
      bool valid = idx < e;
      int s = csr[valid ? idx : b];
      uint4 u = *(const uint4*)&feat[(size_t)s*64 + ch];
      if (!valid){ u.x = 0; u.y = 0; u.z = 0; u.w = 0; }
      a0 += __uint_as_float(u.x << 16); a1 += __uint_as_float(u.x & 0xFFFF0000u);
      a2 += __uint_as_float(u.y << 16); a3 += __uint_as_float(u.y & 0xFFFF0000u);
      a4 += __uint_as_float(u.z << 16); a5 += __uint_as_float(u.z & 0xFFFF0000u);
      a6 += __uint_as_float(u.w << 16); a7 += __uint_as_float(u.w & 0xFFFF0000u);
    }
    #pragma unroll
    for (int o = 8; o <= 32; o <<= 1){
      a0 += __shfl_xor(a0,o,64); a1 += __shfl_xor(a1,o,64);
      a2 += __shfl_xor(a2,o,64); a3 += __shfl_xor(a3,o,64);
      a4 += __shfl_xor(a4,o,64); a5 += __shfl_xor(a5,o,64);
      a6 += __shfl_xor(a6,o,64); a7 += __shfl_xor(a7,o,64);
    }
    if (g == 0){
      float4 w0; w0.x=a0; w0.y=a1; w0.z=a2; w0.w=a3;
      float4 w1; w1.x=a4; w1.y=a5; w1.z=a6; w1.w=a7;
      *(float4*)&agg[(size_t)r*64 + ch] = w0;
      *(float4*)&agg[(size_t)r*64 + ch + 4] = w1;
    }
  }
}

// hhs_scaled[j] = bf16( ((aggx[j] @ W) * is_hyp + b) * is_hyp )
__global__ __launch_bounds__(256) void k_mmA(const float* __restrict__ agg,
    const float* __restrict__ Wg, const float* __restrict__ bias,
    const float* __restrict__ ihy, unsigned short* __restrict__ ouths, int nrows){
  __shared__ __align__(16) float Ws[64*68];
  int tid = threadIdx.x;
  #pragma unroll
  for (int i = 0; i < 16; ++i){ int e = tid + i*256; Ws[(e>>6)*68 + (e&63)] = Wg[e]; }
  __syncthreads();
  int lane = tid & 63, wv = tid >> 6;
  float bl = bias[lane];
  int r = blockIdx.x*4 + wv, stride = gridDim.x*4;
  for (; r < nrows; r += stride){
    float val = agg[r*64 + lane];
    float acc = 0.f;
    #pragma unroll
    for (int k = 0; k < 64; ++k) acc = fmaf(__shfl(val, k, 64), Ws[k*68 + lane], acc);
    float ih = ihy[r];
    ouths[r*64 + lane] = f2bf(fmaf(acc, ih, bl) * ih);
  }
}

// P[n] = LN( hin[n] + (aggh[n] @ W)*is_node[n] + b , g, be )
__global__ __launch_bounds__(256) void k_mmB_ln(const float* __restrict__ agg,
    const float* __restrict__ Wg, const float* __restrict__ bias,
    const float* __restrict__ isn, const float* __restrict__ hin,
    const float* __restrict__ g, const float* __restrict__ be,
    float* __restrict__ P, int nrows){
  __shared__ __align__(16) float Ws[64*68];
  int tid = threadIdx.x;
  #pragma unroll
  for (int i = 0; i < 16; ++i){ int e = tid + i*256; Ws[(e>>6)*68 + (e&63)] = Wg[e]; }
  __syncthreads();
  int lane = tid & 63, wv = tid >> 6;
  float bl = bias[lane], gl = g[lane], bel = be[lane];
  int r = blockIdx.x*4 + wv, stride = gridDim.x*4;
  for (; r < nrows; r += stride){
    float val = agg[r*64 + lane];
    float acc = 0.f;
    #pragma unroll
    for (int k = 0; k < 64; ++k) acc = fmaf(__shfl(val, k, 64), Ws[k*68 + lane], acc);
    float v = fmaf(acc, isn[r], bl) + hin[r*64 + lane];
    float mu, rs; wave_ln_stats(v, mu, rs);
    P[r*64 + lane] = fmaf((v - mu)*rs, gl, bel);
  }
}

// Convert fp32 weights to bf16 once per launch (all layers).
__global__ void k_cvtw(const float* __restrict__ W1, const float* __restrict__ W2,
                       unsigned short* __restrict__ W1b, unsigned short* __restrict__ W2b,
                       int n1, int n2){
  int st = gridDim.x*blockDim.x;
  for (int i = blockIdx.x*blockDim.x + threadIdx.x; i < n1; i += st) W1b[i] = f2bf(W1[i]);
  for (int i = blockIdx.x*blockDim.x + threadIdx.x; i < n2; i += st) W2b[i] = f2bf(W2[i]);
}

// Fused MFMA FFN: Out = LN( X + relu(X@W1+b1)@W2 + b2 , g, be ); also emits
// Qs = bf16(Out * is_n) for the next layer's h-gather.
__global__ __launch_bounds__(256) void k_ffn(
    const float* __restrict__ X,
    const unsigned short* __restrict__ W1b,
    const float* __restrict__ b1g,
    const unsigned short* __restrict__ W2b,
    const float* __restrict__ b2g,
    const float* __restrict__ g, const float* __restrict__ be,
    const float* __restrict__ isn,
    float* __restrict__ Outp, unsigned short* __restrict__ Qs, int nrows)
{
  __shared__ unsigned short sW1T[128*72];
  __shared__ unsigned short sW2T[64*136];
  __shared__ unsigned short sHc[4*16*40];
  int tid = threadIdx.x;
  int lane = tid & 63, w = tid >> 6;
  int quad = lane >> 4, n16 = lane & 15;
  int rowbase = blockIdx.x*64 + w*16;

  int arow = min(rowbase + n16, nrows-1);
  const float4* X4 = (const float4*)X;
  short8 a0, a1;
  {
    float4 u0 = X4[(size_t)arow*16 + quad*2];
    float4 u1 = X4[(size_t)arow*16 + quad*2 + 1];
    float4 u2 = X4[(size_t)arow*16 + 8 + quad*2];
    float4 u3 = X4[(size_t)arow*16 + 8 + quad*2 + 1];
    a0[0]=f2bf(u0.x); a0[1]=f2bf(u0.y); a0[2]=f2bf(u0.z); a0[3]=f2bf(u0.w);
    a0[4]=f2bf(u1.x); a0[5]=f2bf(u1.y); a0[6]=f2bf(u1.z); a0[7]=f2bf(u1.w);
    a1[0]=f2bf(u2.x); a1[1]=f2bf(u2.y); a1[2]=f2bf(u2.z); a1[3]=f2bf(u2.w);
    a1[4]=f2bf(u3.x); a1[5]=f2bf(u3.y); a1[6]=f2bf(u3.z); a1[7]=f2bf(u3.w);
  }

  floatx4 acc2[4];
  #pragma unroll
  for (int t = 0; t < 4; ++t) acc2[t] = (floatx4){0.f,0.f,0.f,0.f};

  unsigned short* myHc = &sHc[w*16*40];

  for (int hb = 0; hb < 2; ++hb){
    __syncthreads();
    #pragma unroll
    for (int i = 0; i < 8; ++i){
      int idx = i*256 + tid;
      int k = idx >> 5, nnb = (idx & 31)*4;
      ushort4v v = *(const ushort4v*)&W1b[k*256 + hb*128 + nnb];
      sW1T[(nnb+0)*72 + k] = v[0];
      sW1T[(nnb+1)*72 + k] = v[1];
      sW1T[(nnb+2)*72 + k] = v[2];
      sW1T[(nnb+3)*72 + k] = v[3];
    }
    #pragma unroll
    for (int i = 0; i < 8; ++i){
      int idx = i*256 + tid;
      int kk = idx >> 4, ob = (idx & 15)*4;
      ushort4v v = *(const ushort4v*)&W2b[(hb*128 + kk)*64 + ob];
      sW2T[(ob+0)*136 + kk] = v[0];
      sW2T[(ob+1)*136 + kk] = v[1];
      sW2T[(ob+2)*136 + kk] = v[2];
      sW2T[(ob+3)*136 + kk] = v[3];
    }
    __syncthreads();

    for (int ck = 0; ck < 4; ++ck){
      #pragma unroll
      for (int nt = 0; nt < 2; ++nt){
        int nn = ck*32 + nt*16 + n16;
        floatx4 c = (floatx4){0.f,0.f,0.f,0.f};
        short8 b0 = *(const short8*)&sW1T[nn*72 + quad*8];
        short8 b1f = *(const short8*)&sW1T[nn*72 + 32 + quad*8];
        c = __builtin_amdgcn_mfma_f32_16x16x32_bf16(a0, b0, c, 0, 0, 0);
        c = __builtin_amdgcn_mfma_f32_16x16x32_bf16(a1, b1f, c, 0, 0, 0);
        float bb = b1g[hb*128 + nn];
        #pragma unroll
        for (int r = 0; r < 4; ++r){
          float h = fmaxf(c[r] + bb, 0.f);
          myHc[(quad*4 + r)*40 + nt*16 + n16] = f2bf(h);
        }
      }
      short8 a2 = *(const short8*)&myHc[n16*40 + quad*8];
      #pragma unroll
      for (int ot = 0; ot < 4; ++ot){
        short8 b2f = *(const short8*)&sW2T[(ot*16 + n16)*136 + ck*32 + quad*8];
        acc2[ot] = __builtin_amdgcn_mfma_f32_16x16x32_bf16(a2, b2f, acc2[ot], 0, 0, 0);
      }
    }
  }

  float pre[4][4];
  #pragma unroll
  for (int ot = 0; ot < 4; ++ot){
    float b2c = b2g[ot*16 + n16];
    #pragma unroll
    for (int r = 0; r < 4; ++r){
      int rr = min(rowbase + quad*4 + r, nrows-1);
      pre[ot][r] = acc2[ot][r] + b2c + X[(size_t)rr*64 + ot*16 + n16];
    }
  }
  float gl[4], bel[4];
  #pragma unroll
  for (int ot = 0; ot < 4; ++ot){ gl[ot] = g[ot*16 + n16]; bel[ot] = be[ot*16 + n16]; }
  #pragma unroll
  for (int r = 0; r < 4; ++r){
    float s = (pre[0][r] + pre[1][r]) + (pre[2][r] + pre[3][r]);
    float q = fmaf(pre[0][r], pre[0][r], pre[1][r]*pre[1][r]) +
              fmaf(pre[2][r], pre[2][r], pre[3][r]*pre[3][r]);
    #pragma unroll
    for (int o = 8; o >= 1; o >>= 1){
      s += __shfl_xor(s, o, 64);
      q += __shfl_xor(q, o, 64);
    }
    float mu = s*(1.f/64.f);
    float var = fmaf(-mu, mu, q*(1.f/64.f));
    float rs = rsqrtf(var + 1e-5f);
    int rr = rowbase + quad*4 + r;
    if (rr < nrows){
      float isr = isn[rr];
      #pragma unroll
      for (int ot = 0; ot < 4; ++ot){
        float ov = fmaf((pre[ot][r]-mu)*rs, gl[ot], bel[ot]);
        Outp[(size_t)rr*64 + ot*16 + n16] = ov;
        Qs[(size_t)rr*64 + ot*16 + n16] = f2bf(ov * isr);
      }
    }
  }
}

// out[n] = LN(Q[n], gF, bF) @ Wo + bo
__global__ __launch_bounds__(256) void k_final(const float* __restrict__ Q,
    const float* __restrict__ Wg, const float* __restrict__ bog,
    const float* __restrict__ gF, const float* __restrict__ bF,
    float* __restrict__ out, int nrows){
  __shared__ __align__(16) float Ws[64*68];
  int tid = threadIdx.x;
  #pragma unroll
  for (int i = 0; i < 16; ++i){ int e = tid + i*256; Ws[(e>>6)*68 + (e&63)] = Wg[e]; }
  __syncthreads();
  int lane = tid & 63, wv = tid >> 6;
  float gl = gF[lane], bl = bF[lane], bol = bog[lane];
  int r = blockIdx.x*4 + wv, stride = gridDim.x*4;
  for (; r < nrows; r += stride){
    float v = Q[r*64 + lane];
    float mu, rs; wave_ln_stats(v, mu, rs);
    float nv = fmaf((v - mu)*rs, gl, bl);
    float acc = 0.f;
    #pragma unroll
    for (int k = 0; k < 64; ++k) acc = fmaf(__shfl(nv, k, 64), Ws[k*68 + lane], acc);
    out[r*64 + lane] = acc + bol;
  }
}

extern "C" void kernel_launch(void* const* d_in, const int* in_sizes, int n_in,
                              void* d_out, int out_size, void* d_ws, size_t ws_size,
                              hipStream_t stream){
  const float* nf   = (const float*)d_in[0];
  const int*   esrc = (const int*)d_in[1];
  const int*   edst = (const int*)d_in[2];
  const float* Wn2h = (const float*)d_in[4];
  const float* bn2h = (const float*)d_in[5];
  const float* Wh2n = (const float*)d_in[6];
  const float* bh2n = (const float*)d_in[7];
  const float* W1   = (const float*)d_in[8];
  const float* b1   = (const float*)d_in[9];
  const float* W2   = (const float*)d_in[10];
  const float* b2   = (const float*)d_in[11];
  const float* g1   = (const float*)d_in[12];
  const float* be1  = (const float*)d_in[13];
  const float* g2   = (const float*)d_in[14];
  const float* be2  = (const float*)d_in[15];
  const float* gF   = (const float*)d_in[16];
  const float* bF   = (const float*)d_in[17];
  const float* Wo   = (const float*)d_in[18];
  const float* bo   = (const float*)d_in[19];
  const int N = in_sizes[0] / 64;
  const int E = in_sizes[1];
  const int H = HYP;
  float* out = (float*)d_out;

  char* w = (char*)d_ws;
  auto carve = [&](size_t bytes) -> char* {
    char* p = w; w += (bytes + 255) & ~(size_t)255; return p;
  };
  int* bh = (int*)carve((size_t)(NB_H + NB_N)*4);   // bh[NB_H] then bn[NB_N], one memset
  int* bn = bh + NB_H;
  int* bstart_h = (int*)carve((size_t)(NB_H+1)*4);
  int* gcur_h   = (int*)carve((size_t)NB_H*4);
  int* bstart_n = (int*)carve((size_t)(NB_N+1)*4);
  int* gcur_n   = (int*)carve((size_t)NB_N*4);
  unsigned* Ebuf_h = (unsigned*)carve((size_t)E*4);
  unsigned* Ebuf_n = (unsigned*)carve((size_t)E*4);
  int*   off_h = (int*)carve((size_t)(H+1)*4);
  int*   off_n = (int*)carve((size_t)(N+1)*4);
  float* is_h  = (float*)carve((size_t)H*4);
  float* is_n  = (float*)carve((size_t)N*4);
  int*   csr_h = (int*)carve((size_t)E*4);
  int*   csr_n = (int*)carve((size_t)E*4);
  float* aggx  = (float*)carve((size_t)H*64*4);
  float* aggh  = (float*)carve((size_t)N*64*4);
  float* Pb    = (float*)carve((size_t)N*64*4);
  float* Qb    = (float*)carve((size_t)N*64*4);
  unsigned short* hhsb = (unsigned short*)carve((size_t)H*64*2);
  unsigned short* xb0  = (unsigned short*)carve((size_t)N*64*2);
  unsigned short* Qs   = (unsigned short*)carve((size_t)N*64*2);
  unsigned short* W1g16 = (unsigned short*)carve((size_t)NLAYER*64*256*2);
  unsigned short* W2g16 = (unsigned short*)carve((size_t)NLAYER*256*64*2);

  hipMemsetAsync(bh, 0, (size_t)(NB_H + NB_N)*4, stream);
  k_cvtw<<<96, 256, 0, stream>>>(W1, W2, W1g16, W2g16, NLAYER*64*256, NLAYER*256*64);
  k_hist<<<512, 256, 0, stream>>>(esrc, edst, E, bh, bn);
  k_bscan<<<1, 256, 0, stream>>>(bh, bn, bstart_h, gcur_h, bstart_n, gcur_n);
  k_partition<<<(E + PT - 1)/PT, 256, 0, stream>>>(edst, esrc, E, 17, NB_H, gcur_h, Ebuf_h);
  k_partition<<<(E + PT - 1)/PT, 256, 0, stream>>>(esrc, edst, E, 15, NB_N, gcur_n, Ebuf_n);
  k_build<<<NB_H, 256, 0, stream>>>(Ebuf_h, bstart_h, 17, 64, 0x1FFFF, H, off_h, is_h, csr_h);
  k_build<<<NB_N, 256, 0, stream>>>(Ebuf_n, bstart_n, 15, 256, 0x7FFF, N, off_n, is_n, csr_n);
  k_prescale<<<4096, 256, 0, stream>>>(nf, is_n, xb0, N);

  for (int l = 0; l < NLAYER; ++l){
    const float* hin = (l == 0) ? nf : Qb;
    const unsigned short* hsrc = (l == 0) ? xb0 : Qs;
    k_gather8<<<2048, 256, 0, stream>>>(hsrc, csr_h, off_h, aggx, H);
    k_mmA<<<512, 256, 0, stream>>>(aggx, Wn2h + l*4096, bn2h + l*64, is_h, hhsb, H);
    k_gather8<<<2048, 256, 0, stream>>>(hhsb, csr_n, off_n, aggh, N);
    k_mmB_ln<<<1024, 256, 0, stream>>>(aggh, Wh2n + l*4096, bh2n + l*64, is_n, hin,
                                       g1 + l*64, be1 + l*64, Pb, N);
    k_ffn<<<(N + 63)/64, 256, 0, stream>>>(Pb, W1g16 + l*64*256, b1 + l*256,
                                           W2g16 + l*256*64, b2 + l*64,
                                           g2 + l*64, be2 + l*64, is_n, Qb, Qs, N);
  }
  k_final<<<1024, 256, 0, stream>>>(Qb, Wo, bo, gF, bF, out, N);
}

// Round 5
// 618.985 us; speedup vs baseline: 3.0939x; 1.5875x over previous
//
#include <hip/hip_runtime.h>

// Problem constants (from reference): N=100000, H=20000, E=1600000, D=64, L=3, F=256
#define HYP 20000
#define NLAYER 3
// Bucket-sort geometry: ids fit 15 bits (H=20000) / 17 bits (N=100000).
#define NB_H 313
#define NB_N 391
#define PT 4096

typedef __attribute__((ext_vector_type(8))) short short8;
typedef __attribute__((ext_vector_type(4))) float floatx4;
typedef __attribute__((ext_vector_type(4))) unsigned short ushort4v;

static __device__ __forceinline__ unsigned short f2bf(float f){
  union { float f; unsigned u; } v; v.f = f;
  unsigned r = v.u + 0x7FFF + ((v.u >> 16) & 1);
  return (unsigned short)(r >> 16);
}

// ---- CSR build, stage 1: global bucket histogram (LDS-staged) ----
__global__ __launch_bounds__(256) void k_hist(const int* __restrict__ src,
    const int* __restrict__ dst, int E, int* __restrict__ bh, int* __restrict__ bn){
  __shared__ int lh[NB_H + NB_N];
  int tid = threadIdx.x;
  for (int i = tid; i < NB_H + NB_N; i += 256) lh[i] = 0;
  __syncthreads();
  for (int i = blockIdx.x*256 + tid; i < E; i += gridDim.x*256){
    atomicAdd(&lh[dst[i] >> 6], 1);
    atomicAdd(&lh[NB_H + (src[i] >> 8)], 1);
  }
  __syncthreads();
  for (int i = tid; i < NB_H; i += 256) if (lh[i]) atomicAdd(&bh[i], lh[i]);
  for (int i = tid; i < NB_N; i += 256) if (lh[NB_H+i]) atomicAdd(&bn[i], lh[NB_H+i]);
}

// ---- stage 2: exclusive scan of bucket counts -> bucket starts + cursors ----
__global__ __launch_bounds__(256) void k_bscan(const int* __restrict__ bh,
    const int* __restrict__ bn, int* __restrict__ bstart_h, int* __restrict__ gcur_h,
    int* __restrict__ bstart_n, int* __restrict__ gcur_n){
  __shared__ int ssc[4];
  __shared__ int scarry;
  int tid = threadIdx.x, lane = tid & 63, wv = tid >> 6;
  if (tid == 0) scarry = 0;
  __syncthreads();
  for (int base = 0; base < NB_H; base += 256){
    int i = base + tid; int v = (i < NB_H) ? bh[i] : 0; int x = v;
    #pragma unroll
    for (int o = 1; o < 64; o <<= 1){ int t = __shfl_up(x,o,64); if (lane >= o) x += t; }
    if (lane == 63) ssc[wv] = x;
    __syncthreads();
    int add = (wv>0?ssc[0]:0)+(wv>1?ssc[1]:0)+(wv>2?ssc[2]:0);
    int c = scarry;
    if (i < NB_H){ int ex = c + add + x - v; bstart_h[i] = ex; gcur_h[i] = ex; }
    __syncthreads();
    if (tid == 255) scarry = c + ssc[0]+ssc[1]+ssc[2]+ssc[3];
    __syncthreads();
  }
  if (tid == 0){ bstart_h[NB_H] = scarry; scarry = 0; }
  __syncthreads();
  for (int base = 0; base < NB_N; base += 256){
    int i = base + tid; int v = (i < NB_N) ? bn[i] : 0; int x = v;
    #pragma unroll
    for (int o = 1; o < 64; o <<= 1){ int t = __shfl_up(x,o,64); if (lane >= o) x += t; }
    if (lane == 63) ssc[wv] = x;
    __syncthreads();
    int add = (wv>0?ssc[0]:0)+(wv>1?ssc[1]:0)+(wv>2?ssc[2]:0);
    int c = scarry;
    if (i < NB_N){ int ex = c + add + x - v; bstart_n[i] = ex; gcur_n[i] = ex; }
    __syncthreads();
    if (tid == 255) scarry = c + ssc[0]+ssc[1]+ssc[2]+ssc[3];
    __syncthreads();
  }
  if (tid == 0) bstart_n[NB_N] = scarry;
}

// ---- stage 3: LDS-staged radix partition into bucket-contiguous entry buffer ----
__global__ __launch_bounds__(256) void k_partition(const int* __restrict__ keys,
    const int* __restrict__ pays, int E, int keyshift, int nb,
    int* __restrict__ gcur, unsigned* __restrict__ Ebuf){
  __shared__ unsigned sst[PT];
  __shared__ int lh[NB_N], lpre[NB_N], gb[NB_N];
  __shared__ int ssc[4];
  __shared__ int scarry;
  int tid = threadIdx.x, lane = tid & 63, wv = tid >> 6;
  int base = blockIdx.x*PT;
  int m = min(PT, E - base);
  for (int i = tid; i < nb; i += 256) lh[i] = 0;
  if (tid == 0) scarry = 0;
  __syncthreads();
  unsigned en[16]; int rk[16];
  #pragma unroll
  for (int j = 0; j < 16; ++j){
    int i = base + j*256 + tid;
    if (i < E){
      unsigned k = (unsigned)keys[i], p = (unsigned)pays[i];
      en[j] = (k << keyshift) | p;
      rk[j] = atomicAdd(&lh[en[j] >> 23], 1);
    } else { en[j] = 0; rk[j] = -1; }
  }
  __syncthreads();
  for (int b2 = 0; b2 < nb; b2 += 256){
    int i = b2 + tid; int v = (i < nb) ? lh[i] : 0; int x = v;
    #pragma unroll
    for (int o = 1; o < 64; o <<= 1){ int t = __shfl_up(x,o,64); if (lane >= o) x += t; }
    if (lane == 63) ssc[wv] = x;
    __syncthreads();
    int add = (wv>0?ssc[0]:0)+(wv>1?ssc[1]:0)+(wv>2?ssc[2]:0);
    int c = scarry;
    if (i < nb) lpre[i] = c + add + x - v;
    __syncthreads();
    if (tid == 255) scarry = c + ssc[0]+ssc[1]+ssc[2]+ssc[3];
    __syncthreads();
  }
  for (int i = tid; i < nb; i += 256) gb[i] = atomicAdd(&gcur[i], lh[i]);
  #pragma unroll
  for (int j = 0; j < 16; ++j){
    if (rk[j] >= 0){
      int bk = en[j] >> 23;
      sst[lpre[bk] + rk[j]] = en[j];
    }
  }
  __syncthreads();
  for (int j = tid; j < m; j += 256){
    unsigned e = sst[j];
    int bk = e >> 23;
    Ebuf[gb[bk] + (j - lpre[bk])] = e;
  }
}

// ---- stage 4: per-bucket CSR build ----
__global__ __launch_bounds__(256) void k_build(const unsigned* __restrict__ Ebuf,
    const int* __restrict__ bstart, int keyshift, int ipb, int paymask, int limit,
    int* __restrict__ off, float* __restrict__ isv, int* __restrict__ csr){
  __shared__ int lcnt[256], lpre2[256], lcur[256];
  int tid = threadIdx.x, lane = tid & 63, wv = tid >> 6;
  int b = blockIdx.x;
  int base = bstart[b], m = bstart[b+1] - base;
  for (int i = tid; i < ipb; i += 256) lcnt[i] = 0;
  __syncthreads();
  for (int i = tid; i < m; i += 256){
    unsigned e = Ebuf[base + i];
    atomicAdd(&lcnt[(e >> keyshift) & (ipb-1)], 1);
  }
  __syncthreads();
  if (wv == 0){
    int carry = 0;
    for (int c = 0; c < ipb; c += 64){
      int li = c + lane;
      int v = lcnt[li]; int x = v;
      #pragma unroll
      for (int o = 1; o < 64; o <<= 1){ int t = __shfl_up(x,o,64); if (lane >= o) x += t; }
      int ex = carry + x - v;
      int id = b*ipb + li;
      if (id <= limit) off[id] = base + ex;
      if (id < limit) isv[id] = rsqrtf((float)(v > 0 ? v : 1));
      lpre2[li] = ex;
      carry += __shfl(x, 63, 64);
    }
  }
  for (int i = tid; i < ipb; i += 256) lcur[i] = 0;
  __syncthreads();
  for (int i = tid; i < m; i += 256){
    unsigned e = Ebuf[base + i];
    int li = (e >> keyshift) & (ipb-1);
    int pos = base + lpre2[li] + atomicAdd(&lcur[li], 1);
    csr[pos] = (int)(e & (unsigned)paymask);
  }
}

// Pre-scale + bf16-convert node features for layer-0 h-gather
__global__ void k_prescale(const float* __restrict__ x, const float* __restrict__ isn,
                           unsigned short* __restrict__ xb, int nrows){
  int i = blockIdx.x*blockDim.x + threadIdx.x;
  int st = gridDim.x*blockDim.x;
  int tot = nrows*64;
  for (; i < tot; i += st){ xb[i] = f2bf(x[i]*isn[i >> 6]); }
}

// Convert all fp32 weight tensors to bf16 once per launch.
__global__ void k_cvtall(const float* __restrict__ W1, const float* __restrict__ W2,
                         const float* __restrict__ Wa, const float* __restrict__ Wb,
                         const float* __restrict__ Wo,
                         unsigned short* __restrict__ W1b, unsigned short* __restrict__ W2b,
                         unsigned short* __restrict__ Wab, unsigned short* __restrict__ Wbb,
                         unsigned short* __restrict__ Wob){
  int st = gridDim.x*blockDim.x;
  int t0 = blockIdx.x*blockDim.x + threadIdx.x;
  for (int i = t0; i < NLAYER*64*256; i += st) W1b[i] = f2bf(W1[i]);
  for (int i = t0; i < NLAYER*256*64; i += st) W2b[i] = f2bf(W2[i]);
  for (int i = t0; i < NLAYER*4096; i += st) Wab[i] = f2bf(Wa[i]);
  for (int i = t0; i < NLAYER*4096; i += st) Wbb[i] = f2bf(Wb[i]);
  for (int i = t0; i < 4096; i += st) Wob[i] = f2bf(Wo[i]);
}

// Gather: wave per row, 2x unrolled (two outstanding 1KB feat loads), bf16 in/out,
// fp32 accumulate, butterfly-combine 8 edge slots (xor 8/16/32).
__global__ __launch_bounds__(256) void k_gather8(const unsigned short* __restrict__ feat,
    const int* __restrict__ csr, const int* __restrict__ off,
    unsigned short* __restrict__ agg, int nrows){
  int lane = threadIdx.x & 63, wvi = threadIdx.x >> 6;
  int g = lane >> 3;
  int ch = (lane & 7) * 8;
  int r = blockIdx.x*4 + wvi, stride = gridDim.x*4;
  for (; r < nrows; r += stride){
    int b = off[r], e = off[r+1];
    float a0=0,a1=0,a2=0,a3=0,a4=0,a5=0,a6=0,a7=0;
    int t = b;
    for (; t + 16 <= e; t += 16){
      int s0 = csr[t + g];
      int s1 = csr[t + 8 + g];
      uint4 u0 = *(const uint4*)&feat[(size_t)s0*64 + ch];
      uint4 u1 = *(const uint4*)&feat[(size_t)s1*64 + ch];
      a0 += __uint_as_float(u0.x << 16); a1 += __uint_as_float(u0.x & 0xFFFF0000u);
      a2 += __uint_as_float(u0.y << 16); a3 += __uint_as_float(u0.y & 0xFFFF0000u);
      a4 += __uint_as_float(u0.z << 16); a5 += __uint_as_float(u0.z & 0xFFFF0000u);
      a6 += __uint_as_float(u0.w << 16); a7 += __uint_as_float(u0.w & 0xFFFF0000u);
      a0 += __uint_as_float(u1.x << 16); a1 += __uint_as_float(u1.x & 0xFFFF0000u);
      a2 += __uint_as_float(u1.y << 16); a3 += __uint_as_float(u1.y & 0xFFFF0000u);
      a4 += __uint_as_float(u1.z << 16); a5 += __uint_as_float(u1.z & 0xFFFF0000u);
      a6 += __uint_as_float(u1.w << 16); a7 += __uint_as_float(u1.w & 0xFFFF0000u);
    }
    for (; t < e; t += 8){
      int idx = t + g;
      bool valid = idx < e;
      int s = csr[valid ? idx : b];
      uint4 u = *(const uint4*)&feat[(size_t)s*64 + ch];
      if (!valid){ u.x = 0; u.y = 0; u.z = 0; u.w = 0; }
      a0 += __uint_as_float(u.x << 16); a1 += __uint_as_float(u.x & 0xFFFF0000u);
      a2 += __uint_as_float(u.y << 16); a3 += __uint_as_float(u.y & 0xFFFF0000u);
      a4 += __uint_as_float(u.z << 16); a5 += __uint_as_float(u.z & 0xFFFF0000u);
      a6 += __uint_as_float(u.w << 16); a7 += __uint_as_float(u.w & 0xFFFF0000u);
    }
    #pragma unroll
    for (int o = 8; o <= 32; o <<= 1){
      a0 += __shfl_xor(a0,o,64); a1 += __shfl_xor(a1,o,64);
      a2 += __shfl_xor(a2,o,64); a3 += __shfl_xor(a3,o,64);
      a4 += __shfl_xor(a4,o,64); a5 += __shfl_xor(a5,o,64);
      a6 += __shfl_xor(a6,o,64); a7 += __shfl_xor(a7,o,64);
    }
    if (g == 0){
      uint4 w;
      w.x = (unsigned)f2bf(a0) | ((unsigned)f2bf(a1) << 16);
      w.y = (unsigned)f2bf(a2) | ((unsigned)f2bf(a3) << 16);
      w.z = (unsigned)f2bf(a4) | ((unsigned)f2bf(a5) << 16);
      w.w = (unsigned)f2bf(a6) | ((unsigned)f2bf(a7) << 16);
      *(uint4*)&agg[(size_t)r*64 + ch] = w;
    }
  }
}

// MFMA mmA: hhsb[j] = bf16( ((aggx[j]@Wa)*is_h + ba) * is_h ), 64 rows/block.
__global__ __launch_bounds__(256) void k_mmA(const unsigned short* __restrict__ aggb,
    const unsigned short* __restrict__ Wbb, const float* __restrict__ bias,
    const float* __restrict__ ihy, unsigned short* __restrict__ ouths, int nrows){
  __shared__ unsigned short sWb[64*72];
  int tid = threadIdx.x;
  int lane = tid & 63, w = tid >> 6;
  int quad = lane >> 4, n16 = lane & 15;
  #pragma unroll
  for (int i = 0; i < 4; ++i){
    int idx = i*256 + tid;
    int k = idx >> 4, nb = (idx & 15)*4;
    ushort4v v = *(const ushort4v*)&Wbb[k*64 + nb];
    sWb[(nb+0)*72 + k] = v[0];
    sWb[(nb+1)*72 + k] = v[1];
    sWb[(nb+2)*72 + k] = v[2];
    sWb[(nb+3)*72 + k] = v[3];
  }
  __syncthreads();
  int rowbase = blockIdx.x*64 + w*16;
  int arow = min(rowbase + n16, nrows-1);
  short8 a0 = *(const short8*)&aggb[(size_t)arow*64 + quad*8];
  short8 a1 = *(const short8*)&aggb[(size_t)arow*64 + 32 + quad*8];
  float ih[4];
  #pragma unroll
  for (int r = 0; r < 4; ++r) ih[r] = ihy[min(rowbase + quad*4 + r, nrows-1)];
  #pragma unroll
  for (int ot = 0; ot < 4; ++ot){
    floatx4 c = (floatx4){0.f,0.f,0.f,0.f};
    short8 b0 = *(const short8*)&sWb[(ot*16+n16)*72 + quad*8];
    short8 b1 = *(const short8*)&sWb[(ot*16+n16)*72 + 32 + quad*8];
    c = __builtin_amdgcn_mfma_f32_16x16x32_bf16(a0, b0, c, 0, 0, 0);
    c = __builtin_amdgcn_mfma_f32_16x16x32_bf16(a1, b1, c, 0, 0, 0);
    float bl = bias[ot*16 + n16];
    #pragma unroll
    for (int r = 0; r < 4; ++r){
      int rr = rowbase + quad*4 + r;
      if (rr < nrows)
        ouths[(size_t)rr*64 + ot*16 + n16] = f2bf(fmaf(c[r], ih[r], bl) * ih[r]);
    }
  }
}

// Fused per-node pipeline: P = LN1(hin + (aggh@Wb)*is_n + bb);
// Out = LN2(P + relu(P@W1+b1)@W2 + b2); Qs = bf16(Out*is_n).
__global__ __launch_bounds__(256) void k_fused(
    const unsigned short* __restrict__ aggb,   // N x 64 bf16
    const unsigned short* __restrict__ Wbb,    // 64 x 64 bf16 (layer)
    const float* __restrict__ bbg,
    const float* __restrict__ isn,
    const float* __restrict__ hin,             // N x 64 fp32
    const float* __restrict__ g1v, const float* __restrict__ be1v,
    const unsigned short* __restrict__ W1b, const float* __restrict__ b1g,
    const unsigned short* __restrict__ W2b, const float* __restrict__ b2g,
    const float* __restrict__ g2v, const float* __restrict__ be2v,
    float* __restrict__ Outp, unsigned short* __restrict__ Qs, int nrows)
{
  __shared__ unsigned short sW1T[128*72];      // also hosts sWb (first 64*72) pre-FFN
  __shared__ unsigned short sW2T[64*136];
  __shared__ unsigned short sPH[4*16*72];      // per-wave: P staging, then H1 chunks
  unsigned short* sWb = sW1T;
  int tid = threadIdx.x;
  int lane = tid & 63, w = tid >> 6;
  int quad = lane >> 4, n16 = lane & 15;
  int rowbase = blockIdx.x*64 + w*16;

  // stage Wb
  #pragma unroll
  for (int i = 0; i < 4; ++i){
    int idx = i*256 + tid;
    int k = idx >> 4, nb = (idx & 15)*4;
    ushort4v v = *(const ushort4v*)&Wbb[k*64 + nb];
    sWb[(nb+0)*72 + k] = v[0];
    sWb[(nb+1)*72 + k] = v[1];
    sWb[(nb+2)*72 + k] = v[2];
    sWb[(nb+3)*72 + k] = v[3];
  }
  __syncthreads();

  // mmB: aggh @ Wb
  int arow = min(rowbase + n16, nrows-1);
  short8 a0 = *(const short8*)&aggb[(size_t)arow*64 + quad*8];
  short8 a1 = *(const short8*)&aggb[(size_t)arow*64 + 32 + quad*8];
  floatx4 cB[4];
  #pragma unroll
  for (int ot = 0; ot < 4; ++ot){
    floatx4 c = (floatx4){0.f,0.f,0.f,0.f};
    short8 b0 = *(const short8*)&sWb[(ot*16+n16)*72 + quad*8];
    short8 b1 = *(const short8*)&sWb[(ot*16+n16)*72 + 32 + quad*8];
    c = __builtin_amdgcn_mfma_f32_16x16x32_bf16(a0, b0, c, 0, 0, 0);
    c = __builtin_amdgcn_mfma_f32_16x16x32_bf16(a1, b1, c, 0, 0, 0);
    cB[ot] = c;
  }

  // epilogue-1: *is_n + bb + hin, then LN1 -> pP (registers) + sPH (A-layout source)
  float isr[4];
  #pragma unroll
  for (int r = 0; r < 4; ++r) isr[r] = isn[min(rowbase + quad*4 + r, nrows-1)];
  float pP[4][4];
  #pragma unroll
  for (int ot = 0; ot < 4; ++ot){
    float bb = bbg[ot*16 + n16];
    #pragma unroll
    for (int r = 0; r < 4; ++r){
      int rr = min(rowbase + quad*4 + r, nrows-1);
      pP[ot][r] = fmaf(cB[ot][r], isr[r], bb) + hin[(size_t)rr*64 + ot*16 + n16];
    }
  }
  {
    float gl[4], bl[4];
    #pragma unroll
    for (int ot = 0; ot < 4; ++ot){ gl[ot] = g1v[ot*16+n16]; bl[ot] = be1v[ot*16+n16]; }
    #pragma unroll
    for (int r = 0; r < 4; ++r){
      float s = (pP[0][r] + pP[1][r]) + (pP[2][r] + pP[3][r]);
      float q = fmaf(pP[0][r], pP[0][r], pP[1][r]*pP[1][r]) +
                fmaf(pP[2][r], pP[2][r], pP[3][r]*pP[3][r]);
      #pragma unroll
      for (int o = 8; o >= 1; o >>= 1){
        s += __shfl_xor(s, o, 64);
        q += __shfl_xor(q, o, 64);
      }
      float mu = s*(1.f/64.f);
      float var = fmaf(-mu, mu, q*(1.f/64.f));
      float rs = rsqrtf(var + 1e-5f);
      #pragma unroll
      for (int ot = 0; ot < 4; ++ot)
        pP[ot][r] = fmaf((pP[ot][r]-mu)*rs, gl[ot], bl[ot]);
    }
  }
  unsigned short* myP = &sPH[w*16*72];
  #pragma unroll
  for (int ot = 0; ot < 4; ++ot)
    #pragma unroll
    for (int r = 0; r < 4; ++r)
      myP[(quad*4 + r)*72 + ot*16 + n16] = f2bf(pP[ot][r]);
  short8 p0 = *(const short8*)&myP[n16*72 + quad*8];
  short8 p1 = *(const short8*)&myP[n16*72 + 32 + quad*8];

  // FFN
  floatx4 acc2[4];
  #pragma unroll
  for (int t = 0; t < 4; ++t) acc2[t] = (floatx4){0.f,0.f,0.f,0.f};
  unsigned short* myHc = &sPH[w*16*72];   // reused (p0/p1 already in regs)

  for (int hb = 0; hb < 2; ++hb){
    __syncthreads();
    #pragma unroll
    for (int i = 0; i < 8; ++i){
      int idx = i*256 + tid;
      int k = idx >> 5, nnb = (idx & 31)*4;
      ushort4v v = *(const ushort4v*)&W1b[k*256 + hb*128 + nnb];
      sW1T[(nnb+0)*72 + k] = v[0];
      sW1T[(nnb+1)*72 + k] = v[1];
      sW1T[(nnb+2)*72 + k] = v[2];
      sW1T[(nnb+3)*72 + k] = v[3];
    }
    #pragma unroll
    for (int i = 0; i < 8; ++i){
      int idx = i*256 + tid;
      int kk = idx >> 4, ob = (idx & 15)*4;
      ushort4v v = *(const ushort4v*)&W2b[(hb*128 + kk)*64 + ob];
      sW2T[(ob+0)*136 + kk] = v[0];
      sW2T[(ob+1)*136 + kk] = v[1];
      sW2T[(ob+2)*136 + kk] = v[2];
      sW2T[(ob+3)*136 + kk] = v[3];
    }
    __syncthreads();

    for (int ck = 0; ck < 4; ++ck){
      #pragma unroll
      for (int nt = 0; nt < 2; ++nt){
        int nn = ck*32 + nt*16 + n16;
        floatx4 c = (floatx4){0.f,0.f,0.f,0.f};
        short8 b0 = *(const short8*)&sW1T[nn*72 + quad*8];
        short8 b1f = *(const short8*)&sW1T[nn*72 + 32 + quad*8];
        c = __builtin_amdgcn_mfma_f32_16x16x32_bf16(p0, b0, c, 0, 0, 0);
        c = __builtin_amdgcn_mfma_f32_16x16x32_bf16(p1, b1f, c, 0, 0, 0);
        float bb = b1g[hb*128 + nn];
        #pragma unroll
        for (int r = 0; r < 4; ++r){
          float h = fmaxf(c[r] + bb, 0.f);
          myHc[(quad*4 + r)*40 + nt*16 + n16] = f2bf(h);
        }
      }
      short8 a2 = *(const short8*)&myHc[n16*40 + quad*8];
      #pragma unroll
      for (int ot = 0; ot < 4; ++ot){
        short8 b2f = *(const short8*)&sW2T[(ot*16 + n16)*136 + ck*32 + quad*8];
        acc2[ot] = __builtin_amdgcn_mfma_f32_16x16x32_bf16(a2, b2f, acc2[ot], 0, 0, 0);
      }
    }
  }

  // epilogue-2: + b2 + P residual (registers), LN2, write Out fp32 + Qs bf16
  float pre[4][4];
  #pragma unroll
  for (int ot = 0; ot < 4; ++ot){
    float b2c = b2g[ot*16 + n16];
    #pragma unroll
    for (int r = 0; r < 4; ++r)
      pre[ot][r] = acc2[ot][r] + b2c + pP[ot][r];
  }
  float gl[4], bel[4];
  #pragma unroll
  for (int ot = 0; ot < 4; ++ot){ gl[ot] = g2v[ot*16 + n16]; bel[ot] = be2v[ot*16 + n16]; }
  #pragma unroll
  for (int r = 0; r < 4; ++r){
    float s = (pre[0][r] + pre[1][r]) + (pre[2][r] + pre[3][r]);
    float q = fmaf(pre[0][r], pre[0][r], pre[1][r]*pre[1][r]) +
              fmaf(pre[2][r], pre[2][r], pre[3][r]*pre[3][r]);
    #pragma unroll
    for (int o = 8; o >= 1; o >>= 1){
      s += __shfl_xor(s, o, 64);
      q += __shfl_xor(q, o, 64);
    }
    float mu = s*(1.f/64.f);
    float var = fmaf(-mu, mu, q*(1.f/64.f));
    float rs = rsqrtf(var + 1e-5f);
    int rr = rowbase + quad*4 + r;
    if (rr < nrows){
      float isr2 = isn[rr];
      #pragma unroll
      for (int ot = 0; ot < 4; ++ot){
        float ov = fmaf((pre[ot][r]-mu)*rs, gl[ot], bel[ot]);
        Outp[(size_t)rr*64 + ot*16 + n16] = ov;
        Qs[(size_t)rr*64 + ot*16 + n16] = f2bf(ov * isr2);
      }
    }
  }
}

// MFMA final: out = LN(Q, gF, bF) @ Wo + bo
__global__ __launch_bounds__(256) void k_final(const float* __restrict__ Q,
    const unsigned short* __restrict__ Wob, const float* __restrict__ bog,
    const float* __restrict__ gF, const float* __restrict__ bF,
    float* __restrict__ out, int nrows){
  __shared__ unsigned short sWb[64*72];
  int tid = threadIdx.x;
  int lane = tid & 63, w = tid >> 6;
  int quad = lane >> 4, n16 = lane & 15;
  #pragma unroll
  for (int i = 0; i < 4; ++i){
    int idx = i*256 + tid;
    int k = idx >> 4, nb = (idx & 15)*4;
    ushort4v v = *(const ushort4v*)&Wob[k*64 + nb];
    sWb[(nb+0)*72 + k] = v[0];
    sWb[(nb+1)*72 + k] = v[1];
    sWb[(nb+2)*72 + k] = v[2];
    sWb[(nb+3)*72 + k] = v[3];
  }
  __syncthreads();
  int rowbase = blockIdx.x*64 + w*16;
  int arow = min(rowbase + n16, nrows-1);
  // A-layout fp32 loads: row=n16, k = quad*8..+7 and 32+quad*8..+7
  float4 q0 = *(const float4*)&Q[(size_t)arow*64 + quad*8];
  float4 q1 = *(const float4*)&Q[(size_t)arow*64 + quad*8 + 4];
  float4 q2 = *(const float4*)&Q[(size_t)arow*64 + 32 + quad*8];
  float4 q3 = *(const float4*)&Q[(size_t)arow*64 + 32 + quad*8 + 4];
  float s = (q0.x+q0.y+q0.z+q0.w) + (q1.x+q1.y+q1.z+q1.w)
          + (q2.x+q2.y+q2.z+q2.w) + (q3.x+q3.y+q3.z+q3.w);
  float qq = (q0.x*q0.x+q0.y*q0.y+q0.z*q0.z+q0.w*q0.w)
           + (q1.x*q1.x+q1.y*q1.y+q1.z*q1.z+q1.w*q1.w)
           + (q2.x*q2.x+q2.y*q2.y+q2.z*q2.z+q2.w*q2.w)
           + (q3.x*q3.x+q3.y*q3.y+q3.z*q3.z+q3.w*q3.w);
  s += __shfl_xor(s, 16, 64);  qq += __shfl_xor(qq, 16, 64);
  s += __shfl_xor(s, 32, 64);  qq += __shfl_xor(qq, 32, 64);
  float mu = s*(1.f/64.f);
  float var = fmaf(-mu, mu, qq*(1.f/64.f));
  float rs = rsqrtf(var + 1e-5f);
  float4 g0 = *(const float4*)&gF[quad*8];
  float4 g1 = *(const float4*)&gF[quad*8 + 4];
  float4 g2 = *(const float4*)&gF[32 + quad*8];
  float4 g3 = *(const float4*)&gF[32 + quad*8 + 4];
  float4 f0 = *(const float4*)&bF[quad*8];
  float4 f1 = *(const float4*)&bF[quad*8 + 4];
  float4 f2 = *(const float4*)&bF[32 + quad*8];
  float4 f3 = *(const float4*)&bF[32 + quad*8 + 4];
  short8 a0, a1;
  a0[0]=f2bf(fmaf((q0.x-mu)*rs, g0.x, f0.x)); a0[1]=f2bf(fmaf((q0.y-mu)*rs, g0.y, f0.y));
  a0[2]=f2bf(fmaf((q0.z-mu)*rs, g0.z, f0.z)); a0[3]=f2bf(fmaf((q0.w-mu)*rs, g0.w, f0.w));
  a0[4]=f2bf(fmaf((q1.x-mu)*rs, g1.x, f1.x)); a0[5]=f2bf(fmaf((q1.y-mu)*rs, g1.y, f1.y));
  a0[6]=f2bf(fmaf((q1.z-mu)*rs, g1.z, f1.z)); a0[7]=f2bf(fmaf((q1.w-mu)*rs, g1.w, f1.w));
  a1[0]=f2bf(fmaf((q2.x-mu)*rs, g2.x, f2.x)); a1[1]=f2bf(fmaf((q2.y-mu)*rs, g2.y, f2.y));
  a1[2]=f2bf(fmaf((q2.z-mu)*rs, g2.z, f2.z)); a1[3]=f2bf(fmaf((q2.w-mu)*rs, g2.w, f2.w));
  a1[4]=f2bf(fmaf((q3.x-mu)*rs, g3.x, f3.x)); a1[5]=f2bf(fmaf((q3.y-mu)*rs, g3.y, f3.y));
  a1[6]=f2bf(fmaf((q3.z-mu)*rs, g3.z, f3.z)); a1[7]=f2bf(fmaf((q3.w-mu)*rs, g3.w, f3.w));
  #pragma unroll
  for (int ot = 0; ot < 4; ++ot){
    floatx4 c = (floatx4){0.f,0.f,0.f,0.f};
    short8 b0 = *(const short8*)&sWb[(ot*16+n16)*72 + quad*8];
    short8 b1 = *(const short8*)&sWb[(ot*16+n16)*72 + 32 + quad*8];
    c = __builtin_amdgcn_mfma_f32_16x16x32_bf16(a0, b0, c, 0, 0, 0);
    c = __builtin_amdgcn_mfma_f32_16x16x32_bf16(a1, b1, c, 0, 0, 0);
    float bol = bog[ot*16 + n16];
    #pragma unroll
    for (int r = 0; r < 4; ++r){
      int rr = rowbase + quad*4 + r;
      if (rr < nrows) out[(size_t)rr*64 + ot*16 + n16] = c[r] + bol;
    }
  }
}

extern "C" void kernel_launch(void* const* d_in, const int* in_sizes, int n_in,
                              void* d_out, int out_size, void* d_ws, size_t ws_size,
                              hipStream_t stream){
  const float* nf   = (const float*)d_in[0];
  const int*   esrc = (const int*)d_in[1];
  const int*   edst = (const int*)d_in[2];
  const float* Wn2h = (const float*)d_in[4];
  const float* bn2h = (const float*)d_in[5];
  const float* Wh2n = (const float*)d_in[6];
  const float* bh2n = (const float*)d_in[7];
  const float* W1   = (const float*)d_in[8];
  const float* b1   = (const float*)d_in[9];
  const float* W2   = (const float*)d_in[10];
  const float* b2   = (const float*)d_in[11];
  const float* g1   = (const float*)d_in[12];
  const float* be1  = (const float*)d_in[13];
  const float* g2   = (const float*)d_in[14];
  const float* be2  = (const float*)d_in[15];
  const float* gF   = (const float*)d_in[16];
  const float* bF   = (const float*)d_in[17];
  const float* Wo   = (const float*)d_in[18];
  const float* bo   = (const float*)d_in[19];
  const int N = in_sizes[0] / 64;
  const int E = in_sizes[1];
  const int H = HYP;
  float* out = (float*)d_out;

  char* w = (char*)d_ws;
  auto carve = [&](size_t bytes) -> char* {
    char* p = w; w += (bytes + 255) & ~(size_t)255; return p;
  };
  int* bh = (int*)carve((size_t)(NB_H + NB_N)*4);
  int* bn = bh + NB_H;
  int* bstart_h = (int*)carve((size_t)(NB_H+1)*4);
  int* gcur_h   = (int*)carve((size_t)NB_H*4);
  int* bstart_n = (int*)carve((size_t)(NB_N+1)*4);
  int* gcur_n   = (int*)carve((size_t)NB_N*4);
  unsigned* Ebuf_h = (unsigned*)carve((size_t)E*4);
  unsigned* Ebuf_n = (unsigned*)carve((size_t)E*4);
  int*   off_h = (int*)carve((size_t)(H+1)*4);
  int*   off_n = (int*)carve((size_t)(N+1)*4);
  float* is_h  = (float*)carve((size_t)H*4);
  float* is_n  = (float*)carve((size_t)N*4);
  int*   csr_h = (int*)carve((size_t)E*4);
  int*   csr_n = (int*)carve((size_t)E*4);
  unsigned short* aggxb = (unsigned short*)carve((size_t)H*64*2);
  unsigned short* agghb = (unsigned short*)carve((size_t)N*64*2);
  float* Qb    = (float*)carve((size_t)N*64*4);
  unsigned short* hhsb = (unsigned short*)carve((size_t)H*64*2);
  unsigned short* xb0  = (unsigned short*)carve((size_t)N*64*2);
  unsigned short* Qs   = (unsigned short*)carve((size_t)N*64*2);
  unsigned short* W1g16 = (unsigned short*)carve((size_t)NLAYER*64*256*2);
  unsigned short* W2g16 = (unsigned short*)carve((size_t)NLAYER*256*64*2);
  unsigned short* Wag16 = (unsigned short*)carve((size_t)NLAYER*4096*2);
  unsigned short* Wbg16 = (unsigned short*)carve((size_t)NLAYER*4096*2);
  unsigned short* Wog16 = (unsigned short*)carve((size_t)4096*2);

  hipMemsetAsync(bh, 0, (size_t)(NB_H + NB_N)*4, stream);
  k_cvtall<<<96, 256, 0, stream>>>(W1, W2, Wn2h, Wh2n, Wo,
                                   W1g16, W2g16, Wag16, Wbg16, Wog16);
  k_hist<<<512, 256, 0, stream>>>(esrc, edst, E, bh, bn);
  k_bscan<<<1, 256, 0, stream>>>(bh, bn, bstart_h, gcur_h, bstart_n, gcur_n);
  k_partition<<<(E + PT - 1)/PT, 256, 0, stream>>>(edst, esrc, E, 17, NB_H, gcur_h, Ebuf_h);
  k_partition<<<(E + PT - 1)/PT, 256, 0, stream>>>(esrc, edst, E, 15, NB_N, gcur_n, Ebuf_n);
  k_build<<<NB_H, 256, 0, stream>>>(Ebuf_h, bstart_h, 17, 64, 0x1FFFF, H, off_h, is_h, csr_h);
  k_build<<<NB_N, 256, 0, stream>>>(Ebuf_n, bstart_n, 15, 256, 0x7FFF, N, off_n, is_n, csr_n);
  k_prescale<<<4096, 256, 0, stream>>>(nf, is_n, xb0, N);

  const int NB64 = (N + 63)/64;
  const int HB64 = (H + 63)/64;
  for (int l = 0; l < NLAYER; ++l){
    const float* hin = (l == 0) ? nf : Qb;
    const unsigned short* hsrc = (l == 0) ? xb0 : Qs;
    k_gather8<<<2048, 256, 0, stream>>>(hsrc, csr_h, off_h, aggxb, H);
    k_mmA<<<HB64, 256, 0, stream>>>(aggxb, Wag16 + l*4096, bn2h + l*64, is_h, hhsb, H);
    k_gather8<<<2048, 256, 0, stream>>>(hhsb, csr_n, off_n, agghb, N);
    k_fused<<<NB64, 256, 0, stream>>>(agghb, Wbg16 + l*4096, bh2n + l*64, is_n, hin,
                                      g1 + l*64, be1 + l*64,
                                      W1g16 + l*64*256, b1 + l*256,
                                      W2g16 + l*256*64, b2 + l*64,
                                      g2 + l*64, be2 + l*64, Qb, Qs, N);
  }
  k_final<<<NB64, 256, 0, stream>>>(Qb, Wog16, bo, gF, bF, out, N);
}

// Round 6
// 538.026 us; speedup vs baseline: 3.5595x; 1.1505x over previous
//
#include <hip/hip_runtime.h>

// Problem constants (from reference): N=100000, H=20000, E=1600000, D=64, L=3, F=256
#define HYP 20000
#define NLAYER 3
// Bucket-sort geometry: ids fit 15 bits (H=20000) / 17 bits (N=100000).
#define NB_H 313
#define NB_N 391
#define PT 4096

typedef __attribute__((ext_vector_type(8))) short short8;
typedef __attribute__((ext_vector_type(4))) float floatx4;

static __device__ __forceinline__ unsigned short f2bf(float f){
  union { float f; unsigned u; } v; v.f = f;
  unsigned r = v.u + 0x7FFF + ((v.u >> 16) & 1);
  return (unsigned short)(r >> 16);
}

// ---- CSR build, stage 1: global bucket histogram (LDS-staged) ----
__global__ __launch_bounds__(256) void k_hist(const int* __restrict__ src,
    const int* __restrict__ dst, int E, int* __restrict__ bh, int* __restrict__ bn){
  __shared__ int lh[NB_H + NB_N];
  int tid = threadIdx.x;
  for (int i = tid; i < NB_H + NB_N; i += 256) lh[i] = 0;
  __syncthreads();
  for (int i = blockIdx.x*256 + tid; i < E; i += gridDim.x*256){
    atomicAdd(&lh[dst[i] >> 6], 1);
    atomicAdd(&lh[NB_H + (src[i] >> 8)], 1);
  }
  __syncthreads();
  for (int i = tid; i < NB_H; i += 256) if (lh[i]) atomicAdd(&bh[i], lh[i]);
  for (int i = tid; i < NB_N; i += 256) if (lh[NB_H+i]) atomicAdd(&bn[i], lh[NB_H+i]);
}

// ---- stage 2: exclusive scan of bucket counts -> bucket starts + cursors ----
__global__ __launch_bounds__(256) void k_bscan(const int* __restrict__ bh,
    const int* __restrict__ bn, int* __restrict__ bstart_h, int* __restrict__ gcur_h,
    int* __restrict__ bstart_n, int* __restrict__ gcur_n){
  __shared__ int ssc[4];
  __shared__ int scarry;
  int tid = threadIdx.x, lane = tid & 63, wv = tid >> 6;
  if (tid == 0) scarry = 0;
  __syncthreads();
  for (int base = 0; base < NB_H; base += 256){
    int i = base + tid; int v = (i < NB_H) ? bh[i] : 0; int x = v;
    #pragma unroll
    for (int o = 1; o < 64; o <<= 1){ int t = __shfl_up(x,o,64); if (lane >= o) x += t; }
    if (lane == 63) ssc[wv] = x;
    __syncthreads();
    int add = (wv>0?ssc[0]:0)+(wv>1?ssc[1]:0)+(wv>2?ssc[2]:0);
    int c = scarry;
    if (i < NB_H){ int ex = c + add + x - v; bstart_h[i] = ex; gcur_h[i] = ex; }
    __syncthreads();
    if (tid == 255) scarry = c + ssc[0]+ssc[1]+ssc[2]+ssc[3];
    __syncthreads();
  }
  if (tid == 0){ bstart_h[NB_H] = scarry; scarry = 0; }
  __syncthreads();
  for (int base = 0; base < NB_N; base += 256){
    int i = base + tid; int v = (i < NB_N) ? bn[i] : 0; int x = v;
    #pragma unroll
    for (int o = 1; o < 64; o <<= 1){ int t = __shfl_up(x,o,64); if (lane >= o) x += t; }
    if (lane == 63) ssc[wv] = x;
    __syncthreads();
    int add = (wv>0?ssc[0]:0)+(wv>1?ssc[1]:0)+(wv>2?ssc[2]:0);
    int c = scarry;
    if (i < NB_N){ int ex = c + add + x - v; bstart_n[i] = ex; gcur_n[i] = ex; }
    __syncthreads();
    if (tid == 255) scarry = c + ssc[0]+ssc[1]+ssc[2]+ssc[3];
    __syncthreads();
  }
  if (tid == 0) bstart_n[NB_N] = scarry;
}

// ---- stage 3: LDS-staged radix partition into bucket-contiguous entry buffer ----
__global__ __launch_bounds__(256) void k_partition(const int* __restrict__ keys,
    const int* __restrict__ pays, int E, int keyshift, int nb,
    int* __restrict__ gcur, unsigned* __restrict__ Ebuf){
  __shared__ unsigned sst[PT];
  __shared__ int lh[NB_N], lpre[NB_N], gb[NB_N];
  __shared__ int ssc[4];
  __shared__ int scarry;
  int tid = threadIdx.x, lane = tid & 63, wv = tid >> 6;
  int base = blockIdx.x*PT;
  int m = min(PT, E - base);
  for (int i = tid; i < nb; i += 256) lh[i] = 0;
  if (tid == 0) scarry = 0;
  __syncthreads();
  unsigned en[16]; int rk[16];
  #pragma unroll
  for (int j = 0; j < 16; ++j){
    int i = base + j*256 + tid;
    if (i < E){
      unsigned k = (unsigned)keys[i], p = (unsigned)pays[i];
      en[j] = (k << keyshift) | p;
      rk[j] = atomicAdd(&lh[en[j] >> 23], 1);
    } else { en[j] = 0; rk[j] = -1; }
  }
  __syncthreads();
  for (int b2 = 0; b2 < nb; b2 += 256){
    int i = b2 + tid; int v = (i < nb) ? lh[i] : 0; int x = v;
    #pragma unroll
    for (int o = 1; o < 64; o <<= 1){ int t = __shfl_up(x,o,64); if (lane >= o) x += t; }
    if (lane == 63) ssc[wv] = x;
    __syncthreads();
    int add = (wv>0?ssc[0]:0)+(wv>1?ssc[1]:0)+(wv>2?ssc[2]:0);
    int c = scarry;
    if (i < nb) lpre[i] = c + add + x - v;
    __syncthreads();
    if (tid == 255) scarry = c + ssc[0]+ssc[1]+ssc[2]+ssc[3];
    __syncthreads();
  }
  for (int i = tid; i < nb; i += 256) gb[i] = atomicAdd(&gcur[i], lh[i]);
  #pragma unroll
  for (int j = 0; j < 16; ++j){
    if (rk[j] >= 0){
      int bk = en[j] >> 23;
      sst[lpre[bk] + rk[j]] = en[j];
    }
  }
  __syncthreads();
  for (int j = tid; j < m; j += 256){
    unsigned e = sst[j];
    int bk = e >> 23;
    Ebuf[gb[bk] + (j - lpre[bk])] = e;
  }
}

// ---- stage 4: per-bucket CSR build ----
__global__ __launch_bounds__(256) void k_build(const unsigned* __restrict__ Ebuf,
    const int* __restrict__ bstart, int keyshift, int ipb, int paymask, int limit,
    int* __restrict__ off, float* __restrict__ isv, int* __restrict__ csr){
  __shared__ int lcnt[256], lpre2[256], lcur[256];
  int tid = threadIdx.x, lane = tid & 63, wv = tid >> 6;
  int b = blockIdx.x;
  int base = bstart[b], m = bstart[b+1] - base;
  for (int i = tid; i < ipb; i += 256) lcnt[i] = 0;
  __syncthreads();
  for (int i = tid; i < m; i += 256){
    unsigned e = Ebuf[base + i];
    atomicAdd(&lcnt[(e >> keyshift) & (ipb-1)], 1);
  }
  __syncthreads();
  if (wv == 0){
    int carry = 0;
    for (int c = 0; c < ipb; c += 64){
      int li = c + lane;
      int v = lcnt[li]; int x = v;
      #pragma unroll
      for (int o = 1; o < 64; o <<= 1){ int t = __shfl_up(x,o,64); if (lane >= o) x += t; }
      int ex = carry + x - v;
      int id = b*ipb + li;
      if (id <= limit) off[id] = base + ex;
      if (id < limit) isv[id] = rsqrtf((float)(v > 0 ? v : 1));
      lpre2[li] = ex;
      carry += __shfl(x, 63, 64);
    }
  }
  for (int i = tid; i < ipb; i += 256) lcur[i] = 0;
  __syncthreads();
  for (int i = tid; i < m; i += 256){
    unsigned e = Ebuf[base + i];
    int li = (e >> keyshift) & (ipb-1);
    int pos = base + lpre2[li] + atomicAdd(&lcur[li], 1);
    csr[pos] = (int)(e & (unsigned)paymask);
  }
}

// Pre-scale + bf16-convert node features for layer-0 h-gather
__global__ void k_prescale(const float* __restrict__ x, const float* __restrict__ isn,
                           unsigned short* __restrict__ xb, int nrows){
  int i = blockIdx.x*blockDim.x + threadIdx.x;
  int st = gridDim.x*blockDim.x;
  int tot = nrows*64;
  for (; i < tot; i += st){ xb[i] = f2bf(x[i]*isn[i >> 6]); }
}

// Convert all weights to bf16, TRANSPOSED layouts (so LDS staging in the hot
// kernels is a contiguous copy with conflict-minimal b128 writes).
// W1T[l][n][k] (256x64), W2T[l][o][kk] (64x256), WaT/WbT/WoT[n][k] (64x64).
__global__ void k_cvtall(const float* __restrict__ W1, const float* __restrict__ W2,
                         const float* __restrict__ Wa, const float* __restrict__ Wb,
                         const float* __restrict__ Wo,
                         unsigned short* __restrict__ W1T, unsigned short* __restrict__ W2T,
                         unsigned short* __restrict__ WaT, unsigned short* __restrict__ WbT,
                         unsigned short* __restrict__ WoT){
  int st = gridDim.x*blockDim.x;
  int t0 = blockIdx.x*blockDim.x + threadIdx.x;
  for (int j = t0; j < NLAYER*16384; j += st){
    int l = j >> 14, n = (j >> 6) & 255, k = j & 63;
    W1T[j] = f2bf(W1[l*16384 + k*256 + n]);
  }
  for (int j = t0; j < NLAYER*16384; j += st){
    int l = j >> 14, o = (j >> 8) & 63, kk = j & 255;
    W2T[j] = f2bf(W2[l*16384 + kk*64 + o]);
  }
  for (int j = t0; j < NLAYER*4096; j += st){
    int l = j >> 12, n = (j >> 6) & 63, k = j & 63;
    WaT[j] = f2bf(Wa[l*4096 + k*64 + n]);
  }
  for (int j = t0; j < NLAYER*4096; j += st){
    int l = j >> 12, n = (j >> 6) & 63, k = j & 63;
    WbT[j] = f2bf(Wb[l*4096 + k*64 + n]);
  }
  for (int j = t0; j < 4096; j += st){
    int n = (j >> 6) & 63, k = j & 63;
    WoT[j] = f2bf(Wo[k*64 + n]);
  }
}

// Contiguous 16B-chunk LDS staging of a pre-transposed [rows][64] bf16 matrix
// into stride-`LSTR` LDS. chunks = rows*8; bank = 4*((row+chunk)%8) -> minimal.
template<int LSTR>
static __device__ __forceinline__ void stage64(const unsigned short* __restrict__ gsrc,
    unsigned short* __restrict__ ldst, int tid, int rows){
  int nch = rows*8;
  for (int idx = tid; idx < nch; idx += 256){
    int row = idx >> 3, kc = (idx & 7)*8;
    uint4 v = *(const uint4*)&gsrc[row*64 + kc];
    *(uint4*)&ldst[row*LSTR + kc] = v;
  }
}

// Gather: wave per row, 2x unrolled (two outstanding 1KB feat loads), bf16 in/out,
// fp32 accumulate, butterfly-combine 8 edge slots (xor 8/16/32).
__global__ __launch_bounds__(256) void k_gather8(const unsigned short* __restrict__ feat,
    const int* __restrict__ csr, const int* __restrict__ off,
    unsigned short* __restrict__ agg, int nrows){
  int lane = threadIdx.x & 63, wvi = threadIdx.x >> 6;
  int g = lane >> 3;
  int ch = (lane & 7) * 8;
  int r = blockIdx.x*4 + wvi, stride = gridDim.x*4;
  for (; r < nrows; r += stride){
    int b = off[r], e = off[r+1];
    float a0=0,a1=0,a2=0,a3=0,a4=0,a5=0,a6=0,a7=0;
    int t = b;
    for (; t + 16 <= e; t += 16){
      int s0 = csr[t + g];
      int s1 = csr[t + 8 + g];
      uint4 u0 = *(const uint4*)&feat[(size_t)s0*64 + ch];
      uint4 u1 = *(const uint4*)&feat[(size_t)s1*64 + ch];
      a0 += __uint_as_float(u0.x << 16); a1 += __uint_as_float(u0.x & 0xFFFF0000u);
      a2 += __uint_as_float(u0.y << 16); a3 += __uint_as_float(u0.y & 0xFFFF0000u);
      a4 += __uint_as_float(u0.z << 16); a5 += __uint_as_float(u0.z & 0xFFFF0000u);
      a6 += __uint_as_float(u0.w << 16); a7 += __uint_as_float(u0.w & 0xFFFF0000u);
      a0 += __uint_as_float(u1.x << 16); a1 += __uint_as_float(u1.x & 0xFFFF0000u);
      a2 += __uint_as_float(u1.y << 16); a3 += __uint_as_float(u1.y & 0xFFFF0000u);
      a4 += __uint_as_float(u1.z << 16); a5 += __uint_as_float(u1.z & 0xFFFF0000u);
      a6 += __uint_as_float(u1.w << 16); a7 += __uint_as_float(u1.w & 0xFFFF0000u);
    }
    for (; t < e; t += 8){
      int idx = t + g;
      bool valid = idx < e;
      int s = csr[valid ? idx : b];
      uint4 u = *(const uint4*)&feat[(size_t)s*64 + ch];
      if (!valid){ u.x = 0; u.y = 0; u.z = 0; u.w = 0; }
      a0 += __uint_as_float(u.x << 16); a1 += __uint_as_float(u.x & 0xFFFF0000u);
      a2 += __uint_as_float(u.y << 16); a3 += __uint_as_float(u.y & 0xFFFF0000u);
      a4 += __uint_as_float(u.z << 16); a5 += __uint_as_float(u.z & 0xFFFF0000u);
      a6 += __uint_as_float(u.w << 16); a7 += __uint_as_float(u.w & 0xFFFF0000u);
    }
    #pragma unroll
    for (int o = 8; o <= 32; o <<= 1){
      a0 += __shfl_xor(a0,o,64); a1 += __shfl_xor(a1,o,64);
      a2 += __shfl_xor(a2,o,64); a3 += __shfl_xor(a3,o,64);
      a4 += __shfl_xor(a4,o,64); a5 += __shfl_xor(a5,o,64);
      a6 += __shfl_xor(a6,o,64); a7 += __shfl_xor(a7,o,64);
    }
    if (g == 0){
      uint4 w;
      w.x = (unsigned)f2bf(a0) | ((unsigned)f2bf(a1) << 16);
      w.y = (unsigned)f2bf(a2) | ((unsigned)f2bf(a3) << 16);
      w.z = (unsigned)f2bf(a4) | ((unsigned)f2bf(a5) << 16);
      w.w = (unsigned)f2bf(a6) | ((unsigned)f2bf(a7) << 16);
      *(uint4*)&agg[(size_t)r*64 + ch] = w;
    }
  }
}

// MFMA mmA: hhsb[j] = bf16( ((aggx[j]@Wa)*is_h + ba) * is_h ), 64 rows/block.
__global__ __launch_bounds__(256) void k_mmA(const unsigned short* __restrict__ aggb,
    const unsigned short* __restrict__ WaT, const float* __restrict__ bias,
    const float* __restrict__ ihy, unsigned short* __restrict__ ouths, int nrows){
  __shared__ unsigned short sWb[64*72];
  int tid = threadIdx.x;
  int lane = tid & 63, w = tid >> 6;
  int quad = lane >> 4, n16 = lane & 15;
  stage64<72>(WaT, sWb, tid, 64);
  __syncthreads();
  int rowbase = blockIdx.x*64 + w*16;
  int arow = min(rowbase + n16, nrows-1);
  short8 a0 = *(const short8*)&aggb[(size_t)arow*64 + quad*8];
  short8 a1 = *(const short8*)&aggb[(size_t)arow*64 + 32 + quad*8];
  float ih[4];
  #pragma unroll
  for (int r = 0; r < 4; ++r) ih[r] = ihy[min(rowbase + quad*4 + r, nrows-1)];
  #pragma unroll
  for (int ot = 0; ot < 4; ++ot){
    floatx4 c = (floatx4){0.f,0.f,0.f,0.f};
    short8 b0 = *(const short8*)&sWb[(ot*16+n16)*72 + quad*8];
    short8 b1 = *(const short8*)&sWb[(ot*16+n16)*72 + 32 + quad*8];
    c = __builtin_amdgcn_mfma_f32_16x16x32_bf16(a0, b0, c, 0, 0, 0);
    c = __builtin_amdgcn_mfma_f32_16x16x32_bf16(a1, b1, c, 0, 0, 0);
    float bl = bias[ot*16 + n16];
    #pragma unroll
    for (int r = 0; r < 4; ++r){
      int rr = rowbase + quad*4 + r;
      if (rr < nrows)
        ouths[(size_t)rr*64 + ot*16 + n16] = f2bf(fmaf(c[r], ih[r], bl) * ih[r]);
    }
  }
}

// Fused per-node pipeline: P = LN1(hin + (aggh@Wb)*is_n + bb);
// Out = LN2(P + relu(P@W1+b1)@W2 + b2); Qs = bf16(Out*is_n).
__global__ __launch_bounds__(256) void k_fused(
    const unsigned short* __restrict__ aggb,   // N x 64 bf16
    const unsigned short* __restrict__ WbT,    // 64 x 64 bf16 transposed (layer)
    const float* __restrict__ bbg,
    const float* __restrict__ isn,
    const float* __restrict__ hin,             // N x 64 fp32
    const float* __restrict__ g1v, const float* __restrict__ be1v,
    const unsigned short* __restrict__ W1T,    // 256 x 64 transposed (layer)
    const float* __restrict__ b1g,
    const unsigned short* __restrict__ W2T,    // 64 x 256 transposed (layer)
    const float* __restrict__ b2g,
    const float* __restrict__ g2v, const float* __restrict__ be2v,
    float* __restrict__ Outp, unsigned short* __restrict__ Qs, int nrows)
{
  __shared__ unsigned short sW1T[128*72];      // also hosts sWb (first 64*72) pre-FFN
  __shared__ unsigned short sW2T[64*136];
  __shared__ unsigned short sPH[4*16*72];      // per-wave: P staging, then H1 chunks
  unsigned short* sWb = sW1T;
  int tid = threadIdx.x;
  int lane = tid & 63, w = tid >> 6;
  int quad = lane >> 4, n16 = lane & 15;
  int rowbase = blockIdx.x*64 + w*16;

  stage64<72>(WbT, sWb, tid, 64);
  __syncthreads();

  // mmB: aggh @ Wb
  int arow = min(rowbase + n16, nrows-1);
  short8 a0 = *(const short8*)&aggb[(size_t)arow*64 + quad*8];
  short8 a1 = *(const short8*)&aggb[(size_t)arow*64 + 32 + quad*8];
  floatx4 cB[4];
  #pragma unroll
  for (int ot = 0; ot < 4; ++ot){
    floatx4 c = (floatx4){0.f,0.f,0.f,0.f};
    short8 b0 = *(const short8*)&sWb[(ot*16+n16)*72 + quad*8];
    short8 b1 = *(const short8*)&sWb[(ot*16+n16)*72 + 32 + quad*8];
    c = __builtin_amdgcn_mfma_f32_16x16x32_bf16(a0, b0, c, 0, 0, 0);
    c = __builtin_amdgcn_mfma_f32_16x16x32_bf16(a1, b1, c, 0, 0, 0);
    cB[ot] = c;
  }

  // epilogue-1: *is_n + bb + hin, then LN1 -> pP (registers) + sPH (A-layout source)
  float isr[4];
  #pragma unroll
  for (int r = 0; r < 4; ++r) isr[r] = isn[min(rowbase + quad*4 + r, nrows-1)];
  float pP[4][4];
  #pragma unroll
  for (int ot = 0; ot < 4; ++ot){
    float bb = bbg[ot*16 + n16];
    #pragma unroll
    for (int r = 0; r < 4; ++r){
      int rr = min(rowbase + quad*4 + r, nrows-1);
      pP[ot][r] = fmaf(cB[ot][r], isr[r], bb) + hin[(size_t)rr*64 + ot*16 + n16];
    }
  }
  {
    float gl[4], bl[4];
    #pragma unroll
    for (int ot = 0; ot < 4; ++ot){ gl[ot] = g1v[ot*16+n16]; bl[ot] = be1v[ot*16+n16]; }
    #pragma unroll
    for (int r = 0; r < 4; ++r){
      float s = (pP[0][r] + pP[1][r]) + (pP[2][r] + pP[3][r]);
      float q = fmaf(pP[0][r], pP[0][r], pP[1][r]*pP[1][r]) +
                fmaf(pP[2][r], pP[2][r], pP[3][r]*pP[3][r]);
      #pragma unroll
      for (int o = 8; o >= 1; o >>= 1){
        s += __shfl_xor(s, o, 64);
        q += __shfl_xor(q, o, 64);
      }
      float mu = s*(1.f/64.f);
      float var = fmaf(-mu, mu, q*(1.f/64.f));
      float rs = rsqrtf(var + 1e-5f);
      #pragma unroll
      for (int ot = 0; ot < 4; ++ot)
        pP[ot][r] = fmaf((pP[ot][r]-mu)*rs, gl[ot], bl[ot]);
    }
  }
  unsigned short* myP = &sPH[w*16*72];
  #pragma unroll
  for (int ot = 0; ot < 4; ++ot)
    #pragma unroll
    for (int r = 0; r < 4; ++r)
      myP[(quad*4 + r)*72 + ot*16 + n16] = f2bf(pP[ot][r]);
  short8 p0 = *(const short8*)&myP[n16*72 + quad*8];
  short8 p1 = *(const short8*)&myP[n16*72 + 32 + quad*8];

  // FFN
  floatx4 acc2[4];
  #pragma unroll
  for (int t = 0; t < 4; ++t) acc2[t] = (floatx4){0.f,0.f,0.f,0.f};
  unsigned short* myHc = &sPH[w*16*72];   // reused (p0/p1 already in regs)

  for (int hb = 0; hb < 2; ++hb){
    __syncthreads();
    // stage W1T rows [hb*128, hb*128+128) -> sW1T (stride 72)
    stage64<72>(W1T + hb*128*64, sW1T, tid, 128);
    // stage W2T [64 o][kk in hb*128..+128) -> sW2T (stride 136)
    for (int idx = tid; idx < 1024; idx += 256){
      int o = idx >> 4, kc = (idx & 15)*8;
      uint4 v = *(const uint4*)&W2T[o*256 + hb*128 + kc];
      *(uint4*)&sW2T[o*136 + kc] = v;
    }
    __syncthreads();

    for (int ck = 0; ck < 4; ++ck){
      #pragma unroll
      for (int nt = 0; nt < 2; ++nt){
        int nn = ck*32 + nt*16 + n16;
        floatx4 c = (floatx4){0.f,0.f,0.f,0.f};
        short8 b0 = *(const short8*)&sW1T[nn*72 + quad*8];
        short8 b1f = *(const short8*)&sW1T[nn*72 + 32 + quad*8];
        c = __builtin_amdgcn_mfma_f32_16x16x32_bf16(p0, b0, c, 0, 0, 0);
        c = __builtin_amdgcn_mfma_f32_16x16x32_bf16(p1, b1f, c, 0, 0, 0);
        float bb = b1g[hb*128 + nn];
        #pragma unroll
        for (int r = 0; r < 4; ++r){
          float h = fmaxf(c[r] + bb, 0.f);
          myHc[(quad*4 + r)*40 + nt*16 + n16] = f2bf(h);
        }
      }
      short8 a2 = *(const short8*)&myHc[n16*40 + quad*8];
      #pragma unroll
      for (int ot = 0; ot < 4; ++ot){
        short8 b2f = *(const short8*)&sW2T[(ot*16 + n16)*136 + ck*32 + quad*8];
        acc2[ot] = __builtin_amdgcn_mfma_f32_16x16x32_bf16(a2, b2f, acc2[ot], 0, 0, 0);
      }
    }
  }

  // epilogue-2: + b2 + P residual (registers), LN2, write Out fp32 + Qs bf16
  float pre[4][4];
  #pragma unroll
  for (int ot = 0; ot < 4; ++ot){
    float b2c = b2g[ot*16 + n16];
    #pragma unroll
    for (int r = 0; r < 4; ++r)
      pre[ot][r] = acc2[ot][r] + b2c + pP[ot][r];
  }
  float gl[4], bel[4];
  #pragma unroll
  for (int ot = 0; ot < 4; ++ot){ gl[ot] = g2v[ot*16 + n16]; bel[ot] = be2v[ot*16 + n16]; }
  #pragma unroll
  for (int r = 0; r < 4; ++r){
    float s = (pre[0][r] + pre[1][r]) + (pre[2][r] + pre[3][r]);
    float q = fmaf(pre[0][r], pre[0][r], pre[1][r]*pre[1][r]) +
              fmaf(pre[2][r], pre[2][r], pre[3][r]*pre[3][r]);
    #pragma unroll
    for (int o = 8; o >= 1; o >>= 1){
      s += __shfl_xor(s, o, 64);
      q += __shfl_xor(q, o, 64);
    }
    float mu = s*(1.f/64.f);
    float var = fmaf(-mu, mu, q*(1.f/64.f));
    float rs = rsqrtf(var + 1e-5f);
    int rr = rowbase + quad*4 + r;
    if (rr < nrows){
      float isr2 = isn[rr];
      #pragma unroll
      for (int ot = 0; ot < 4; ++ot){
        float ov = fmaf((pre[ot][r]-mu)*rs, gl[ot], bel[ot]);
        Outp[(size_t)rr*64 + ot*16 + n16] = ov;
        Qs[(size_t)rr*64 + ot*16 + n16] = f2bf(ov * isr2);
      }
    }
  }
}

// MFMA final: out = LN(Q, gF, bF) @ Wo + bo
__global__ __launch_bounds__(256) void k_final(const float* __restrict__ Q,
    const unsigned short* __restrict__ WoT, const float* __restrict__ bog,
    const float* __restrict__ gF, const float* __restrict__ bF,
    float* __restrict__ out, int nrows){
  __shared__ unsigned short sWb[64*72];
  int tid = threadIdx.x;
  int lane = tid & 63, w = tid >> 6;
  int quad = lane >> 4, n16 = lane & 15;
  stage64<72>(WoT, sWb, tid, 64);
  __syncthreads();
  int rowbase = blockIdx.x*64 + w*16;
  int arow = min(rowbase + n16, nrows-1);
  float4 q0 = *(const float4*)&Q[(size_t)arow*64 + quad*8];
  float4 q1 = *(const float4*)&Q[(size_t)arow*64 + quad*8 + 4];
  float4 q2 = *(const float4*)&Q[(size_t)arow*64 + 32 + quad*8];
  float4 q3 = *(const float4*)&Q[(size_t)arow*64 + 32 + quad*8 + 4];
  float s = (q0.x+q0.y+q0.z+q0.w) + (q1.x+q1.y+q1.z+q1.w)
          + (q2.x+q2.y+q2.z+q2.w) + (q3.x+q3.y+q3.z+q3.w);
  float qq = (q0.x*q0.x+q0.y*q0.y+q0.z*q0.z+q0.w*q0.w)
           + (q1.x*q1.x+q1.y*q1.y+q1.z*q1.z+q1.w*q1.w)
           + (q2.x*q2.x+q2.y*q2.y+q2.z*q2.z+q2.w*q2.w)
           + (q3.x*q3.x+q3.y*q3.y+q3.z*q3.z+q3.w*q3.w);
  s += __shfl_xor(s, 16, 64);  qq += __shfl_xor(qq, 16, 64);
  s += __shfl_xor(s, 32, 64);  qq += __shfl_xor(qq, 32, 64);
  float mu = s*(1.f/64.f);
  float var = fmaf(-mu, mu, qq*(1.f/64.f));
  float rs = rsqrtf(var + 1e-5f);
  float4 g0 = *(const float4*)&gF[quad*8];
  float4 g1 = *(const float4*)&gF[quad*8 + 4];
  float4 g2 = *(const float4*)&gF[32 + quad*8];
  float4 g3 = *(const float4*)&gF[32 + quad*8 + 4];
  float4 f0 = *(const float4*)&bF[quad*8];
  float4 f1 = *(const float4*)&bF[quad*8 + 4];
  float4 f2 = *(const float4*)&bF[32 + quad*8];
  float4 f3 = *(const float4*)&bF[32 + quad*8 + 4];
  short8 a0, a1;
  a0[0]=f2bf(fmaf((q0.x-mu)*rs, g0.x, f0.x)); a0[1]=f2bf(fmaf((q0.y-mu)*rs, g0.y, f0.y));
  a0[2]=f2bf(fmaf((q0.z-mu)*rs, g0.z, f0.z)); a0[3]=f2bf(fmaf((q0.w-mu)*rs, g0.w, f0.w));
  a0[4]=f2bf(fmaf((q1.x-mu)*rs, g1.x, f1.x)); a0[5]=f2bf(fmaf((q1.y-mu)*rs, g1.y, f1.y));
  a0[6]=f2bf(fmaf((q1.z-mu)*rs, g1.z, f1.z)); a0[7]=f2bf(fmaf((q1.w-mu)*rs, g1.w, f1.w));
  a1[0]=f2bf(fmaf((q2.x-mu)*rs, g2.x, f2.x)); a1[1]=f2bf(fmaf((q2.y-mu)*rs, g2.y, f2.y));
  a1[2]=f2bf(fmaf((q2.z-mu)*rs, g2.z, f2.z)); a1[3]=f2bf(fmaf((q2.w-mu)*rs, g2.w, f2.w));
  a1[4]=f2bf(fmaf((q3.x-mu)*rs, g3.x, f3.x)); a1[5]=f2bf(fmaf((q3.y-mu)*rs, g3.y, f3.y));
  a1[6]=f2bf(fmaf((q3.z-mu)*rs, g3.z, f3.z)); a1[7]=f2bf(fmaf((q3.w-mu)*rs, g3.w, f3.w));
  #pragma unroll
  for (int ot = 0; ot < 4; ++ot){
    floatx4 c = (floatx4){0.f,0.f,0.f,0.f};
    short8 b0 = *(const short8*)&sWb[(ot*16+n16)*72 + quad*8];
    short8 b1 = *(const short8*)&sWb[(ot*16+n16)*72 + 32 + quad*8];
    c = __builtin_amdgcn_mfma_f32_16x16x32_bf16(a0, b0, c, 0, 0, 0);
    c = __builtin_amdgcn_mfma_f32_16x16x32_bf16(a1, b1, c, 0, 0, 0);
    float bol = bog[ot*16 + n16];
    #pragma unroll
    for (int r = 0; r < 4; ++r){
      int rr = rowbase + quad*4 + r;
      if (rr < nrows) out[(size_t)rr*64 + ot*16 + n16] = c[r] + bol;
    }
  }
}

extern "C" void kernel_launch(void* const* d_in, const int* in_sizes, int n_in,
                              void* d_out, int out_size, void* d_ws, size_t ws_size,
                              hipStream_t stream){
  const float* nf   = (const float*)d_in[0];
  const int*   esrc = (const int*)d_in[1];
  const int*   edst = (const int*)d_in[2];
  const float* Wn2h = (const float*)d_in[4];
  const float* bn2h = (const float*)d_in[5];
  const float* Wh2n = (const float*)d_in[6];
  const float* bh2n = (const float*)d_in[7];
  const float* W1   = (const float*)d_in[8];
  const float* b1   = (const float*)d_in[9];
  const float* W2   = (const float*)d_in[10];
  const float* b2   = (const float*)d_in[11];
  const float* g1   = (const float*)d_in[12];
  const float* be1  = (const float*)d_in[13];
  const float* g2   = (const float*)d_in[14];
  const float* be2  = (const float*)d_in[15];
  const float* gF   = (const float*)d_in[16];
  const float* bF   = (const float*)d_in[17];
  const float* Wo   = (const float*)d_in[18];
  const float* bo   = (const float*)d_in[19];
  const int N = in_sizes[0] / 64;
  const int E = in_sizes[1];
  const int H = HYP;
  float* out = (float*)d_out;

  char* w = (char*)d_ws;
  auto carve = [&](size_t bytes) -> char* {
    char* p = w; w += (bytes + 255) & ~(size_t)255; return p;
  };
  int* bh = (int*)carve((size_t)(NB_H + NB_N)*4);
  int* bn = bh + NB_H;
  int* bstart_h = (int*)carve((size_t)(NB_H+1)*4);
  int* gcur_h   = (int*)carve((size_t)NB_H*4);
  int* bstart_n = (int*)carve((size_t)(NB_N+1)*4);
  int* gcur_n   = (int*)carve((size_t)NB_N*4);
  unsigned* Ebuf_h = (unsigned*)carve((size_t)E*4);
  unsigned* Ebuf_n = (unsigned*)carve((size_t)E*4);
  int*   off_h = (int*)carve((size_t)(H+1)*4);
  int*   off_n = (int*)carve((size_t)(N+1)*4);
  float* is_h  = (float*)carve((size_t)H*4);
  float* is_n  = (float*)carve((size_t)N*4);
  int*   csr_h = (int*)carve((size_t)E*4);
  int*   csr_n = (int*)carve((size_t)E*4);
  unsigned short* aggxb = (unsigned short*)carve((size_t)H*64*2);
  unsigned short* agghb = (unsigned short*)carve((size_t)N*64*2);
  float* Qb    = (float*)carve((size_t)N*64*4);
  unsigned short* hhsb = (unsigned short*)carve((size_t)H*64*2);
  unsigned short* xb0  = (unsigned short*)carve((size_t)N*64*2);
  unsigned short* Qs   = (unsigned short*)carve((size_t)N*64*2);
  unsigned short* W1g16 = (unsigned short*)carve((size_t)NLAYER*64*256*2);
  unsigned short* W2g16 = (unsigned short*)carve((size_t)NLAYER*256*64*2);
  unsigned short* Wag16 = (unsigned short*)carve((size_t)NLAYER*4096*2);
  unsigned short* Wbg16 = (unsigned short*)carve((size_t)NLAYER*4096*2);
  unsigned short* Wog16 = (unsigned short*)carve((size_t)4096*2);

  hipMemsetAsync(bh, 0, (size_t)(NB_H + NB_N)*4, stream);
  k_cvtall<<<96, 256, 0, stream>>>(W1, W2, Wn2h, Wh2n, Wo,
                                   W1g16, W2g16, Wag16, Wbg16, Wog16);
  k_hist<<<512, 256, 0, stream>>>(esrc, edst, E, bh, bn);
  k_bscan<<<1, 256, 0, stream>>>(bh, bn, bstart_h, gcur_h, bstart_n, gcur_n);
  k_partition<<<(E + PT - 1)/PT, 256, 0, stream>>>(edst, esrc, E, 17, NB_H, gcur_h, Ebuf_h);
  k_partition<<<(E + PT - 1)/PT, 256, 0, stream>>>(esrc, edst, E, 15, NB_N, gcur_n, Ebuf_n);
  k_build<<<NB_H, 256, 0, stream>>>(Ebuf_h, bstart_h, 17, 64, 0x1FFFF, H, off_h, is_h, csr_h);
  k_build<<<NB_N, 256, 0, stream>>>(Ebuf_n, bstart_n, 15, 256, 0x7FFF, N, off_n, is_n, csr_n);
  k_prescale<<<4096, 256, 0, stream>>>(nf, is_n, xb0, N);

  const int NB64 = (N + 63)/64;
  const int HB64 = (H + 63)/64;
  for (int l = 0; l < NLAYER; ++l){
    const float* hin = (l == 0) ? nf : Qb;
    const unsigned short* hsrc = (l == 0) ? xb0 : Qs;
    k_gather8<<<2048, 256, 0, stream>>>(hsrc, csr_h, off_h, aggxb, H);
    k_mmA<<<HB64, 256, 0, stream>>>(aggxb, Wag16 + l*4096, bn2h + l*64, is_h, hhsb, H);
    k_gather8<<<2048, 256, 0, stream>>>(hhsb, csr_n, off_n, agghb, N);
    k_fused<<<NB64, 256, 0, stream>>>(agghb, Wbg16 + l*4096, bh2n + l*64, is_n, hin,
                                      g1 + l*64, be1 + l*64,
                                      W1g16 + l*64*256, b1 + l*256,
                                      W2g16 + l*256*64, b2 + l*64,
                                      g2 + l*64, be2 + l*64, Qb, Qs, N);
  }
  k_final<<<NB64, 256, 0, stream>>>(Qb, Wog16, bo, gF, bF, out, N);
}

// Round 7
// 535.055 us; speedup vs baseline: 3.5793x; 1.0056x over previous
//
#include <hip/hip_runtime.h>

// Problem constants (from reference): N=100000, H=20000, E=1600000, D=64, L=3, F=256
#define HYP 20000
#define NLAYER 3
// Bucket-sort geometry: ids fit 15 bits (H=20000) / 17 bits (N=100000).
#define NB_H 313
#define NB_N 391
#define PT 4096

typedef __attribute__((ext_vector_type(8))) short short8;
typedef __attribute__((ext_vector_type(4))) float floatx4;

static __device__ __forceinline__ unsigned short f2bf(float f){
  union { float f; unsigned u; } v; v.f = f;
  unsigned r = v.u + 0x7FFF + ((v.u >> 16) & 1);
  return (unsigned short)(r >> 16);
}

// ---- CSR build, stage 1: global bucket histogram (LDS-staged) ----
__global__ __launch_bounds__(256) void k_hist(const int* __restrict__ src,
    const int* __restrict__ dst, int E, int* __restrict__ bh, int* __restrict__ bn){
  __shared__ int lh[NB_H + NB_N];
  int tid = threadIdx.x;
  for (int i = tid; i < NB_H + NB_N; i += 256) lh[i] = 0;
  __syncthreads();
  for (int i = blockIdx.x*256 + tid; i < E; i += gridDim.x*256){
    atomicAdd(&lh[dst[i] >> 6], 1);
    atomicAdd(&lh[NB_H + (src[i] >> 8)], 1);
  }
  __syncthreads();
  for (int i = tid; i < NB_H; i += 256) if (lh[i]) atomicAdd(&bh[i], lh[i]);
  for (int i = tid; i < NB_N; i += 256) if (lh[NB_H+i]) atomicAdd(&bn[i], lh[NB_H+i]);
}

// ---- stage 2: exclusive scan of bucket counts -> bucket starts + cursors ----
__global__ __launch_bounds__(256) void k_bscan(const int* __restrict__ bh,
    const int* __restrict__ bn, int* __restrict__ bstart_h, int* __restrict__ gcur_h,
    int* __restrict__ bstart_n, int* __restrict__ gcur_n){
  __shared__ int ssc[4];
  __shared__ int scarry;
  int tid = threadIdx.x, lane = tid & 63, wv = tid >> 6;
  if (tid == 0) scarry = 0;
  __syncthreads();
  for (int base = 0; base < NB_H; base += 256){
    int i = base + tid; int v = (i < NB_H) ? bh[i] : 0; int x = v;
    #pragma unroll
    for (int o = 1; o < 64; o <<= 1){ int t = __shfl_up(x,o,64); if (lane >= o) x += t; }
    if (lane == 63) ssc[wv] = x;
    __syncthreads();
    int add = (wv>0?ssc[0]:0)+(wv>1?ssc[1]:0)+(wv>2?ssc[2]:0);
    int c = scarry;
    if (i < NB_H){ int ex = c + add + x - v; bstart_h[i] = ex; gcur_h[i] = ex; }
    __syncthreads();
    if (tid == 255) scarry = c + ssc[0]+ssc[1]+ssc[2]+ssc[3];
    __syncthreads();
  }
  if (tid == 0){ bstart_h[NB_H] = scarry; scarry = 0; }
  __syncthreads();
  for (int base = 0; base < NB_N; base += 256){
    int i = base + tid; int v = (i < NB_N) ? bn[i] : 0; int x = v;
    #pragma unroll
    for (int o = 1; o < 64; o <<= 1){ int t = __shfl_up(x,o,64); if (lane >= o) x += t; }
    if (lane == 63) ssc[wv] = x;
    __syncthreads();
    int add = (wv>0?ssc[0]:0)+(wv>1?ssc[1]:0)+(wv>2?ssc[2]:0);
    int c = scarry;
    if (i < NB_N){ int ex = c + add + x - v; bstart_n[i] = ex; gcur_n[i] = ex; }
    __syncthreads();
    if (tid == 255) scarry = c + ssc[0]+ssc[1]+ssc[2]+ssc[3];
    __syncthreads();
  }
  if (tid == 0) bstart_n[NB_N] = scarry;
}

// ---- stage 3: LDS-staged radix partition into bucket-contiguous entry buffer ----
__global__ __launch_bounds__(256) void k_partition(const int* __restrict__ keys,
    const int* __restrict__ pays, int E, int keyshift, int nb,
    int* __restrict__ gcur, unsigned* __restrict__ Ebuf){
  __shared__ unsigned sst[PT];
  __shared__ int lh[NB_N], lpre[NB_N], gb[NB_N];
  __shared__ int ssc[4];
  __shared__ int scarry;
  int tid = threadIdx.x, lane = tid & 63, wv = tid >> 6;
  int base = blockIdx.x*PT;
  int m = min(PT, E - base);
  for (int i = tid; i < nb; i += 256) lh[i] = 0;
  if (tid == 0) scarry = 0;
  __syncthreads();
  unsigned en[16]; int rk[16];
  #pragma unroll
  for (int j = 0; j < 16; ++j){
    int i = base + j*256 + tid;
    if (i < E){
      unsigned k = (unsigned)keys[i], p = (unsigned)pays[i];
      en[j] = (k << keyshift) | p;
      rk[j] = atomicAdd(&lh[en[j] >> 23], 1);
    } else { en[j] = 0; rk[j] = -1; }
  }
  __syncthreads();
  for (int b2 = 0; b2 < nb; b2 += 256){
    int i = b2 + tid; int v = (i < nb) ? lh[i] : 0; int x = v;
    #pragma unroll
    for (int o = 1; o < 64; o <<= 1){ int t = __shfl_up(x,o,64); if (lane >= o) x += t; }
    if (lane == 63) ssc[wv] = x;
    __syncthreads();
    int add = (wv>0?ssc[0]:0)+(wv>1?ssc[1]:0)+(wv>2?ssc[2]:0);
    int c = scarry;
    if (i < nb) lpre[i] = c + add + x - v;
    __syncthreads();
    if (tid == 255) scarry = c + ssc[0]+ssc[1]+ssc[2]+ssc[3];
    __syncthreads();
  }
  for (int i = tid; i < nb; i += 256) gb[i] = atomicAdd(&gcur[i], lh[i]);
  #pragma unroll
  for (int j = 0; j < 16; ++j){
    if (rk[j] >= 0){
      int bk = en[j] >> 23;
      sst[lpre[bk] + rk[j]] = en[j];
    }
  }
  __syncthreads();
  for (int j = tid; j < m; j += 256){
    unsigned e = sst[j];
    int bk = e >> 23;
    Ebuf[gb[bk] + (j - lpre[bk])] = e;
  }
}

// ---- stage 4: per-bucket CSR build ----
__global__ __launch_bounds__(256) void k_build(const unsigned* __restrict__ Ebuf,
    const int* __restrict__ bstart, int keyshift, int ipb, int paymask, int limit,
    int* __restrict__ off, float* __restrict__ isv, int* __restrict__ csr){
  __shared__ int lcnt[256], lpre2[256], lcur[256];
  int tid = threadIdx.x, lane = tid & 63, wv = tid >> 6;
  int b = blockIdx.x;
  int base = bstart[b], m = bstart[b+1] - base;
  for (int i = tid; i < ipb; i += 256) lcnt[i] = 0;
  __syncthreads();
  for (int i = tid; i < m; i += 256){
    unsigned e = Ebuf[base + i];
    atomicAdd(&lcnt[(e >> keyshift) & (ipb-1)], 1);
  }
  __syncthreads();
  if (wv == 0){
    int carry = 0;
    for (int c = 0; c < ipb; c += 64){
      int li = c + lane;
      int v = lcnt[li]; int x = v;
      #pragma unroll
      for (int o = 1; o < 64; o <<= 1){ int t = __shfl_up(x,o,64); if (lane >= o) x += t; }
      int ex = carry + x - v;
      int id = b*ipb + li;
      if (id <= limit) off[id] = base + ex;
      if (id < limit) isv[id] = rsqrtf((float)(v > 0 ? v : 1));
      lpre2[li] = ex;
      carry += __shfl(x, 63, 64);
    }
  }
  for (int i = tid; i < ipb; i += 256) lcur[i] = 0;
  __syncthreads();
  for (int i = tid; i < m; i += 256){
    unsigned e = Ebuf[base + i];
    int li = (e >> keyshift) & (ipb-1);
    int pos = base + lpre2[li] + atomicAdd(&lcur[li], 1);
    csr[pos] = (int)(e & (unsigned)paymask);
  }
}

// Pre-scale + bf16-convert node features for layer-0 h-gather
__global__ void k_prescale(const float* __restrict__ x, const float* __restrict__ isn,
                           unsigned short* __restrict__ xb, int nrows){
  int i = blockIdx.x*blockDim.x + threadIdx.x;
  int st = gridDim.x*blockDim.x;
  int tot = nrows*64;
  for (; i < tot; i += st){ xb[i] = f2bf(x[i]*isn[i >> 6]); }
}

// Convert all weights to bf16, TRANSPOSED layouts.
__global__ void k_cvtall(const float* __restrict__ W1, const float* __restrict__ W2,
                         const float* __restrict__ Wa, const float* __restrict__ Wb,
                         const float* __restrict__ Wo,
                         unsigned short* __restrict__ W1T, unsigned short* __restrict__ W2T,
                         unsigned short* __restrict__ WaT, unsigned short* __restrict__ WbT,
                         unsigned short* __restrict__ WoT){
  int st = gridDim.x*blockDim.x;
  int t0 = blockIdx.x*blockDim.x + threadIdx.x;
  for (int j = t0; j < NLAYER*16384; j += st){
    int l = j >> 14, n = (j >> 6) & 255, k = j & 63;
    W1T[j] = f2bf(W1[l*16384 + k*256 + n]);
  }
  for (int j = t0; j < NLAYER*16384; j += st){
    int l = j >> 14, o = (j >> 8) & 63, kk = j & 255;
    W2T[j] = f2bf(W2[l*16384 + kk*64 + o]);
  }
  for (int j = t0; j < NLAYER*4096; j += st){
    int l = j >> 12, n = (j >> 6) & 63, k = j & 63;
    WaT[j] = f2bf(Wa[l*4096 + k*64 + n]);
  }
  for (int j = t0; j < NLAYER*4096; j += st){
    int l = j >> 12, n = (j >> 6) & 63, k = j & 63;
    WbT[j] = f2bf(Wb[l*4096 + k*64 + n]);
  }
  for (int j = t0; j < 4096; j += st){
    int n = (j >> 6) & 63, k = j & 63;
    WoT[j] = f2bf(Wo[k*64 + n]);
  }
}

// Contiguous 16B-chunk LDS staging of a pre-transposed [rows][64] bf16 matrix.
template<int LSTR>
static __device__ __forceinline__ void stage64(const unsigned short* __restrict__ gsrc,
    unsigned short* __restrict__ ldst, int tid, int rows){
  int nch = rows*8;
  for (int idx = tid; idx < nch; idx += 256){
    int row = idx >> 3, kc = (idx & 7)*8;
    uint4 v = *(const uint4*)&gsrc[row*64 + kc];
    *(uint4*)&ldst[row*LSTR + kc] = v;
  }
}

#define ACC8(u) \
  a0 += __uint_as_float(u.x << 16); a1 += __uint_as_float(u.x & 0xFFFF0000u); \
  a2 += __uint_as_float(u.y << 16); a3 += __uint_as_float(u.y & 0xFFFF0000u); \
  a4 += __uint_as_float(u.z << 16); a5 += __uint_as_float(u.z & 0xFFFF0000u); \
  a6 += __uint_as_float(u.w << 16); a7 += __uint_as_float(u.w & 0xFFFF0000u);

// Gather: wave per row, 4x unrolled (four outstanding 1KB feat loads), bf16 in/out,
// fp32 accumulate, butterfly-combine 8 edge slots (xor 8/16/32).
__global__ __launch_bounds__(256) void k_gather8(const unsigned short* __restrict__ feat,
    const int* __restrict__ csr, const int* __restrict__ off,
    unsigned short* __restrict__ agg, int nrows){
  int lane = threadIdx.x & 63, wvi = threadIdx.x >> 6;
  int g = lane >> 3;
  int ch = (lane & 7) * 8;
  int r = blockIdx.x*4 + wvi, stride = gridDim.x*4;
  for (; r < nrows; r += stride){
    int b = off[r], e = off[r+1];
    float a0=0,a1=0,a2=0,a3=0,a4=0,a5=0,a6=0,a7=0;
    int t = b;
    for (; t + 32 <= e; t += 32){
      int s0 = csr[t + g];
      int s1 = csr[t + 8 + g];
      int s2 = csr[t + 16 + g];
      int s3 = csr[t + 24 + g];
      uint4 u0 = *(const uint4*)&feat[(size_t)s0*64 + ch];
      uint4 u1 = *(const uint4*)&feat[(size_t)s1*64 + ch];
      uint4 u2 = *(const uint4*)&feat[(size_t)s2*64 + ch];
      uint4 u3 = *(const uint4*)&feat[(size_t)s3*64 + ch];
      ACC8(u0); ACC8(u1); ACC8(u2); ACC8(u3);
    }
    for (; t + 16 <= e; t += 16){
      int s0 = csr[t + g];
      int s1 = csr[t + 8 + g];
      uint4 u0 = *(const uint4*)&feat[(size_t)s0*64 + ch];
      uint4 u1 = *(const uint4*)&feat[(size_t)s1*64 + ch];
      ACC8(u0); ACC8(u1);
    }
    for (; t < e; t += 8){
      int idx = t + g;
      bool valid = idx < e;
      int s = csr[valid ? idx : b];
      uint4 u = *(const uint4*)&feat[(size_t)s*64 + ch];
      if (!valid){ u.x = 0; u.y = 0; u.z = 0; u.w = 0; }
      ACC8(u);
    }
    #pragma unroll
    for (int o = 8; o <= 32; o <<= 1){
      a0 += __shfl_xor(a0,o,64); a1 += __shfl_xor(a1,o,64);
      a2 += __shfl_xor(a2,o,64); a3 += __shfl_xor(a3,o,64);
      a4 += __shfl_xor(a4,o,64); a5 += __shfl_xor(a5,o,64);
      a6 += __shfl_xor(a6,o,64); a7 += __shfl_xor(a7,o,64);
    }
    if (g == 0){
      uint4 w;
      w.x = (unsigned)f2bf(a0) | ((unsigned)f2bf(a1) << 16);
      w.y = (unsigned)f2bf(a2) | ((unsigned)f2bf(a3) << 16);
      w.z = (unsigned)f2bf(a4) | ((unsigned)f2bf(a5) << 16);
      w.w = (unsigned)f2bf(a6) | ((unsigned)f2bf(a7) << 16);
      *(uint4*)&agg[(size_t)r*64 + ch] = w;
    }
  }
}

// MFMA mmA: hhsb[j] = bf16( ((aggx[j]@Wa)*is_h + ba) * is_h ), 64 rows/block.
__global__ __launch_bounds__(256) void k_mmA(const unsigned short* __restrict__ aggb,
    const unsigned short* __restrict__ WaT, const float* __restrict__ bias,
    const float* __restrict__ ihy, unsigned short* __restrict__ ouths, int nrows){
  __shared__ unsigned short sWb[64*72];
  int tid = threadIdx.x;
  int lane = tid & 63, w = tid >> 6;
  int quad = lane >> 4, n16 = lane & 15;
  stage64<72>(WaT, sWb, tid, 64);
  __syncthreads();
  int rowbase = blockIdx.x*64 + w*16;
  int arow = min(rowbase + n16, nrows-1);
  short8 a0 = *(const short8*)&aggb[(size_t)arow*64 + quad*8];
  short8 a1 = *(const short8*)&aggb[(size_t)arow*64 + 32 + quad*8];
  float ih[4];
  #pragma unroll
  for (int r = 0; r < 4; ++r) ih[r] = ihy[min(rowbase + quad*4 + r, nrows-1)];
  #pragma unroll
  for (int ot = 0; ot < 4; ++ot){
    floatx4 c = (floatx4){0.f,0.f,0.f,0.f};
    short8 b0 = *(const short8*)&sWb[(ot*16+n16)*72 + quad*8];
    short8 b1 = *(const short8*)&sWb[(ot*16+n16)*72 + 32 + quad*8];
    c = __builtin_amdgcn_mfma_f32_16x16x32_bf16(a0, b0, c, 0, 0, 0);
    c = __builtin_amdgcn_mfma_f32_16x16x32_bf16(a1, b1, c, 0, 0, 0);
    float bl = bias[ot*16 + n16];
    #pragma unroll
    for (int r = 0; r < 4; ++r){
      int rr = rowbase + quad*4 + r;
      if (rr < nrows)
        ouths[(size_t)rr*64 + ot*16 + n16] = f2bf(fmaf(c[r], ih[r], bl) * ih[r]);
    }
  }
}

// Fused per-node pipeline, 128-row tile (2 sub-tiles of 16 rows per wave):
// P = LN1(hin + (aggh@Wb)*is_n + bb); Out = LN2(P + relu(P@W1+b1)@W2 + b2);
// Qs = bf16(Out*is_n). Weight staging amortized over 2x rows vs 64-row tile.
__global__ __launch_bounds__(256) void k_fused(
    const unsigned short* __restrict__ aggb,
    const unsigned short* __restrict__ WbT,
    const float* __restrict__ bbg,
    const float* __restrict__ isn,
    const float* __restrict__ hin,
    const float* __restrict__ g1v, const float* __restrict__ be1v,
    const unsigned short* __restrict__ W1T, const float* __restrict__ b1g,
    const unsigned short* __restrict__ W2T, const float* __restrict__ b2g,
    const float* __restrict__ g2v, const float* __restrict__ be2v,
    float* __restrict__ Outp, unsigned short* __restrict__ Qs, int nrows)
{
  __shared__ unsigned short sW1T[128*72];      // also hosts sWb pre-FFN
  __shared__ unsigned short sW2T[64*136];
  __shared__ unsigned short sPH[4*16*72];      // per-wave scratch (P / H1 round-trips)
  unsigned short* sWb = sW1T;
  int tid = threadIdx.x;
  int lane = tid & 63, w = tid >> 6;
  int quad = lane >> 4, n16 = lane & 15;
  int rb[2];
  rb[0] = blockIdx.x*128 + w*16;
  rb[1] = rb[0] + 64;

  stage64<72>(WbT, sWb, tid, 64);
  __syncthreads();

  float pP[2][4][4];
  float isr[2][4];
  #pragma unroll
  for (int s = 0; s < 2; ++s){
    int arow = min(rb[s] + n16, nrows-1);
    short8 a0 = *(const short8*)&aggb[(size_t)arow*64 + quad*8];
    short8 a1 = *(const short8*)&aggb[(size_t)arow*64 + 32 + quad*8];
    #pragma unroll
    for (int r = 0; r < 4; ++r) isr[s][r] = isn[min(rb[s] + quad*4 + r, nrows-1)];
    #pragma unroll
    for (int ot = 0; ot < 4; ++ot){
      floatx4 c = (floatx4){0.f,0.f,0.f,0.f};
      short8 b0 = *(const short8*)&sWb[(ot*16+n16)*72 + quad*8];
      short8 b1 = *(const short8*)&sWb[(ot*16+n16)*72 + 32 + quad*8];
      c = __builtin_amdgcn_mfma_f32_16x16x32_bf16(a0, b0, c, 0, 0, 0);
      c = __builtin_amdgcn_mfma_f32_16x16x32_bf16(a1, b1, c, 0, 0, 0);
      float bb = bbg[ot*16 + n16];
      #pragma unroll
      for (int r = 0; r < 4; ++r){
        int rr = min(rb[s] + quad*4 + r, nrows-1);
        pP[s][ot][r] = fmaf(c[r], isr[s][r], bb) + hin[(size_t)rr*64 + ot*16 + n16];
      }
    }
  }
  // LN1 (both sub-tiles)
  {
    float gl[4], bl[4];
    #pragma unroll
    for (int ot = 0; ot < 4; ++ot){ gl[ot] = g1v[ot*16+n16]; bl[ot] = be1v[ot*16+n16]; }
    #pragma unroll
    for (int s = 0; s < 2; ++s)
      #pragma unroll
      for (int r = 0; r < 4; ++r){
        float sv = (pP[s][0][r] + pP[s][1][r]) + (pP[s][2][r] + pP[s][3][r]);
        float q = fmaf(pP[s][0][r], pP[s][0][r], pP[s][1][r]*pP[s][1][r]) +
                  fmaf(pP[s][2][r], pP[s][2][r], pP[s][3][r]*pP[s][3][r]);
        #pragma unroll
        for (int o = 8; o >= 1; o >>= 1){
          sv += __shfl_xor(sv, o, 64);
          q  += __shfl_xor(q, o, 64);
        }
        float mu = sv*(1.f/64.f);
        float var = fmaf(-mu, mu, q*(1.f/64.f));
        float rs = rsqrtf(var + 1e-5f);
        #pragma unroll
        for (int ot = 0; ot < 4; ++ot)
          pP[s][ot][r] = fmaf((pP[s][ot][r]-mu)*rs, gl[ot], bl[ot]);
      }
  }
  // C-layout -> A-layout via per-wave LDS round trip (sequential per sub-tile)
  unsigned short* myP = &sPH[w*16*72];
  short8 p0[2], p1[2];
  #pragma unroll
  for (int s = 0; s < 2; ++s){
    #pragma unroll
    for (int ot = 0; ot < 4; ++ot)
      #pragma unroll
      for (int r = 0; r < 4; ++r)
        myP[(quad*4 + r)*72 + ot*16 + n16] = f2bf(pP[s][ot][r]);
    p0[s] = *(const short8*)&myP[n16*72 + quad*8];
    p1[s] = *(const short8*)&myP[n16*72 + 32 + quad*8];
  }

  // FFN
  floatx4 acc2[2][4];
  #pragma unroll
  for (int s = 0; s < 2; ++s)
    #pragma unroll
    for (int t = 0; t < 4; ++t) acc2[s][t] = (floatx4){0.f,0.f,0.f,0.f};
  unsigned short* myHc = &sPH[w*16*72];

  for (int hb = 0; hb < 2; ++hb){
    __syncthreads();
    stage64<72>(W1T + hb*128*64, sW1T, tid, 128);
    for (int idx = tid; idx < 1024; idx += 256){
      int o = idx >> 4, kc = (idx & 15)*8;
      uint4 v = *(const uint4*)&W2T[o*256 + hb*128 + kc];
      *(uint4*)&sW2T[o*136 + kc] = v;
    }
    __syncthreads();

    for (int ck = 0; ck < 4; ++ck){
      #pragma unroll
      for (int s = 0; s < 2; ++s){
        #pragma unroll
        for (int nt = 0; nt < 2; ++nt){
          int nn = ck*32 + nt*16 + n16;
          floatx4 c = (floatx4){0.f,0.f,0.f,0.f};
          short8 b0 = *(const short8*)&sW1T[nn*72 + quad*8];
          short8 b1f = *(const short8*)&sW1T[nn*72 + 32 + quad*8];
          c = __builtin_amdgcn_mfma_f32_16x16x32_bf16(p0[s], b0, c, 0, 0, 0);
          c = __builtin_amdgcn_mfma_f32_16x16x32_bf16(p1[s], b1f, c, 0, 0, 0);
          float bb = b1g[hb*128 + nn];
          #pragma unroll
          for (int r = 0; r < 4; ++r){
            float h = fmaxf(c[r] + bb, 0.f);
            myHc[(quad*4 + r)*40 + nt*16 + n16] = f2bf(h);
          }
        }
        short8 a2 = *(const short8*)&myHc[n16*40 + quad*8];
        #pragma unroll
        for (int ot = 0; ot < 4; ++ot){
          short8 b2f = *(const short8*)&sW2T[(ot*16 + n16)*136 + ck*32 + quad*8];
          acc2[s][ot] = __builtin_amdgcn_mfma_f32_16x16x32_bf16(a2, b2f, acc2[s][ot], 0, 0, 0);
        }
      }
    }
  }

  // epilogue-2 per sub-tile
  float gl[4], bel[4];
  #pragma unroll
  for (int ot = 0; ot < 4; ++ot){ gl[ot] = g2v[ot*16 + n16]; bel[ot] = be2v[ot*16 + n16]; }
  #pragma unroll
  for (int s = 0; s < 2; ++s){
    float pre[4][4];
    #pragma unroll
    for (int ot = 0; ot < 4; ++ot){
      float b2c = b2g[ot*16 + n16];
      #pragma unroll
      for (int r = 0; r < 4; ++r)
        pre[ot][r] = acc2[s][ot][r] + b2c + pP[s][ot][r];
    }
    #pragma unroll
    for (int r = 0; r < 4; ++r){
      float sv = (pre[0][r] + pre[1][r]) + (pre[2][r] + pre[3][r]);
      float q = fmaf(pre[0][r], pre[0][r], pre[1][r]*pre[1][r]) +
                fmaf(pre[2][r], pre[2][r], pre[3][r]*pre[3][r]);
      #pragma unroll
      for (int o = 8; o >= 1; o >>= 1){
        sv += __shfl_xor(sv, o, 64);
        q  += __shfl_xor(q, o, 64);
      }
      float mu = sv*(1.f/64.f);
      float var = fmaf(-mu, mu, q*(1.f/64.f));
      float rs = rsqrtf(var + 1e-5f);
      int rr = rb[s] + quad*4 + r;
      if (rr < nrows){
        float isr2 = isn[rr];
        #pragma unroll
        for (int ot = 0; ot < 4; ++ot){
          float ov = fmaf((pre[ot][r]-mu)*rs, gl[ot], bel[ot]);
          Outp[(size_t)rr*64 + ot*16 + n16] = ov;
          Qs[(size_t)rr*64 + ot*16 + n16] = f2bf(ov * isr2);
        }
      }
    }
  }
}

// MFMA final: out = LN(Q, gF, bF) @ Wo + bo
__global__ __launch_bounds__(256) void k_final(const float* __restrict__ Q,
    const unsigned short* __restrict__ WoT, const float* __restrict__ bog,
    const float* __restrict__ gF, const float* __restrict__ bF,
    float* __restrict__ out, int nrows){
  __shared__ unsigned short sWb[64*72];
  int tid = threadIdx.x;
  int lane = tid & 63, w = tid >> 6;
  int quad = lane >> 4, n16 = lane & 15;
  stage64<72>(WoT, sWb, tid, 64);
  __syncthreads();
  int rowbase = blockIdx.x*64 + w*16;
  int arow = min(rowbase + n16, nrows-1);
  float4 q0 = *(const float4*)&Q[(size_t)arow*64 + quad*8];
  float4 q1 = *(const float4*)&Q[(size_t)arow*64 + quad*8 + 4];
  float4 q2 = *(const float4*)&Q[(size_t)arow*64 + 32 + quad*8];
  float4 q3 = *(const float4*)&Q[(size_t)arow*64 + 32 + quad*8 + 4];
  float s = (q0.x+q0.y+q0.z+q0.w) + (q1.x+q1.y+q1.z+q1.w)
          + (q2.x+q2.y+q2.z+q2.w) + (q3.x+q3.y+q3.z+q3.w);
  float qq = (q0.x*q0.x+q0.y*q0.y+q0.z*q0.z+q0.w*q0.w)
           + (q1.x*q1.x+q1.y*q1.y+q1.z*q1.z+q1.w*q1.w)
           + (q2.x*q2.x+q2.y*q2.y+q2.z*q2.z+q2.w*q2.w)
           + (q3.x*q3.x+q3.y*q3.y+q3.z*q3.z+q3.w*q3.w);
  s += __shfl_xor(s, 16, 64);  qq += __shfl_xor(qq, 16, 64);
  s += __shfl_xor(s, 32, 64);  qq += __shfl_xor(qq, 32, 64);
  float mu = s*(1.f/64.f);
  float var = fmaf(-mu, mu, qq*(1.f/64.f));
  float rs = rsqrtf(var + 1e-5f);
  float4 g0 = *(const float4*)&gF[quad*8];
  float4 g1 = *(const float4*)&gF[quad*8 + 4];
  float4 g2 = *(const float4*)&gF[32 + quad*8];
  float4 g3 = *(const float4*)&gF[32 + quad*8 + 4];
  float4 f0 = *(const float4*)&bF[quad*8];
  float4 f1 = *(const float4*)&bF[quad*8 + 4];
  float4 f2 = *(const float4*)&bF[32 + quad*8];
  float4 f3 = *(const float4*)&bF[32 + quad*8 + 4];
  short8 a0, a1;
  a0[0]=f2bf(fmaf((q0.x-mu)*rs, g0.x, f0.x)); a0[1]=f2bf(fmaf((q0.y-mu)*rs, g0.y, f0.y));
  a0[2]=f2bf(fmaf((q0.z-mu)*rs, g0.z, f0.z)); a0[3]=f2bf(fmaf((q0.w-mu)*rs, g0.w, f0.w));
  a0[4]=f2bf(fmaf((q1.x-mu)*rs, g1.x, f1.x)); a0[5]=f2bf(fmaf((q1.y-mu)*rs, g1.y, f1.y));
  a0[6]=f2bf(fmaf((q1.z-mu)*rs, g1.z, f1.z)); a0[7]=f2bf(fmaf((q1.w-mu)*rs, g1.w, f1.w));
  a1[0]=f2bf(fmaf((q2.x-mu)*rs, g2.x, f2.x)); a1[1]=f2bf(fmaf((q2.y-mu)*rs, g2.y, f2.y));
  a1[2]=f2bf(fmaf((q2.z-mu)*rs, g2.z, f2.z)); a1[3]=f2bf(fmaf((q2.w-mu)*rs, g2.w, f2.w));
  a1[4]=f2bf(fmaf((q3.x-mu)*rs, g3.x, f3.x)); a1[5]=f2bf(fmaf((q3.y-mu)*rs, g3.y, f3.y));
  a1[6]=f2bf(fmaf((q3.z-mu)*rs, g3.z, f3.z)); a1[7]=f2bf(fmaf((q3.w-mu)*rs, g3.w, f3.w));
  #pragma unroll
  for (int ot = 0; ot < 4; ++ot){
    floatx4 c = (floatx4){0.f,0.f,0.f,0.f};
    short8 b0 = *(const short8*)&sWb[(ot*16+n16)*72 + quad*8];
    short8 b1 = *(const short8*)&sWb[(ot*16+n16)*72 + 32 + quad*8];
    c = __builtin_amdgcn_mfma_f32_16x16x32_bf16(a0, b0, c, 0, 0, 0);
    c = __builtin_amdgcn_mfma_f32_16x16x32_bf16(a1, b1, c, 0, 0, 0);
    float bol = bog[ot*16 + n16];
    #pragma unroll
    for (int r = 0; r < 4; ++r){
      int rr = rowbase + quad*4 + r;
      if (rr < nrows) out[(size_t)rr*64 + ot*16 + n16] = c[r] + bol;
    }
  }
}

extern "C" void kernel_launch(void* const* d_in, const int* in_sizes, int n_in,
                              void* d_out, int out_size, void* d_ws, size_t ws_size,
                              hipStream_t stream){
  const float* nf   = (const float*)d_in[0];
  const int*   esrc = (const int*)d_in[1];
  const int*   edst = (const int*)d_in[2];
  const float* Wn2h = (const float*)d_in[4];
  const float* bn2h = (const float*)d_in[5];
  const float* Wh2n = (const float*)d_in[6];
  const float* bh2n = (const float*)d_in[7];
  const float* W1   = (const float*)d_in[8];
  const float* b1   = (const float*)d_in[9];
  const float* W2   = (const float*)d_in[10];
  const float* b2   = (const float*)d_in[11];
  const float* g1   = (const float*)d_in[12];
  const float* be1  = (const float*)d_in[13];
  const float* g2   = (const float*)d_in[14];
  const float* be2  = (const float*)d_in[15];
  const float* gF   = (const float*)d_in[16];
  const float* bF   = (const float*)d_in[17];
  const float* Wo   = (const float*)d_in[18];
  const float* bo   = (const float*)d_in[19];
  const int N = in_sizes[0] / 64;
  const int E = in_sizes[1];
  const int H = HYP;
  float* out = (float*)d_out;

  char* w = (char*)d_ws;
  auto carve = [&](size_t bytes) -> char* {
    char* p = w; w += (bytes + 255) & ~(size_t)255; return p;
  };
  int* bh = (int*)carve((size_t)(NB_H + NB_N)*4);
  int* bn = bh + NB_H;
  int* bstart_h = (int*)carve((size_t)(NB_H+1)*4);
  int* gcur_h   = (int*)carve((size_t)NB_H*4);
  int* bstart_n = (int*)carve((size_t)(NB_N+1)*4);
  int* gcur_n   = (int*)carve((size_t)NB_N*4);
  unsigned* Ebuf_h = (unsigned*)carve((size_t)E*4);
  unsigned* Ebuf_n = (unsigned*)carve((size_t)E*4);
  int*   off_h = (int*)carve((size_t)(H+1)*4);
  int*   off_n = (int*)carve((size_t)(N+1)*4);
  float* is_h  = (float*)carve((size_t)H*4);
  float* is_n  = (float*)carve((size_t)N*4);
  int*   csr_h = (int*)carve((size_t)E*4);
  int*   csr_n = (int*)carve((size_t)E*4);
  unsigned short* aggxb = (unsigned short*)carve((size_t)H*64*2);
  unsigned short* agghb = (unsigned short*)carve((size_t)N*64*2);
  float* Qb    = (float*)carve((size_t)N*64*4);
  unsigned short* hhsb = (unsigned short*)carve((size_t)H*64*2);
  unsigned short* xb0  = (unsigned short*)carve((size_t)N*64*2);
  unsigned short* Qs   = (unsigned short*)carve((size_t)N*64*2);
  unsigned short* W1g16 = (unsigned short*)carve((size_t)NLAYER*64*256*2);
  unsigned short* W2g16 = (unsigned short*)carve((size_t)NLAYER*256*64*2);
  unsigned short* Wag16 = (unsigned short*)carve((size_t)NLAYER*4096*2);
  unsigned short* Wbg16 = (unsigned short*)carve((size_t)NLAYER*4096*2);
  unsigned short* Wog16 = (unsigned short*)carve((size_t)4096*2);

  hipMemsetAsync(bh, 0, (size_t)(NB_H + NB_N)*4, stream);
  k_cvtall<<<96, 256, 0, stream>>>(W1, W2, Wn2h, Wh2n, Wo,
                                   W1g16, W2g16, Wag16, Wbg16, Wog16);
  k_hist<<<512, 256, 0, stream>>>(esrc, edst, E, bh, bn);
  k_bscan<<<1, 256, 0, stream>>>(bh, bn, bstart_h, gcur_h, bstart_n, gcur_n);
  k_partition<<<(E + PT - 1)/PT, 256, 0, stream>>>(edst, esrc, E, 17, NB_H, gcur_h, Ebuf_h);
  k_partition<<<(E + PT - 1)/PT, 256, 0, stream>>>(esrc, edst, E, 15, NB_N, gcur_n, Ebuf_n);
  k_build<<<NB_H, 256, 0, stream>>>(Ebuf_h, bstart_h, 17, 64, 0x1FFFF, H, off_h, is_h, csr_h);
  k_build<<<NB_N, 256, 0, stream>>>(Ebuf_n, bstart_n, 15, 256, 0x7FFF, N, off_n, is_n, csr_n);
  k_prescale<<<4096, 256, 0, stream>>>(nf, is_n, xb0, N);

  const int NB64 = (N + 63)/64;
  const int NB128 = (N + 127)/128;
  const int HB64 = (H + 63)/64;
  for (int l = 0; l < NLAYER; ++l){
    const float* hin = (l == 0) ? nf : Qb;
    const unsigned short* hsrc = (l == 0) ? xb0 : Qs;
    k_gather8<<<2048, 256, 0, stream>>>(hsrc, csr_h, off_h, aggxb, H);
    k_mmA<<<HB64, 256, 0, stream>>>(aggxb, Wag16 + l*4096, bn2h + l*64, is_h, hhsb, H);
    k_gather8<<<2048, 256, 0, stream>>>(hhsb, csr_n, off_n, agghb, N);
    k_fused<<<NB128, 256, 0, stream>>>(agghb, Wbg16 + l*4096, bh2n + l*64, is_n, hin,
                                       g1 + l*64, be1 + l*64,
                                       W1g16 + l*64*256, b1 + l*256,
                                       W2g16 + l*256*64, b2 + l*64,
                                       g2 + l*64, be2 + l*64, Qb, Qs, N);
  }
  k_final<<<NB64, 256, 0, stream>>>(Qb, Wog16, bo, gF, bF, out, N);
}